// Round 5
// baseline (279.087 us; speedup 1.0000x reference)
//
#include <hip/hip_runtime.h>
#include <cstdint>
#include <cstddef>

#define HIDS 1024
#define NHEAD 16
#define HDIM 64
#define LSEQ 2048
#define BBATCH 2
#define NROW (BBATCH * LSEQ)  // 4096
#define CHUNK 64
#define NCHUNK (LSEQ / CHUNK)  // 32
#define RANK 16

typedef short short8 __attribute__((ext_vector_type(8)));
typedef float floatx4 __attribute__((ext_vector_type(4)));

__device__ __forceinline__ ushort f2bf(float f) {
  uint32_t u = __float_as_uint(f);
  uint32_t r = (u + 0x7fffu + ((u >> 16) & 1u)) >> 16;  // RNE
  return (ushort)r;
}
__device__ __forceinline__ float bf2f(ushort u) {
  return __uint_as_float(((uint32_t)u) << 16);
}

__device__ __forceinline__ void async_copy16(const void* g, void* l) {
  __builtin_amdgcn_global_load_lds(
      (const __attribute__((address_space(1))) void*)g,
      (__attribute__((address_space(3))) void*)l, 16, 0, 0);
}

// ---------------------------------------------------------------------------
// x fp32 -> bf16 flat
// ---------------------------------------------------------------------------
__global__ __launch_bounds__(256) void cvt_x_kernel(const float* __restrict__ x,
                                                    ushort* __restrict__ xbf) {
  const int i = blockIdx.x * 256 + threadIdx.x;
  float4 f = *(const float4*)(x + (size_t)i * 4);
  ushort4 o;
  o.x = f2bf(f.x); o.y = f2bf(f.y); o.z = f2bf(f.z); o.w = f2bf(f.w);
  *(ushort4*)(xbf + (size_t)i * 4) = o;
}

// ---------------------------------------------------------------------------
// W [K][N] fp32 -> Wt [N][K] bf16, z selects one of 5 matrices
// ---------------------------------------------------------------------------
__global__ __launch_bounds__(256) void transpose_w_kernel(
    const float* __restrict__ W0, const float* __restrict__ W1,
    const float* __restrict__ W2, const float* __restrict__ W3,
    const float* __restrict__ W4, ushort* __restrict__ T0,
    ushort* __restrict__ T1, ushort* __restrict__ T2, ushort* __restrict__ T3,
    ushort* __restrict__ T4) {
  const int z = blockIdx.z;
  const float* W = (z == 0) ? W0 : (z == 1) ? W1 : (z == 2) ? W2 : (z == 3) ? W3 : W4;
  ushort* T = (z == 0) ? T0 : (z == 1) ? T1 : (z == 2) ? T2 : (z == 3) ? T3 : T4;
  __shared__ float sl[64][65];
  const int tid = threadIdx.x;
  const int k0 = blockIdx.y * 64, n0 = blockIdx.x * 64;
  const int r = tid >> 2, c4 = (tid & 3) * 16;
#pragma unroll
  for (int i = 0; i < 4; ++i) {
    float4 f = *(const float4*)(W + (size_t)(k0 + r) * HIDS + n0 + c4 + i * 4);
    sl[r][c4 + i * 4 + 0] = f.x;
    sl[r][c4 + i * 4 + 1] = f.y;
    sl[r][c4 + i * 4 + 2] = f.z;
    sl[r][c4 + i * 4 + 3] = f.w;
  }
  __syncthreads();
  const int n = tid >> 2, kc = (tid & 3) * 16;
#pragma unroll
  for (int i = 0; i < 4; ++i) {
    int kk = kc + i * 4;
    ushort4 o;
    o.x = f2bf(sl[kk + 0][n]);
    o.y = f2bf(sl[kk + 1][n]);
    o.z = f2bf(sl[kk + 2][n]);
    o.w = f2bf(sl[kk + 3][n]);
    *(ushort4*)(T + (size_t)(n0 + n) * HIDS + k0 + kk) = o;
  }
}

// ---------------------------------------------------------------------------
// Wefft[n][k] (bf16) = sum_r Wgk1[k][r] * Wgk2[r][n].  Grid (16,16), 256 thr.
// ---------------------------------------------------------------------------
__global__ __launch_bounds__(256) void weff_kernel(const float* __restrict__ Wgk1,
                                                   const float* __restrict__ Wgk2,
                                                   ushort* __restrict__ Wte) {
  __shared__ float sW1[64][17];  // [k_local][r]
  __shared__ float sW2[16][65];  // [r][n_local]
  const int tid = threadIdx.x;
  const int n0 = blockIdx.x * 64, k0 = blockIdx.y * 64;
  {
    const int kl = tid >> 2, r4 = (tid & 3) * 4;
    float4 f = *(const float4*)(Wgk1 + (size_t)(k0 + kl) * RANK + r4);
    sW1[kl][r4] = f.x; sW1[kl][r4 + 1] = f.y; sW1[kl][r4 + 2] = f.z; sW1[kl][r4 + 3] = f.w;
    const int rr = tid >> 4, nl = (tid & 15) * 4;
    float4 g = *(const float4*)(Wgk2 + (size_t)rr * HIDS + n0 + nl);
    sW2[rr][nl] = g.x; sW2[rr][nl + 1] = g.y; sW2[rr][nl + 2] = g.z; sW2[rr][nl + 3] = g.w;
  }
  __syncthreads();
  const int nl = tid & 63, kq = (tid >> 6) * 16;
  float w2[16];
#pragma unroll
  for (int r = 0; r < 16; ++r) w2[r] = sW2[r][nl];
  ushort ob[16];
#pragma unroll
  for (int i = 0; i < 16; ++i) {
    float s = 0.f;
#pragma unroll
    for (int r = 0; r < 16; ++r) s = fmaf(sW1[kq + i][r], w2[r], s);
    ob[i] = f2bf(s);
  }
#pragma unroll
  for (int i = 0; i < 2; ++i)
    *(short8*)(Wte + (size_t)(n0 + nl) * HIDS + k0 + kq + i * 8) = *(short8*)&ob[i * 8];
}

// ---------------------------------------------------------------------------
// proj5: 128x128 bf16 MFMA GEMM; z<4 -> bf16 q/k/v/g; z==4 -> fp32 logg
//   logg = log_sigmoid(x@Weff + bgk2) / 16
// ---------------------------------------------------------------------------
__global__ __launch_bounds__(256) void proj5_kernel(
    const ushort* __restrict__ xbf, const ushort* __restrict__ Wtq,
    const ushort* __restrict__ Wtk, const ushort* __restrict__ Wtv,
    const ushort* __restrict__ Wtg, const ushort* __restrict__ Wte,
    ushort* __restrict__ qb, ushort* __restrict__ kb, ushort* __restrict__ vb,
    ushort* __restrict__ gb, float* __restrict__ logg,
    const float* __restrict__ bgk2) {
  const int z = blockIdx.z;
  const ushort* Bt = (z == 0) ? Wtq : (z == 1) ? Wtk : (z == 2) ? Wtv
                     : (z == 3) ? Wtg : Wte;
  __shared__ ushort As[128 * 32];
  __shared__ ushort Bs[128 * 32];
  const int tid = threadIdx.x;
  const int wave = tid >> 6, lane = tid & 63;
  const int wm = (wave >> 1) * 64, wn = (wave & 1) * 64;
  const int bm = blockIdx.y * 128, bn = blockIdx.x * 128;
  const int lrow = tid >> 2, lk8 = (tid & 3) * 8;
  const ushort* Ag = xbf + (size_t)(bm + lrow) * HIDS + lk8;
  const ushort* Bg = Bt + (size_t)(bn + lrow) * HIDS + lk8;
  char* AsB = (char*)As + tid * 16;
  char* BsB = (char*)Bs + tid * 16;

  floatx4 acc[4][4];
#pragma unroll
  for (int i = 0; i < 4; ++i)
#pragma unroll
    for (int j = 0; j < 4; ++j) acc[i][j] = (floatx4){0.f, 0.f, 0.f, 0.f};

  const int fm = lane & 15, quad = lane >> 4;

  for (int k0 = 0; k0 < HIDS; k0 += 32) {
    __syncthreads();
    async_copy16(Ag + k0, AsB);
    async_copy16(Ag + (size_t)64 * HIDS + k0, AsB + 4096);
    async_copy16(Bg + k0, BsB);
    async_copy16(Bg + (size_t)64 * HIDS + k0, BsB + 4096);
    __syncthreads();

    short8 af[4], bfr[4];
#pragma unroll
    for (int i = 0; i < 4; ++i)
      af[i] = *(const short8*)&As[(wm + i * 16 + fm) * 32 + quad * 8];
#pragma unroll
    for (int j = 0; j < 4; ++j)
      bfr[j] = *(const short8*)&Bs[(wn + j * 16 + fm) * 32 + quad * 8];
#pragma unroll
    for (int i = 0; i < 4; ++i)
#pragma unroll
      for (int j = 0; j < 4; ++j)
        acc[i][j] = __builtin_amdgcn_mfma_f32_16x16x32_bf16(af[i], bfr[j],
                                                            acc[i][j], 0, 0, 0);
  }

  if (z < 4) {
    ushort* C = (z == 0) ? qb : (z == 1) ? kb : (z == 2) ? vb : gb;
#pragma unroll
    for (int i = 0; i < 4; ++i) {
      const int row0 = bm + wm + i * 16 + quad * 4;
#pragma unroll
      for (int j = 0; j < 4; ++j) {
        const int col = bn + wn + j * 16 + fm;
#pragma unroll
        for (int r = 0; r < 4; ++r)
          C[(size_t)(row0 + r) * HIDS + col] = f2bf(acc[i][j][r]);
      }
    }
  } else {
#pragma unroll
    for (int j = 0; j < 4; ++j) {
      const int col = bn + wn + j * 16 + fm;
      const float bias = bgk2[col];
#pragma unroll
      for (int i = 0; i < 4; ++i) {
        const int row0 = bm + wm + i * 16 + quad * 4;
#pragma unroll
        for (int r = 0; r < 4; ++r) {
          float zv = acc[i][j][r] + bias;
          float ls = fminf(zv, 0.f) - log1pf(expf(-fabsf(zv)));
          logg[(size_t)(row0 + r) * HIDS + col] = ls * (1.f / 16.f);
        }
      }
    }
  }
}

// ---------------------------------------------------------------------------
// Output GEMM: 128(M) x 64(N) tile, fp32 out. 512 blocks.
// ---------------------------------------------------------------------------
__global__ __launch_bounds__(256) void gemm_out_kernel(
    const ushort* __restrict__ A, const ushort* __restrict__ Bt,
    float* __restrict__ C) {
  __shared__ ushort As[128 * 32];
  __shared__ ushort Bs[64 * 32];
  const int tid = threadIdx.x;
  const int wave = tid >> 6, lane = tid & 63;
  const int fm = lane & 15, quad = lane >> 4;
  const int bm = blockIdx.y * 128, bn = blockIdx.x * 64;
  const int lrow = tid >> 2, lk8 = (tid & 3) * 8;
  const ushort* Ag = A + (size_t)(bm + lrow) * HIDS + lk8;
  const ushort* Bg = Bt + (size_t)(bn + lrow) * HIDS + lk8;
  char* AsB = (char*)As + tid * 16;
  char* BsB = (char*)Bs + tid * 16;

  floatx4 acc[2][4];
#pragma unroll
  for (int i = 0; i < 2; ++i)
#pragma unroll
    for (int j = 0; j < 4; ++j) acc[i][j] = (floatx4){0.f, 0.f, 0.f, 0.f};

  for (int k0 = 0; k0 < HIDS; k0 += 32) {
    __syncthreads();
    async_copy16(Ag + k0, AsB);
    async_copy16(Ag + (size_t)64 * HIDS + k0, AsB + 4096);
    async_copy16(Bg + k0, BsB);
    __syncthreads();

    short8 af[2], bfr[4];
#pragma unroll
    for (int i = 0; i < 2; ++i)
      af[i] = *(const short8*)&As[(wave * 32 + i * 16 + fm) * 32 + quad * 8];
#pragma unroll
    for (int j = 0; j < 4; ++j)
      bfr[j] = *(const short8*)&Bs[(j * 16 + fm) * 32 + quad * 8];
#pragma unroll
    for (int i = 0; i < 2; ++i)
#pragma unroll
      for (int j = 0; j < 4; ++j)
        acc[i][j] = __builtin_amdgcn_mfma_f32_16x16x32_bf16(af[i], bfr[j],
                                                            acc[i][j], 0, 0, 0);
  }

#pragma unroll
  for (int i = 0; i < 2; ++i) {
    const int row0 = bm + wave * 32 + i * 16 + quad * 4;
#pragma unroll
    for (int j = 0; j < 4; ++j) {
      const int col = bn + j * 16 + fm;
#pragma unroll
      for (int r = 0; r < 4; ++r)
        C[(size_t)(row0 + r) * HIDS + col] = acc[i][j][r];
    }
  }
}

#define SP 72   // ushort stride for bf16 LDS tiles (16B-aligned rows)
#define SGS 68  // float stride for Gamma tile

// ---------------------------------------------------------------------------
// sdelta: per (b,h,chunk): Gamma=cumsum(logg); Vt~=(e^-G V)^T; Kt=K^T;
//   Sdelta = Lam . (V~^T @ K); Lam = e^{Gamma_63}.
// ---------------------------------------------------------------------------
__global__ __launch_bounds__(256) void sdelta_kernel(
    const ushort* __restrict__ k, const ushort* __restrict__ v,
    const float* __restrict__ logg, float* __restrict__ Sdelta,
    float* __restrict__ Lam) {
  const int bid = blockIdx.x;
  const int c = bid & 31, bh = bid >> 5;
  const int b = bh >> 4, h = bh & 15;
  const int tid = threadIdx.x;
  const int lane = tid & 63, wave = tid >> 6;
  const int fm = lane & 15, quad = lane >> 4;
  const int wm2 = (wave >> 1) * 32, wn2 = (wave & 1) * 32;

  __shared__ ushort sKt[64 * SP];
  __shared__ ushort sVt[64 * SP];
  __shared__ float sG[64 * SGS];

  const size_t base = ((size_t)b * LSEQ + (size_t)c * CHUNK) * HIDS + (size_t)h * HDIM;
  // natural partition (logg)
  const int r = tid >> 2, c0 = (tid & 3) * 16;
  const size_t gb = base + (size_t)r * HIDS + c0;
#pragma unroll
  for (int m = 0; m < 4; ++m)
    *(float4*)&sG[r * SGS + c0 + m * 4] = *(const float4*)(logg + gb + m * 4);
  // pair partition (K, V)
  const int pr = (tid >> 3) * 2, pc = (tid & 7) * 8;
  const size_t pb = base + (size_t)pr * HIDS + pc;
  short8 ka = *(const short8*)(k + pb);
  short8 kb2 = *(const short8*)(k + pb + HIDS);
  short8 va = *(const short8*)(v + pb);
  short8 vb2 = *(const short8*)(v + pb + HIDS);
  __syncthreads();

  // inclusive cumsum along t per v column
  const int vcol = tid & 63, qtr = tid >> 6;
  {
    float run = 0.f;
#pragma unroll
    for (int i = 0; i < 16; ++i) {
      int idx = (qtr * 16 + i) * SGS + vcol;
      run += sG[idx];
      sG[idx] = run;
    }
  }
  __syncthreads();
  float pre = 0.f;
  for (int j = 0; j < qtr; ++j) pre += sG[(j * 16 + 15) * SGS + vcol];
  __syncthreads();
#pragma unroll
  for (int i = 0; i < 16; ++i) sG[(qtr * 16 + i) * SGS + vcol] += pre;
  __syncthreads();

  // transposed tiles (ushort2 writes)
#pragma unroll
  for (int i = 0; i < 8; ++i) {
    ushort2 kk;
    kk.x = (ushort)ka[i];
    kk.y = (ushort)kb2[i];
    *(ushort2*)&sKt[(pc + i) * SP + pr] = kk;
    float Ga = sG[pr * SGS + pc + i];
    float Gb2 = sG[(pr + 1) * SGS + pc + i];
    ushort2 vv;
    vv.x = f2bf(bf2f((ushort)va[i]) * expf(-Ga));
    vv.y = f2bf(bf2f((ushort)vb2[i]) * expf(-Gb2));
    *(ushort2*)&sVt[(pc + i) * SP + pr] = vv;
  }
  __syncthreads();

  if (tid < 64)
    Lam[(size_t)(bh * NCHUNK + c) * HDIM + tid] = expf(sG[63 * SGS + tid]);

  floatx4 accD[2][2];
#pragma unroll
  for (int i = 0; i < 2; ++i)
#pragma unroll
    for (int j = 0; j < 2; ++j) accD[i][j] = (floatx4){0.f, 0.f, 0.f, 0.f};
#pragma unroll
  for (int ks = 0; ks < 2; ++ks) {
    short8 av[2], bk[2];
#pragma unroll
    for (int i = 0; i < 2; ++i)
      av[i] = *(const short8*)&sVt[(wm2 + i * 16 + fm) * SP + ks * 32 + quad * 8];
#pragma unroll
    for (int j = 0; j < 2; ++j)
      bk[j] = *(const short8*)&sKt[(wn2 + j * 16 + fm) * SP + ks * 32 + quad * 8];
#pragma unroll
    for (int i = 0; i < 2; ++i)
#pragma unroll
      for (int j = 0; j < 2; ++j)
        accD[i][j] = __builtin_amdgcn_mfma_f32_16x16x32_bf16(av[i], bk[j],
                                                             accD[i][j], 0, 0, 0);
  }
  const size_t sbase = (size_t)(bh * NCHUNK + c) * (HDIM * HDIM);
#pragma unroll
  for (int i = 0; i < 2; ++i) {
    const int m0 = wm2 + i * 16 + quad * 4;
    float lam[4];
#pragma unroll
    for (int rr = 0; rr < 4; ++rr) lam[rr] = expf(sG[63 * SGS + m0 + rr]);
#pragma unroll
    for (int j = 0; j < 2; ++j) {
      const int n = wn2 + j * 16 + fm;
#pragma unroll
      for (int rr = 0; rr < 4; ++rr)
        Sdelta[sbase + (size_t)(m0 + rr) * HDIM + n] = accD[i][j][rr] * lam[rr];
    }
  }
}

// ---------------------------------------------------------------------------
// state_scan: sequential over 32 chunk boundaries; 32 blocks, state in regs.
// ---------------------------------------------------------------------------
__global__ __launch_bounds__(256) void state_scan_kernel(
    const float* __restrict__ Sdelta, const float* __restrict__ Lam,
    float* __restrict__ Sprev) {
  const int bh = blockIdx.x;
  const int tid = threadIdx.x;
  float S[16];
#pragma unroll
  for (int i = 0; i < 16; ++i) S[i] = 0.f;

  float pd[16], pl[16];
  {
    const size_t base = (size_t)(bh * NCHUNK) * (HDIM * HDIM);
    const size_t lbase = (size_t)(bh * NCHUNK) * HDIM;
#pragma unroll
    for (int i = 0; i < 16; ++i) {
      int e = tid + 256 * i;
      pd[i] = Sdelta[base + e];
      pl[i] = Lam[lbase + (e >> 6)];
    }
  }
  for (int c = 0; c < NCHUNK; ++c) {
    float cd[16], cl[16];
#pragma unroll
    for (int i = 0; i < 16; ++i) { cd[i] = pd[i]; cl[i] = pl[i]; }
    if (c + 1 < NCHUNK) {
      const size_t base = (size_t)(bh * NCHUNK + c + 1) * (HDIM * HDIM);
      const size_t lbase = (size_t)(bh * NCHUNK + c + 1) * HDIM;
#pragma unroll
      for (int i = 0; i < 16; ++i) {
        int e = tid + 256 * i;
        pd[i] = Sdelta[base + e];
        pl[i] = Lam[lbase + (e >> 6)];
      }
    }
    const size_t obase = (size_t)(bh * NCHUNK + c) * (HDIM * HDIM);
#pragma unroll
    for (int i = 0; i < 16; ++i) {
      int e = tid + 256 * i;
      Sprev[obase + e] = S[i];
      S[i] = fmaf(S[i], cl[i], cd[i]);
    }
  }
}

// ---------------------------------------------------------------------------
// chunk_fused: att = e^Gamma . ( tril(QK^T) @ (e^-G V)  +  Q @ Sprev^T )
// ---------------------------------------------------------------------------
__global__ __launch_bounds__(256) void chunk_fused_kernel(
    const ushort* __restrict__ q, const ushort* __restrict__ k,
    const ushort* __restrict__ v, const float* __restrict__ logg,
    const float* __restrict__ Sprev, float* __restrict__ att) {
  const int bid = blockIdx.x;
  const int c = bid & 31, bh = bid >> 5;
  const int b = bh >> 4, h = bh & 15;
  const int tid = threadIdx.x;
  const int lane = tid & 63, wave = tid >> 6;
  const int fm = lane & 15, quad = lane >> 4;
  const int wm2 = (wave >> 1) * 32, wn2 = (wave & 1) * 32;

  __shared__ ushort sQ[64 * SP];
  __shared__ ushort sK[64 * SP];
  __shared__ ushort sVt[64 * SP];
  __shared__ ushort sSp[64 * SP];
  __shared__ ushort sA[64 * SP];
  __shared__ float sG[64 * SGS];

  const size_t base = ((size_t)b * LSEQ + (size_t)c * CHUNK) * HIDS + (size_t)h * HDIM;
  const size_t sbase = (size_t)(bh * NCHUNK + c) * (HDIM * HDIM);
  // natural partition: Q, K, logg, Sprev
  const int r = tid >> 2, c0 = (tid & 3) * 16;
  const size_t gb = base + (size_t)r * HIDS + c0;
  *(short8*)&sQ[r * SP + c0] = *(const short8*)(q + gb);
  *(short8*)&sQ[r * SP + c0 + 8] = *(const short8*)(q + gb + 8);
  *(short8*)&sK[r * SP + c0] = *(const short8*)(k + gb);
  *(short8*)&sK[r * SP + c0 + 8] = *(const short8*)(k + gb + 8);
#pragma unroll
  for (int m = 0; m < 4; ++m)
    *(float4*)&sG[r * SGS + c0 + m * 4] = *(const float4*)(logg + gb + m * 4);
  {
    const float* sp = Sprev + sbase + (size_t)r * HDIM + c0;
    ushort* d = &sSp[r * SP + c0];
#pragma unroll
    for (int m = 0; m < 4; ++m) {
      float4 s4 = *(const float4*)(sp + m * 4);
      d[m * 4 + 0] = f2bf(s4.x); d[m * 4 + 1] = f2bf(s4.y);
      d[m * 4 + 2] = f2bf(s4.z); d[m * 4 + 3] = f2bf(s4.w);
    }
  }
  // pair partition: V
  const int pr = (tid >> 3) * 2, pc = (tid & 7) * 8;
  const size_t pb = base + (size_t)pr * HIDS + pc;
  short8 va = *(const short8*)(v + pb);
  short8 vb2 = *(const short8*)(v + pb + HIDS);
  __syncthreads();

  // cumsum Gamma
  const int vcol = tid & 63, qtr = tid >> 6;
  {
    float run = 0.f;
#pragma unroll
    for (int i = 0; i < 16; ++i) {
      int idx = (qtr * 16 + i) * SGS + vcol;
      run += sG[idx];
      sG[idx] = run;
    }
  }
  __syncthreads();
  float pre = 0.f;
  for (int j = 0; j < qtr; ++j) pre += sG[(j * 16 + 15) * SGS + vcol];
  __syncthreads();
#pragma unroll
  for (int i = 0; i < 16; ++i) sG[(qtr * 16 + i) * SGS + vcol] += pre;
  __syncthreads();

  // sVt = (e^-Gamma V)^T
#pragma unroll
  for (int i = 0; i < 8; ++i) {
    float Ga = sG[pr * SGS + pc + i];
    float Gb2 = sG[(pr + 1) * SGS + pc + i];
    ushort2 vv;
    vv.x = f2bf(bf2f((ushort)va[i]) * expf(-Ga));
    vv.y = f2bf(bf2f((ushort)vb2[i]) * expf(-Gb2));
    *(ushort2*)&sVt[(pc + i) * SP + pr] = vv;
  }
  __syncthreads();

  // scores = tril(Q K^T) -> sA (bf16)
  {
    floatx4 acc[2][2];
#pragma unroll
    for (int i = 0; i < 2; ++i)
#pragma unroll
      for (int j = 0; j < 2; ++j) acc[i][j] = (floatx4){0.f, 0.f, 0.f, 0.f};
#pragma unroll
    for (int ks = 0; ks < 2; ++ks) {
      short8 a[2], bb[2];
#pragma unroll
      for (int i = 0; i < 2; ++i)
        a[i] = *(const short8*)&sQ[(wm2 + i * 16 + fm) * SP + ks * 32 + quad * 8];
#pragma unroll
      for (int j = 0; j < 2; ++j)
        bb[j] = *(const short8*)&sK[(wn2 + j * 16 + fm) * SP + ks * 32 + quad * 8];
#pragma unroll
      for (int i = 0; i < 2; ++i)
#pragma unroll
        for (int j = 0; j < 2; ++j)
          acc[i][j] = __builtin_amdgcn_mfma_f32_16x16x32_bf16(a[i], bb[j],
                                                              acc[i][j], 0, 0, 0);
    }
#pragma unroll
    for (int i = 0; i < 2; ++i)
#pragma unroll
      for (int j = 0; j < 2; ++j) {
        const int t0 = wm2 + i * 16 + quad * 4;
        const int s = wn2 + j * 16 + fm;
#pragma unroll
        for (int rr = 0; rr < 4; ++rr) {
          float val = (s <= t0 + rr) ? acc[i][j][rr] : 0.f;
          sA[(t0 + rr) * SP + s] = f2bf(val);
        }
      }
  }
  __syncthreads();

  // att = e^G . (sA @ V~  +  Q @ Sprev^T)
  floatx4 acc[2][2];
#pragma unroll
  for (int i = 0; i < 2; ++i)
#pragma unroll
    for (int j = 0; j < 2; ++j) acc[i][j] = (floatx4){0.f, 0.f, 0.f, 0.f};
#pragma unroll
  for (int ks = 0; ks < 2; ++ks) {
    short8 aa[2], aq[2], bv[2], bs[2];
#pragma unroll
    for (int i = 0; i < 2; ++i) {
      aa[i] = *(const short8*)&sA[(wm2 + i * 16 + fm) * SP + ks * 32 + quad * 8];
      aq[i] = *(const short8*)&sQ[(wm2 + i * 16 + fm) * SP + ks * 32 + quad * 8];
    }
#pragma unroll
    for (int j = 0; j < 2; ++j) {
      bv[j] = *(const short8*)&sVt[(wn2 + j * 16 + fm) * SP + ks * 32 + quad * 8];
      bs[j] = *(const short8*)&sSp[(wn2 + j * 16 + fm) * SP + ks * 32 + quad * 8];
    }
#pragma unroll
    for (int i = 0; i < 2; ++i)
#pragma unroll
      for (int j = 0; j < 2; ++j) {
        acc[i][j] = __builtin_amdgcn_mfma_f32_16x16x32_bf16(aa[i], bv[j],
                                                            acc[i][j], 0, 0, 0);
        acc[i][j] = __builtin_amdgcn_mfma_f32_16x16x32_bf16(aq[i], bs[j],
                                                            acc[i][j], 0, 0, 0);
      }
  }
#pragma unroll
  for (int i = 0; i < 2; ++i)
#pragma unroll
    for (int j = 0; j < 2; ++j) {
      const int m0 = wm2 + i * 16 + quad * 4;
      const int n = wn2 + j * 16 + fm;
#pragma unroll
      for (int rr = 0; rr < 4; ++rr) {
        const int m = m0 + rr;
        att[base + (size_t)m * HIDS + n] = acc[i][j][rr] * expf(sG[m * SGS + n]);
      }
    }
}

// ---------------------------------------------------------------------------
// y = (LayerNorm(att) * gamma + beta) * silu(g), bf16 out. g is bf16.
// ---------------------------------------------------------------------------
__global__ __launch_bounds__(256) void ln_gate_kernel(const float* __restrict__ att,
                                                      const ushort* __restrict__ g,
                                                      const float* __restrict__ gamma,
                                                      const float* __restrict__ beta,
                                                      ushort* __restrict__ ybf) {
  const int row = blockIdx.x;
  const int tid = threadIdx.x;
  const float* ar = att + (size_t)row * HIDS;
  float4 a = *(const float4*)(ar + tid * 4);
  float s = a.x + a.y + a.z + a.w;
  float ss = a.x * a.x + a.y * a.y + a.z * a.z + a.w * a.w;
#pragma unroll
  for (int off = 32; off; off >>= 1) {
    s += __shfl_down(s, off);
    ss += __shfl_down(ss, off);
  }
  __shared__ float rs[4], rss[4];
  const int wid = tid >> 6;
  if ((tid & 63) == 0) { rs[wid] = s; rss[wid] = ss; }
  __syncthreads();
  const float mean = (rs[0] + rs[1] + rs[2] + rs[3]) * (1.f / HIDS);
  const float ex2 = (rss[0] + rss[1] + rss[2] + rss[3]) * (1.f / HIDS);
  const float rstd = rsqrtf(ex2 - mean * mean + 1e-5f);

  float4 ga = *(const float4*)(gamma + tid * 4);
  float4 be = *(const float4*)(beta + tid * 4);
  ushort4 gu = *(const ushort4*)(g + (size_t)row * HIDS + tid * 4);
  float gx = bf2f(gu.x), gy = bf2f(gu.y), gz = bf2f(gu.z), gw = bf2f(gu.w);
  float4 o;
  o.x = ((a.x - mean) * rstd * ga.x + be.x) * (gx / (1.f + expf(-gx)));
  o.y = ((a.y - mean) * rstd * ga.y + be.y) * (gy / (1.f + expf(-gy)));
  o.z = ((a.z - mean) * rstd * ga.z + be.z) * (gz / (1.f + expf(-gz)));
  o.w = ((a.w - mean) * rstd * ga.w + be.w) * (gw / (1.f + expf(-gw)));
  ushort4 ob;
  ob.x = f2bf(o.x); ob.y = f2bf(o.y); ob.z = f2bf(o.z); ob.w = f2bf(o.w);
  *(ushort4*)(ybf + (size_t)row * HIDS + tid * 4) = ob;
}

// ---------------------------------------------------------------------------
extern "C" void kernel_launch(void* const* d_in, const int* in_sizes, int n_in,
                              void* d_out, int out_size, void* d_ws, size_t ws_size,
                              hipStream_t stream) {
  const float* x     = (const float*)d_in[0];
  const float* Wq    = (const float*)d_in[1];
  const float* Wk    = (const float*)d_in[2];
  const float* Wv    = (const float*)d_in[3];
  const float* Wg    = (const float*)d_in[4];
  const float* Wgk1  = (const float*)d_in[5];
  const float* Wgk2  = (const float*)d_in[6];
  const float* bgk2  = (const float*)d_in[7];
  const float* gamma = (const float*)d_in[8];
  const float* beta  = (const float*)d_in[9];
  const float* Wout  = (const float*)d_in[10];
  float* out = (float*)d_out;

  const size_t SZ = (size_t)NROW * HIDS;  // 4M elements
  float* ws = (float*)d_ws;
  float* attb   = ws;                 // 4M f
  float* loggb  = ws + SZ;            // 4M f
  float* Sdelta = ws + 2 * SZ;        // 4M f
  float* Sprevb = ws + 3 * SZ;        // 4M f
  float* Lamb   = ws + 4 * SZ;        // 64K f
  ushort* qbf = (ushort*)(ws + 4 * SZ + 65536);
  ushort* kbf = qbf + SZ;
  ushort* vbf = kbf + SZ;
  ushort* gbf = vbf + SZ;
  ushort* xbf = gbf + SZ;
  ushort* Wtq = xbf + SZ;
  ushort* Wtk = Wtq + HIDS * HIDS;
  ushort* Wtv = Wtk + HIDS * HIDS;
  ushort* Wtg = Wtv + HIDS * HIDS;
  ushort* Wto = Wtg + HIDS * HIDS;
  ushort* Wte = Wto + HIDS * HIDS;
  ushort* ybf = vbf;  // vbf dead after chunk_fused

  cvt_x_kernel<<<SZ / 1024, 256, 0, stream>>>(x, xbf);
  transpose_w_kernel<<<dim3(16, 16, 5), 256, 0, stream>>>(
      Wq, Wk, Wv, Wg, Wout, Wtq, Wtk, Wtv, Wtg, Wto);
  weff_kernel<<<dim3(16, 16), 256, 0, stream>>>(Wgk1, Wgk2, Wte);

  proj5_kernel<<<dim3(HIDS / 128, NROW / 128, 5), 256, 0, stream>>>(
      xbf, Wtq, Wtk, Wtv, Wtg, Wte, qbf, kbf, vbf, gbf, loggb, bgk2);

  sdelta_kernel<<<BBATCH * NHEAD * NCHUNK, 256, 0, stream>>>(
      kbf, vbf, loggb, Sdelta, Lamb);
  state_scan_kernel<<<BBATCH * NHEAD, 256, 0, stream>>>(Sdelta, Lamb, Sprevb);
  chunk_fused_kernel<<<BBATCH * NHEAD * NCHUNK, 256, 0, stream>>>(
      qbf, kbf, vbf, loggb, Sprevb, attb);

  ln_gate_kernel<<<NROW, 256, 0, stream>>>(attb, gbf, gamma, beta, ybf);
  gemm_out_kernel<<<dim3(HIDS / 64, NROW / 128), 256, 0, stream>>>(ybf, Wto, out);
}

// Round 6
// 273.340 us; speedup vs baseline: 1.0210x; 1.0210x over previous
//
#include <hip/hip_runtime.h>
#include <cstdint>
#include <cstddef>

#define HIDS 1024
#define NHEAD 16
#define HDIM 64
#define LSEQ 2048
#define BBATCH 2
#define NROW (BBATCH * LSEQ)  // 4096
#define CHUNK 64
#define NCHUNK (LSEQ / CHUNK)  // 32
#define RANK 16

typedef short short8 __attribute__((ext_vector_type(8)));
typedef float floatx4 __attribute__((ext_vector_type(4)));

__device__ __forceinline__ ushort f2bf(float f) {
  uint32_t u = __float_as_uint(f);
  uint32_t r = (u + 0x7fffu + ((u >> 16) & 1u)) >> 16;  // RNE
  return (ushort)r;
}
__device__ __forceinline__ float bf2f(ushort u) {
  return __uint_as_float(((uint32_t)u) << 16);
}
// log_sigmoid(z)/16, stable
__device__ __forceinline__ float logsig16(float z) {
  return (fminf(z, 0.f) - log1pf(expf(-fabsf(z)))) * (1.f / 16.f);
}

__device__ __forceinline__ void async_copy16(const void* g, void* l) {
  __builtin_amdgcn_global_load_lds(
      (const __attribute__((address_space(1))) void*)g,
      (__attribute__((address_space(3))) void*)l, 16, 0, 0);
}

// ---------------------------------------------------------------------------
// x fp32 -> bf16 flat
// ---------------------------------------------------------------------------
__global__ __launch_bounds__(256) void cvt_x_kernel(const float* __restrict__ x,
                                                    ushort* __restrict__ xbf) {
  const int i = blockIdx.x * 256 + threadIdx.x;
  float4 f = *(const float4*)(x + (size_t)i * 4);
  ushort4 o;
  o.x = f2bf(f.x); o.y = f2bf(f.y); o.z = f2bf(f.z); o.w = f2bf(f.w);
  *(ushort4*)(xbf + (size_t)i * 4) = o;
}

// ---------------------------------------------------------------------------
// W [K][N] fp32 -> Wt [N][K] bf16, z selects one of 5 matrices
// ---------------------------------------------------------------------------
__global__ __launch_bounds__(256) void transpose_w_kernel(
    const float* __restrict__ W0, const float* __restrict__ W1,
    const float* __restrict__ W2, const float* __restrict__ W3,
    const float* __restrict__ W4, ushort* __restrict__ T0,
    ushort* __restrict__ T1, ushort* __restrict__ T2, ushort* __restrict__ T3,
    ushort* __restrict__ T4) {
  const int z = blockIdx.z;
  const float* W = (z == 0) ? W0 : (z == 1) ? W1 : (z == 2) ? W2 : (z == 3) ? W3 : W4;
  ushort* T = (z == 0) ? T0 : (z == 1) ? T1 : (z == 2) ? T2 : (z == 3) ? T3 : T4;
  __shared__ float sl[64][65];
  const int tid = threadIdx.x;
  const int k0 = blockIdx.y * 64, n0 = blockIdx.x * 64;
  const int r = tid >> 2, c4 = (tid & 3) * 16;
#pragma unroll
  for (int i = 0; i < 4; ++i) {
    float4 f = *(const float4*)(W + (size_t)(k0 + r) * HIDS + n0 + c4 + i * 4);
    sl[r][c4 + i * 4 + 0] = f.x;
    sl[r][c4 + i * 4 + 1] = f.y;
    sl[r][c4 + i * 4 + 2] = f.z;
    sl[r][c4 + i * 4 + 3] = f.w;
  }
  __syncthreads();
  const int n = tid >> 2, kc = (tid & 3) * 16;
#pragma unroll
  for (int i = 0; i < 4; ++i) {
    int kk = kc + i * 4;
    ushort4 o;
    o.x = f2bf(sl[kk + 0][n]);
    o.y = f2bf(sl[kk + 1][n]);
    o.z = f2bf(sl[kk + 2][n]);
    o.w = f2bf(sl[kk + 3][n]);
    *(ushort4*)(T + (size_t)(n0 + n) * HIDS + k0 + kk) = o;
  }
}

// ---------------------------------------------------------------------------
// Wefft[n][k] (bf16) = sum_r Wgk1[k][r] * Wgk2[r][n].  Grid (16,16), 256 thr.
// ---------------------------------------------------------------------------
__global__ __launch_bounds__(256) void weff_kernel(const float* __restrict__ Wgk1,
                                                   const float* __restrict__ Wgk2,
                                                   ushort* __restrict__ Wte) {
  __shared__ float sW1[64][17];  // [k_local][r]
  __shared__ float sW2[16][65];  // [r][n_local]
  const int tid = threadIdx.x;
  const int n0 = blockIdx.x * 64, k0 = blockIdx.y * 64;
  {
    const int kl = tid >> 2, r4 = (tid & 3) * 4;
    float4 f = *(const float4*)(Wgk1 + (size_t)(k0 + kl) * RANK + r4);
    sW1[kl][r4] = f.x; sW1[kl][r4 + 1] = f.y; sW1[kl][r4 + 2] = f.z; sW1[kl][r4 + 3] = f.w;
    const int rr = tid >> 4, nl = (tid & 15) * 4;
    float4 g = *(const float4*)(Wgk2 + (size_t)rr * HIDS + n0 + nl);
    sW2[rr][nl] = g.x; sW2[rr][nl + 1] = g.y; sW2[rr][nl + 2] = g.z; sW2[rr][nl + 3] = g.w;
  }
  __syncthreads();
  const int nl = tid & 63, kq = (tid >> 6) * 16;
  float w2[16];
#pragma unroll
  for (int r = 0; r < 16; ++r) w2[r] = sW2[r][nl];
  ushort ob[16];
#pragma unroll
  for (int i = 0; i < 16; ++i) {
    float s = 0.f;
#pragma unroll
    for (int r = 0; r < 16; ++r) s = fmaf(sW1[kq + i][r], w2[r], s);
    ob[i] = f2bf(s);
  }
#pragma unroll
  for (int i = 0; i < 2; ++i)
    *(short8*)(Wte + (size_t)(n0 + nl) * HIDS + k0 + kq + i * 8) = *(short8*)&ob[i * 8];
}

// ---------------------------------------------------------------------------
// proj5: 128x128 bf16 MFMA GEMM; z<4 -> bf16 q/k/v/g; z==4 -> bf16 gate
// logits zb = x@Weff + bgk2 (log-sigmoid deferred to consumers -> uniform
// epilogue keeps VGPR low; R5's transcendental epilogue cost 48 VGPR).
// ---------------------------------------------------------------------------
__global__ __launch_bounds__(256) void proj5_kernel(
    const ushort* __restrict__ xbf, const ushort* __restrict__ Wtq,
    const ushort* __restrict__ Wtk, const ushort* __restrict__ Wtv,
    const ushort* __restrict__ Wtg, const ushort* __restrict__ Wte,
    ushort* __restrict__ qb, ushort* __restrict__ kb, ushort* __restrict__ vb,
    ushort* __restrict__ gb, ushort* __restrict__ zb,
    const float* __restrict__ bgk2) {
  const int z = blockIdx.z;
  const ushort* Bt = (z == 0) ? Wtq : (z == 1) ? Wtk : (z == 2) ? Wtv
                     : (z == 3) ? Wtg : Wte;
  __shared__ ushort As[128 * 32];
  __shared__ ushort Bs[128 * 32];
  const int tid = threadIdx.x;
  const int wave = tid >> 6, lane = tid & 63;
  const int wm = (wave >> 1) * 64, wn = (wave & 1) * 64;
  const int bm = blockIdx.y * 128, bn = blockIdx.x * 128;
  const int lrow = tid >> 2, lk8 = (tid & 3) * 8;
  const ushort* Ag = xbf + (size_t)(bm + lrow) * HIDS + lk8;
  const ushort* Bg = Bt + (size_t)(bn + lrow) * HIDS + lk8;
  char* AsB = (char*)As + tid * 16;
  char* BsB = (char*)Bs + tid * 16;

  floatx4 acc[4][4];
#pragma unroll
  for (int i = 0; i < 4; ++i)
#pragma unroll
    for (int j = 0; j < 4; ++j) acc[i][j] = (floatx4){0.f, 0.f, 0.f, 0.f};

  const int fm = lane & 15, quad = lane >> 4;

  for (int k0 = 0; k0 < HIDS; k0 += 32) {
    __syncthreads();
    async_copy16(Ag + k0, AsB);
    async_copy16(Ag + (size_t)64 * HIDS + k0, AsB + 4096);
    async_copy16(Bg + k0, BsB);
    async_copy16(Bg + (size_t)64 * HIDS + k0, BsB + 4096);
    __syncthreads();

    short8 af[4], bfr[4];
#pragma unroll
    for (int i = 0; i < 4; ++i)
      af[i] = *(const short8*)&As[(wm + i * 16 + fm) * 32 + quad * 8];
#pragma unroll
    for (int j = 0; j < 4; ++j)
      bfr[j] = *(const short8*)&Bs[(wn + j * 16 + fm) * 32 + quad * 8];
#pragma unroll
    for (int i = 0; i < 4; ++i)
#pragma unroll
      for (int j = 0; j < 4; ++j)
        acc[i][j] = __builtin_amdgcn_mfma_f32_16x16x32_bf16(af[i], bfr[j],
                                                            acc[i][j], 0, 0, 0);
  }

  if (z < 4) {
    ushort* C = (z == 0) ? qb : (z == 1) ? kb : (z == 2) ? vb : gb;
#pragma unroll
    for (int i = 0; i < 4; ++i) {
      const int row0 = bm + wm + i * 16 + quad * 4;
#pragma unroll
      for (int j = 0; j < 4; ++j) {
        const int col = bn + wn + j * 16 + fm;
#pragma unroll
        for (int r = 0; r < 4; ++r)
          C[(size_t)(row0 + r) * HIDS + col] = f2bf(acc[i][j][r]);
      }
    }
  } else {
#pragma unroll
    for (int i = 0; i < 4; ++i) {
      const int row0 = bm + wm + i * 16 + quad * 4;
#pragma unroll
      for (int j = 0; j < 4; ++j) {
        const int col = bn + wn + j * 16 + fm;
        const float bias = bgk2[col];
#pragma unroll
        for (int r = 0; r < 4; ++r)
          zb[(size_t)(row0 + r) * HIDS + col] = f2bf(acc[i][j][r] + bias);
      }
    }
  }
}

// ---------------------------------------------------------------------------
// Output GEMM: 128(M) x 64(N) tile, fp32 out. 512 blocks.
// ---------------------------------------------------------------------------
__global__ __launch_bounds__(256) void gemm_out_kernel(
    const ushort* __restrict__ A, const ushort* __restrict__ Bt,
    float* __restrict__ C) {
  __shared__ ushort As[128 * 32];
  __shared__ ushort Bs[64 * 32];
  const int tid = threadIdx.x;
  const int wave = tid >> 6, lane = tid & 63;
  const int fm = lane & 15, quad = lane >> 4;
  const int bm = blockIdx.y * 128, bn = blockIdx.x * 64;
  const int lrow = tid >> 2, lk8 = (tid & 3) * 8;
  const ushort* Ag = A + (size_t)(bm + lrow) * HIDS + lk8;
  const ushort* Bg = Bt + (size_t)(bn + lrow) * HIDS + lk8;
  char* AsB = (char*)As + tid * 16;
  char* BsB = (char*)Bs + tid * 16;

  floatx4 acc[2][4];
#pragma unroll
  for (int i = 0; i < 2; ++i)
#pragma unroll
    for (int j = 0; j < 4; ++j) acc[i][j] = (floatx4){0.f, 0.f, 0.f, 0.f};

  for (int k0 = 0; k0 < HIDS; k0 += 32) {
    __syncthreads();
    async_copy16(Ag + k0, AsB);
    async_copy16(Ag + (size_t)64 * HIDS + k0, AsB + 4096);
    async_copy16(Bg + k0, BsB);
    __syncthreads();

    short8 af[2], bfr[4];
#pragma unroll
    for (int i = 0; i < 2; ++i)
      af[i] = *(const short8*)&As[(wave * 32 + i * 16 + fm) * 32 + quad * 8];
#pragma unroll
    for (int j = 0; j < 4; ++j)
      bfr[j] = *(const short8*)&Bs[(j * 16 + fm) * 32 + quad * 8];
#pragma unroll
    for (int i = 0; i < 2; ++i)
#pragma unroll
      for (int j = 0; j < 4; ++j)
        acc[i][j] = __builtin_amdgcn_mfma_f32_16x16x32_bf16(af[i], bfr[j],
                                                            acc[i][j], 0, 0, 0);
  }

#pragma unroll
  for (int i = 0; i < 2; ++i) {
    const int row0 = bm + wave * 32 + i * 16 + quad * 4;
#pragma unroll
    for (int j = 0; j < 4; ++j) {
      const int col = bn + j * 16 + fm;
#pragma unroll
      for (int r = 0; r < 4; ++r)
        C[(size_t)(row0 + r) * HIDS + col] = acc[i][j][r];
    }
  }
}

#define SP 72   // ushort stride for bf16 LDS tiles (16B-aligned rows)
#define SGS 68  // float stride for Gamma tile

// ---------------------------------------------------------------------------
// sdelta: per (b,h,chunk): Gamma=cumsum(logsig16(z)); Vt~=(e^-G V)^T; Kt=K^T;
//   Sdelta = Lam . (V~^T @ K); Lam = e^{Gamma_63}.
// ---------------------------------------------------------------------------
__global__ __launch_bounds__(256) void sdelta_kernel(
    const ushort* __restrict__ k, const ushort* __restrict__ v,
    const ushort* __restrict__ zb, float* __restrict__ Sdelta,
    float* __restrict__ Lam) {
  const int bid = blockIdx.x;
  const int c = bid & 31, bh = bid >> 5;
  const int b = bh >> 4, h = bh & 15;
  const int tid = threadIdx.x;
  const int lane = tid & 63, wave = tid >> 6;
  const int fm = lane & 15, quad = lane >> 4;
  const int wm2 = (wave >> 1) * 32, wn2 = (wave & 1) * 32;

  __shared__ ushort sKt[64 * SP];
  __shared__ ushort sVt[64 * SP];
  __shared__ float sG[64 * SGS];

  const size_t base = ((size_t)b * LSEQ + (size_t)c * CHUNK) * HIDS + (size_t)h * HDIM;
  // natural partition (gate logits)
  const int r = tid >> 2, c0 = (tid & 3) * 16;
  const size_t gb = base + (size_t)r * HIDS + c0;
  {
    short8 z0 = *(const short8*)(zb + gb);
    short8 z1 = *(const short8*)(zb + gb + 8);
#pragma unroll
    for (int i = 0; i < 16; ++i) {
      float zz = bf2f((ushort)(i < 8 ? z0[i] : z1[i - 8]));
      sG[r * SGS + c0 + i] = logsig16(zz);
    }
  }
  // pair partition (K, V)
  const int pr = (tid >> 3) * 2, pc = (tid & 7) * 8;
  const size_t pb = base + (size_t)pr * HIDS + pc;
  short8 ka = *(const short8*)(k + pb);
  short8 kb2 = *(const short8*)(k + pb + HIDS);
  short8 va = *(const short8*)(v + pb);
  short8 vb2 = *(const short8*)(v + pb + HIDS);
  __syncthreads();

  // inclusive cumsum along t per v column
  const int vcol = tid & 63, qtr = tid >> 6;
  {
    float run = 0.f;
#pragma unroll
    for (int i = 0; i < 16; ++i) {
      int idx = (qtr * 16 + i) * SGS + vcol;
      run += sG[idx];
      sG[idx] = run;
    }
  }
  __syncthreads();
  float pre = 0.f;
  for (int j = 0; j < qtr; ++j) pre += sG[(j * 16 + 15) * SGS + vcol];
  __syncthreads();
#pragma unroll
  for (int i = 0; i < 16; ++i) sG[(qtr * 16 + i) * SGS + vcol] += pre;
  __syncthreads();

  // transposed tiles (ushort2 writes)
#pragma unroll
  for (int i = 0; i < 8; ++i) {
    ushort2 kk;
    kk.x = (ushort)ka[i];
    kk.y = (ushort)kb2[i];
    *(ushort2*)&sKt[(pc + i) * SP + pr] = kk;
    float Ga = sG[pr * SGS + pc + i];
    float Gb2 = sG[(pr + 1) * SGS + pc + i];
    ushort2 vv;
    vv.x = f2bf(bf2f((ushort)va[i]) * expf(-Ga));
    vv.y = f2bf(bf2f((ushort)vb2[i]) * expf(-Gb2));
    *(ushort2*)&sVt[(pc + i) * SP + pr] = vv;
  }
  __syncthreads();

  if (tid < 64)
    Lam[(size_t)(bh * NCHUNK + c) * HDIM + tid] = expf(sG[63 * SGS + tid]);

  floatx4 accD[2][2];
#pragma unroll
  for (int i = 0; i < 2; ++i)
#pragma unroll
    for (int j = 0; j < 2; ++j) accD[i][j] = (floatx4){0.f, 0.f, 0.f, 0.f};
#pragma unroll
  for (int ks = 0; ks < 2; ++ks) {
    short8 av[2], bk[2];
#pragma unroll
    for (int i = 0; i < 2; ++i)
      av[i] = *(const short8*)&sVt[(wm2 + i * 16 + fm) * SP + ks * 32 + quad * 8];
#pragma unroll
    for (int j = 0; j < 2; ++j)
      bk[j] = *(const short8*)&sKt[(wn2 + j * 16 + fm) * SP + ks * 32 + quad * 8];
#pragma unroll
    for (int i = 0; i < 2; ++i)
#pragma unroll
      for (int j = 0; j < 2; ++j)
        accD[i][j] = __builtin_amdgcn_mfma_f32_16x16x32_bf16(av[i], bk[j],
                                                             accD[i][j], 0, 0, 0);
  }
  const size_t sbase = (size_t)(bh * NCHUNK + c) * (HDIM * HDIM);
#pragma unroll
  for (int i = 0; i < 2; ++i) {
    const int m0 = wm2 + i * 16 + quad * 4;
    float lam[4];
#pragma unroll
    for (int rr = 0; rr < 4; ++rr) lam[rr] = expf(sG[63 * SGS + m0 + rr]);
#pragma unroll
    for (int j = 0; j < 2; ++j) {
      const int n = wn2 + j * 16 + fm;
#pragma unroll
      for (int rr = 0; rr < 4; ++rr)
        Sdelta[sbase + (size_t)(m0 + rr) * HDIM + n] = accD[i][j][rr] * lam[rr];
    }
  }
}

// ---------------------------------------------------------------------------
// state_scan: sequential over 32 chunk boundaries; 32 blocks, state in regs.
// ---------------------------------------------------------------------------
__global__ __launch_bounds__(256) void state_scan_kernel(
    const float* __restrict__ Sdelta, const float* __restrict__ Lam,
    float* __restrict__ Sprev) {
  const int bh = blockIdx.x;
  const int tid = threadIdx.x;
  float S[16];
#pragma unroll
  for (int i = 0; i < 16; ++i) S[i] = 0.f;

  float pd[16], pl[16];
  {
    const size_t base = (size_t)(bh * NCHUNK) * (HDIM * HDIM);
    const size_t lbase = (size_t)(bh * NCHUNK) * HDIM;
#pragma unroll
    for (int i = 0; i < 16; ++i) {
      int e = tid + 256 * i;
      pd[i] = Sdelta[base + e];
      pl[i] = Lam[lbase + (e >> 6)];
    }
  }
  for (int c = 0; c < NCHUNK; ++c) {
    float cd[16], cl[16];
#pragma unroll
    for (int i = 0; i < 16; ++i) { cd[i] = pd[i]; cl[i] = pl[i]; }
    if (c + 1 < NCHUNK) {
      const size_t base = (size_t)(bh * NCHUNK + c + 1) * (HDIM * HDIM);
      const size_t lbase = (size_t)(bh * NCHUNK + c + 1) * HDIM;
#pragma unroll
      for (int i = 0; i < 16; ++i) {
        int e = tid + 256 * i;
        pd[i] = Sdelta[base + e];
        pl[i] = Lam[lbase + (e >> 6)];
      }
    }
    const size_t obase = (size_t)(bh * NCHUNK + c) * (HDIM * HDIM);
#pragma unroll
    for (int i = 0; i < 16; ++i) {
      int e = tid + 256 * i;
      Sprev[obase + e] = S[i];
      S[i] = fmaf(S[i], cl[i], cd[i]);
    }
  }
}

// ---------------------------------------------------------------------------
// chunk_fused: att = e^Gamma . ( tril(QK^T) @ (e^-G V)  +  Q @ Sprev^T )
// ---------------------------------------------------------------------------
__global__ __launch_bounds__(256) void chunk_fused_kernel(
    const ushort* __restrict__ q, const ushort* __restrict__ k,
    const ushort* __restrict__ v, const ushort* __restrict__ zb,
    const float* __restrict__ Sprev, float* __restrict__ att) {
  const int bid = blockIdx.x;
  const int c = bid & 31, bh = bid >> 5;
  const int b = bh >> 4, h = bh & 15;
  const int tid = threadIdx.x;
  const int lane = tid & 63, wave = tid >> 6;
  const int fm = lane & 15, quad = lane >> 4;
  const int wm2 = (wave >> 1) * 32, wn2 = (wave & 1) * 32;

  __shared__ ushort sQ[64 * SP];
  __shared__ ushort sK[64 * SP];
  __shared__ ushort sVt[64 * SP];
  __shared__ ushort sSp[64 * SP];
  __shared__ ushort sA[64 * SP];
  __shared__ float sG[64 * SGS];

  const size_t base = ((size_t)b * LSEQ + (size_t)c * CHUNK) * HIDS + (size_t)h * HDIM;
  const size_t sbase = (size_t)(bh * NCHUNK + c) * (HDIM * HDIM);
  // natural partition: Q, K, gate logits, Sprev
  const int r = tid >> 2, c0 = (tid & 3) * 16;
  const size_t gb = base + (size_t)r * HIDS + c0;
  *(short8*)&sQ[r * SP + c0] = *(const short8*)(q + gb);
  *(short8*)&sQ[r * SP + c0 + 8] = *(const short8*)(q + gb + 8);
  *(short8*)&sK[r * SP + c0] = *(const short8*)(k + gb);
  *(short8*)&sK[r * SP + c0 + 8] = *(const short8*)(k + gb + 8);
  {
    short8 z0 = *(const short8*)(zb + gb);
    short8 z1 = *(const short8*)(zb + gb + 8);
#pragma unroll
    for (int i = 0; i < 16; ++i) {
      float zz = bf2f((ushort)(i < 8 ? z0[i] : z1[i - 8]));
      sG[r * SGS + c0 + i] = logsig16(zz);
    }
  }
  {
    const float* sp = Sprev + sbase + (size_t)r * HDIM + c0;
    ushort* d = &sSp[r * SP + c0];
#pragma unroll
    for (int m = 0; m < 4; ++m) {
      float4 s4 = *(const float4*)(sp + m * 4);
      d[m * 4 + 0] = f2bf(s4.x); d[m * 4 + 1] = f2bf(s4.y);
      d[m * 4 + 2] = f2bf(s4.z); d[m * 4 + 3] = f2bf(s4.w);
    }
  }
  // pair partition: V
  const int pr = (tid >> 3) * 2, pc = (tid & 7) * 8;
  const size_t pb = base + (size_t)pr * HIDS + pc;
  short8 va = *(const short8*)(v + pb);
  short8 vb2 = *(const short8*)(v + pb + HIDS);
  __syncthreads();

  // cumsum Gamma
  const int vcol = tid & 63, qtr = tid >> 6;
  {
    float run = 0.f;
#pragma unroll
    for (int i = 0; i < 16; ++i) {
      int idx = (qtr * 16 + i) * SGS + vcol;
      run += sG[idx];
      sG[idx] = run;
    }
  }
  __syncthreads();
  float pre = 0.f;
  for (int j = 0; j < qtr; ++j) pre += sG[(j * 16 + 15) * SGS + vcol];
  __syncthreads();
#pragma unroll
  for (int i = 0; i < 16; ++i) sG[(qtr * 16 + i) * SGS + vcol] += pre;
  __syncthreads();

  // sVt = (e^-Gamma V)^T
#pragma unroll
  for (int i = 0; i < 8; ++i) {
    float Ga = sG[pr * SGS + pc + i];
    float Gb2 = sG[(pr + 1) * SGS + pc + i];
    ushort2 vv;
    vv.x = f2bf(bf2f((ushort)va[i]) * expf(-Ga));
    vv.y = f2bf(bf2f((ushort)vb2[i]) * expf(-Gb2));
    *(ushort2*)&sVt[(pc + i) * SP + pr] = vv;
  }
  __syncthreads();

  // scores = tril(Q K^T) -> sA (bf16)
  {
    floatx4 acc[2][2];
#pragma unroll
    for (int i = 0; i < 2; ++i)
#pragma unroll
      for (int j = 0; j < 2; ++j) acc[i][j] = (floatx4){0.f, 0.f, 0.f, 0.f};
#pragma unroll
    for (int ks = 0; ks < 2; ++ks) {
      short8 a[2], bb[2];
#pragma unroll
      for (int i = 0; i < 2; ++i)
        a[i] = *(const short8*)&sQ[(wm2 + i * 16 + fm) * SP + ks * 32 + quad * 8];
#pragma unroll
      for (int j = 0; j < 2; ++j)
        bb[j] = *(const short8*)&sK[(wn2 + j * 16 + fm) * SP + ks * 32 + quad * 8];
#pragma unroll
      for (int i = 0; i < 2; ++i)
#pragma unroll
        for (int j = 0; j < 2; ++j)
          acc[i][j] = __builtin_amdgcn_mfma_f32_16x16x32_bf16(a[i], bb[j],
                                                              acc[i][j], 0, 0, 0);
    }
#pragma unroll
    for (int i = 0; i < 2; ++i)
#pragma unroll
      for (int j = 0; j < 2; ++j) {
        const int t0 = wm2 + i * 16 + quad * 4;
        const int s = wn2 + j * 16 + fm;
#pragma unroll
        for (int rr = 0; rr < 4; ++rr) {
          float val = (s <= t0 + rr) ? acc[i][j][rr] : 0.f;
          sA[(t0 + rr) * SP + s] = f2bf(val);
        }
      }
  }
  __syncthreads();

  // att = e^G . (sA @ V~  +  Q @ Sprev^T)
  floatx4 acc[2][2];
#pragma unroll
  for (int i = 0; i < 2; ++i)
#pragma unroll
    for (int j = 0; j < 2; ++j) acc[i][j] = (floatx4){0.f, 0.f, 0.f, 0.f};
#pragma unroll
  for (int ks = 0; ks < 2; ++ks) {
    short8 aa[2], aq[2], bv[2], bs[2];
#pragma unroll
    for (int i = 0; i < 2; ++i) {
      aa[i] = *(const short8*)&sA[(wm2 + i * 16 + fm) * SP + ks * 32 + quad * 8];
      aq[i] = *(const short8*)&sQ[(wm2 + i * 16 + fm) * SP + ks * 32 + quad * 8];
    }
#pragma unroll
    for (int j = 0; j < 2; ++j) {
      bv[j] = *(const short8*)&sVt[(wn2 + j * 16 + fm) * SP + ks * 32 + quad * 8];
      bs[j] = *(const short8*)&sSp[(wn2 + j * 16 + fm) * SP + ks * 32 + quad * 8];
    }
#pragma unroll
    for (int i = 0; i < 2; ++i)
#pragma unroll
      for (int j = 0; j < 2; ++j) {
        acc[i][j] = __builtin_amdgcn_mfma_f32_16x16x32_bf16(aa[i], bv[j],
                                                            acc[i][j], 0, 0, 0);
        acc[i][j] = __builtin_amdgcn_mfma_f32_16x16x32_bf16(aq[i], bs[j],
                                                            acc[i][j], 0, 0, 0);
      }
  }
#pragma unroll
  for (int i = 0; i < 2; ++i)
#pragma unroll
    for (int j = 0; j < 2; ++j) {
      const int m0 = wm2 + i * 16 + quad * 4;
      const int n = wn2 + j * 16 + fm;
#pragma unroll
      for (int rr = 0; rr < 4; ++rr) {
        const int m = m0 + rr;
        att[base + (size_t)m * HIDS + n] = acc[i][j][rr] * expf(sG[m * SGS + n]);
      }
    }
}

// ---------------------------------------------------------------------------
// y = (LayerNorm(att) * gamma + beta) * silu(g), bf16 out. g is bf16.
// ---------------------------------------------------------------------------
__global__ __launch_bounds__(256) void ln_gate_kernel(const float* __restrict__ att,
                                                      const ushort* __restrict__ g,
                                                      const float* __restrict__ gamma,
                                                      const float* __restrict__ beta,
                                                      ushort* __restrict__ ybf) {
  const int row = blockIdx.x;
  const int tid = threadIdx.x;
  const float* ar = att + (size_t)row * HIDS;
  float4 a = *(const float4*)(ar + tid * 4);
  float s = a.x + a.y + a.z + a.w;
  float ss = a.x * a.x + a.y * a.y + a.z * a.z + a.w * a.w;
#pragma unroll
  for (int off = 32; off; off >>= 1) {
    s += __shfl_down(s, off);
    ss += __shfl_down(ss, off);
  }
  __shared__ float rs[4], rss[4];
  const int wid = tid >> 6;
  if ((tid & 63) == 0) { rs[wid] = s; rss[wid] = ss; }
  __syncthreads();
  const float mean = (rs[0] + rs[1] + rs[2] + rs[3]) * (1.f / HIDS);
  const float ex2 = (rss[0] + rss[1] + rss[2] + rss[3]) * (1.f / HIDS);
  const float rstd = rsqrtf(ex2 - mean * mean + 1e-5f);

  float4 ga = *(const float4*)(gamma + tid * 4);
  float4 be = *(const float4*)(beta + tid * 4);
  ushort4 gu = *(const ushort4*)(g + (size_t)row * HIDS + tid * 4);
  float gx = bf2f(gu.x), gy = bf2f(gu.y), gz = bf2f(gu.z), gw = bf2f(gu.w);
  float4 o;
  o.x = ((a.x - mean) * rstd * ga.x + be.x) * (gx / (1.f + expf(-gx)));
  o.y = ((a.y - mean) * rstd * ga.y + be.y) * (gy / (1.f + expf(-gy)));
  o.z = ((a.z - mean) * rstd * ga.z + be.z) * (gz / (1.f + expf(-gz)));
  o.w = ((a.w - mean) * rstd * ga.w + be.w) * (gw / (1.f + expf(-gw)));
  ushort4 ob;
  ob.x = f2bf(o.x); ob.y = f2bf(o.y); ob.z = f2bf(o.z); ob.w = f2bf(o.w);
  *(ushort4*)(ybf + (size_t)row * HIDS + tid * 4) = ob;
}

// ---------------------------------------------------------------------------
extern "C" void kernel_launch(void* const* d_in, const int* in_sizes, int n_in,
                              void* d_out, int out_size, void* d_ws, size_t ws_size,
                              hipStream_t stream) {
  const float* x     = (const float*)d_in[0];
  const float* Wq    = (const float*)d_in[1];
  const float* Wk    = (const float*)d_in[2];
  const float* Wv    = (const float*)d_in[3];
  const float* Wg    = (const float*)d_in[4];
  const float* Wgk1  = (const float*)d_in[5];
  const float* Wgk2  = (const float*)d_in[6];
  const float* bgk2  = (const float*)d_in[7];
  const float* gamma = (const float*)d_in[8];
  const float* beta  = (const float*)d_in[9];
  const float* Wout  = (const float*)d_in[10];
  float* out = (float*)d_out;

  const size_t SZ = (size_t)NROW * HIDS;  // 4M elements
  float* ws = (float*)d_ws;
  float* attb   = ws;                 // 4M f
  float* Sdelta = ws + SZ;            // 4M f
  float* Sprevb = ws + 2 * SZ;        // 4M f
  float* Lamb   = ws + 3 * SZ;        // 64K f
  ushort* qbf = (ushort*)(ws + 3 * SZ + 65536);
  ushort* kbf = qbf + SZ;
  ushort* vbf = kbf + SZ;
  ushort* gbf = vbf + SZ;
  ushort* zbf = gbf + SZ;             // gate logits (bf16)
  ushort* xbf = zbf + SZ;
  ushort* Wtq = xbf + SZ;
  ushort* Wtk = Wtq + HIDS * HIDS;
  ushort* Wtv = Wtk + HIDS * HIDS;
  ushort* Wtg = Wtv + HIDS * HIDS;
  ushort* Wto = Wtg + HIDS * HIDS;
  ushort* Wte = Wto + HIDS * HIDS;
  ushort* ybf = vbf;  // vbf dead after chunk_fused

  cvt_x_kernel<<<SZ / 1024, 256, 0, stream>>>(x, xbf);
  transpose_w_kernel<<<dim3(16, 16, 5), 256, 0, stream>>>(
      Wq, Wk, Wv, Wg, Wout, Wtq, Wtk, Wtv, Wtg, Wto);
  weff_kernel<<<dim3(16, 16), 256, 0, stream>>>(Wgk1, Wgk2, Wte);

  proj5_kernel<<<dim3(HIDS / 128, NROW / 128, 5), 256, 0, stream>>>(
      xbf, Wtq, Wtk, Wtv, Wtg, Wte, qbf, kbf, vbf, gbf, zbf, bgk2);

  sdelta_kernel<<<BBATCH * NHEAD * NCHUNK, 256, 0, stream>>>(
      kbf, vbf, zbf, Sdelta, Lamb);
  state_scan_kernel<<<BBATCH * NHEAD, 256, 0, stream>>>(Sdelta, Lamb, Sprevb);
  chunk_fused_kernel<<<BBATCH * NHEAD * NCHUNK, 256, 0, stream>>>(
      qbf, kbf, vbf, zbf, Sprevb, attb);

  ln_gate_kernel<<<NROW, 256, 0, stream>>>(attb, gbf, gamma, beta, ybf);
  gemm_out_kernel<<<dim3(HIDS / 64, NROW / 128), 256, 0, stream>>>(ybf, Wto, out);
}

// Round 7
// 240.352 us; speedup vs baseline: 1.1612x; 1.1372x over previous
//
#include <hip/hip_runtime.h>
#include <cstdint>
#include <cstddef>

#define HIDS 1024
#define NHEAD 16
#define HDIM 64
#define LSEQ 2048
#define BBATCH 2
#define NROW (BBATCH * LSEQ)  // 4096
#define CHUNK 64
#define NCHUNK (LSEQ / CHUNK)  // 32
#define RANK 16

typedef short short8 __attribute__((ext_vector_type(8)));
typedef float floatx4 __attribute__((ext_vector_type(4)));

__device__ __forceinline__ ushort f2bf(float f) {
  uint32_t u = __float_as_uint(f);
  uint32_t r = (u + 0x7fffu + ((u >> 16) & 1u)) >> 16;  // RNE
  return (ushort)r;
}
__device__ __forceinline__ float bf2f(ushort u) {
  return __uint_as_float(((uint32_t)u) << 16);
}
// log_sigmoid(z)/16, stable
__device__ __forceinline__ float logsig16(float z) {
  return (fminf(z, 0.f) - log1pf(expf(-fabsf(z)))) * (1.f / 16.f);
}

__device__ __forceinline__ void async_copy16(const void* g, void* l) {
  __builtin_amdgcn_global_load_lds(
      (const __attribute__((address_space(1))) void*)g,
      (__attribute__((address_space(3))) void*)l, 16, 0, 0);
}

// ---------------------------------------------------------------------------
// x fp32 -> bf16 flat
// ---------------------------------------------------------------------------
__global__ __launch_bounds__(256) void cvt_x_kernel(const float* __restrict__ x,
                                                    ushort* __restrict__ xbf) {
  const int i = blockIdx.x * 256 + threadIdx.x;
  float4 f = *(const float4*)(x + (size_t)i * 4);
  ushort4 o;
  o.x = f2bf(f.x); o.y = f2bf(f.y); o.z = f2bf(f.z); o.w = f2bf(f.w);
  *(ushort4*)(xbf + (size_t)i * 4) = o;
}

// ---------------------------------------------------------------------------
// W [K][N] fp32 -> Wt [N][K] bf16, z selects one of 5 matrices
// ---------------------------------------------------------------------------
__global__ __launch_bounds__(256) void transpose_w_kernel(
    const float* __restrict__ W0, const float* __restrict__ W1,
    const float* __restrict__ W2, const float* __restrict__ W3,
    const float* __restrict__ W4, ushort* __restrict__ T0,
    ushort* __restrict__ T1, ushort* __restrict__ T2, ushort* __restrict__ T3,
    ushort* __restrict__ T4) {
  const int z = blockIdx.z;
  const float* W = (z == 0) ? W0 : (z == 1) ? W1 : (z == 2) ? W2 : (z == 3) ? W3 : W4;
  ushort* T = (z == 0) ? T0 : (z == 1) ? T1 : (z == 2) ? T2 : (z == 3) ? T3 : T4;
  __shared__ float sl[64][65];
  const int tid = threadIdx.x;
  const int k0 = blockIdx.y * 64, n0 = blockIdx.x * 64;
  const int r = tid >> 2, c4 = (tid & 3) * 16;
#pragma unroll
  for (int i = 0; i < 4; ++i) {
    float4 f = *(const float4*)(W + (size_t)(k0 + r) * HIDS + n0 + c4 + i * 4);
    sl[r][c4 + i * 4 + 0] = f.x;
    sl[r][c4 + i * 4 + 1] = f.y;
    sl[r][c4 + i * 4 + 2] = f.z;
    sl[r][c4 + i * 4 + 3] = f.w;
  }
  __syncthreads();
  const int n = tid >> 2, kc = (tid & 3) * 16;
#pragma unroll
  for (int i = 0; i < 4; ++i) {
    int kk = kc + i * 4;
    ushort4 o;
    o.x = f2bf(sl[kk + 0][n]);
    o.y = f2bf(sl[kk + 1][n]);
    o.z = f2bf(sl[kk + 2][n]);
    o.w = f2bf(sl[kk + 3][n]);
    *(ushort4*)(T + (size_t)(n0 + n) * HIDS + k0 + kk) = o;
  }
}

// ---------------------------------------------------------------------------
// Wefft[n][k] (bf16) = sum_r Wgk1[k][r] * Wgk2[r][n].  Grid (16,16), 256 thr.
// ---------------------------------------------------------------------------
__global__ __launch_bounds__(256) void weff_kernel(const float* __restrict__ Wgk1,
                                                   const float* __restrict__ Wgk2,
                                                   ushort* __restrict__ Wte) {
  __shared__ float sW1[64][17];  // [k_local][r]
  __shared__ float sW2[16][65];  // [r][n_local]
  const int tid = threadIdx.x;
  const int n0 = blockIdx.x * 64, k0 = blockIdx.y * 64;
  {
    const int kl = tid >> 2, r4 = (tid & 3) * 4;
    float4 f = *(const float4*)(Wgk1 + (size_t)(k0 + kl) * RANK + r4);
    sW1[kl][r4] = f.x; sW1[kl][r4 + 1] = f.y; sW1[kl][r4 + 2] = f.z; sW1[kl][r4 + 3] = f.w;
    const int rr = tid >> 4, nl = (tid & 15) * 4;
    float4 g = *(const float4*)(Wgk2 + (size_t)rr * HIDS + n0 + nl);
    sW2[rr][nl] = g.x; sW2[rr][nl + 1] = g.y; sW2[rr][nl + 2] = g.z; sW2[rr][nl + 3] = g.w;
  }
  __syncthreads();
  const int nl = tid & 63, kq = (tid >> 6) * 16;
  float w2[16];
#pragma unroll
  for (int r = 0; r < 16; ++r) w2[r] = sW2[r][nl];
  ushort ob[16];
#pragma unroll
  for (int i = 0; i < 16; ++i) {
    float s = 0.f;
#pragma unroll
    for (int r = 0; r < 16; ++r) s = fmaf(sW1[kq + i][r], w2[r], s);
    ob[i] = f2bf(s);
  }
#pragma unroll
  for (int i = 0; i < 2; ++i)
    *(short8*)(Wte + (size_t)(n0 + nl) * HIDS + k0 + kq + i * 8) = *(short8*)&ob[i * 8];
}

// ---------------------------------------------------------------------------
// proj5: 128x128 bf16 MFMA GEMM, BK=64 (two stacked BK=32 sub-tiles), uniform
// bf16 epilogue for all 5 slices (bias for z==4 applied in consumers).
// ---------------------------------------------------------------------------
__global__ __launch_bounds__(256) void proj5_kernel(
    const ushort* __restrict__ xbf, const ushort* __restrict__ Wtq,
    const ushort* __restrict__ Wtk, const ushort* __restrict__ Wtv,
    const ushort* __restrict__ Wtg, const ushort* __restrict__ Wte,
    ushort* __restrict__ qb, ushort* __restrict__ kb, ushort* __restrict__ vb,
    ushort* __restrict__ gb, ushort* __restrict__ zb) {
  const int z = blockIdx.z;
  const ushort* Bt = (z == 0) ? Wtq : (z == 1) ? Wtk : (z == 2) ? Wtv
                     : (z == 3) ? Wtg : Wte;
  ushort* C = (z == 0) ? qb : (z == 1) ? kb : (z == 2) ? vb : (z == 3) ? gb : zb;
  __shared__ ushort As[2][128 * 32];
  __shared__ ushort Bs[2][128 * 32];
  const int tid = threadIdx.x;
  const int wave = tid >> 6, lane = tid & 63;
  const int wm = (wave >> 1) * 64, wn = (wave & 1) * 64;
  const int bm = blockIdx.y * 128, bn = blockIdx.x * 128;
  const int lrow = tid >> 2, lk8 = (tid & 3) * 8;
  const ushort* Ag = xbf + (size_t)(bm + lrow) * HIDS + lk8;
  const ushort* Bg = Bt + (size_t)(bn + lrow) * HIDS + lk8;
  char* A0 = (char*)&As[0][0] + tid * 16;
  char* A1 = (char*)&As[1][0] + tid * 16;
  char* B0 = (char*)&Bs[0][0] + tid * 16;
  char* B1 = (char*)&Bs[1][0] + tid * 16;

  floatx4 acc[4][4];
#pragma unroll
  for (int i = 0; i < 4; ++i)
#pragma unroll
    for (int j = 0; j < 4; ++j) acc[i][j] = (floatx4){0.f, 0.f, 0.f, 0.f};

  const int fm = lane & 15, quad = lane >> 4;

  for (int k0 = 0; k0 < HIDS; k0 += 64) {
    __syncthreads();
    async_copy16(Ag + k0, A0);
    async_copy16(Ag + (size_t)64 * HIDS + k0, A0 + 4096);
    async_copy16(Ag + k0 + 32, A1);
    async_copy16(Ag + (size_t)64 * HIDS + k0 + 32, A1 + 4096);
    async_copy16(Bg + k0, B0);
    async_copy16(Bg + (size_t)64 * HIDS + k0, B0 + 4096);
    async_copy16(Bg + k0 + 32, B1);
    async_copy16(Bg + (size_t)64 * HIDS + k0 + 32, B1 + 4096);
    __syncthreads();

#pragma unroll
    for (int ks = 0; ks < 2; ++ks) {
      short8 af[4], bfr[4];
#pragma unroll
      for (int i = 0; i < 4; ++i)
        af[i] = *(const short8*)&As[ks][(wm + i * 16 + fm) * 32 + quad * 8];
#pragma unroll
      for (int j = 0; j < 4; ++j)
        bfr[j] = *(const short8*)&Bs[ks][(wn + j * 16 + fm) * 32 + quad * 8];
#pragma unroll
      for (int i = 0; i < 4; ++i)
#pragma unroll
        for (int j = 0; j < 4; ++j)
          acc[i][j] = __builtin_amdgcn_mfma_f32_16x16x32_bf16(af[i], bfr[j],
                                                              acc[i][j], 0, 0, 0);
    }
  }

#pragma unroll
  for (int i = 0; i < 4; ++i) {
    const int row0 = bm + wm + i * 16 + quad * 4;
#pragma unroll
    for (int j = 0; j < 4; ++j) {
      const int col = bn + wn + j * 16 + fm;
#pragma unroll
      for (int r = 0; r < 4; ++r)
        C[(size_t)(row0 + r) * HIDS + col] = f2bf(acc[i][j][r]);
    }
  }
}

// ---------------------------------------------------------------------------
// Output GEMM: 128(M) x 64(N) tile, BK=64, fp32 out. 512 blocks.
// ---------------------------------------------------------------------------
__global__ __launch_bounds__(256) void gemm_out_kernel(
    const ushort* __restrict__ A, const ushort* __restrict__ Bt,
    float* __restrict__ C) {
  __shared__ ushort As[2][128 * 32];
  __shared__ ushort Bs[2][64 * 32];
  const int tid = threadIdx.x;
  const int wave = tid >> 6, lane = tid & 63;
  const int fm = lane & 15, quad = lane >> 4;
  const int bm = blockIdx.y * 128, bn = blockIdx.x * 64;
  const int lrow = tid >> 2, lk8 = (tid & 3) * 8;
  const ushort* Ag = A + (size_t)(bm + lrow) * HIDS + lk8;
  const ushort* Bg = Bt + (size_t)(bn + lrow) * HIDS + lk8;
  char* A0 = (char*)&As[0][0] + tid * 16;
  char* A1 = (char*)&As[1][0] + tid * 16;
  char* B0 = (char*)&Bs[0][0] + tid * 16;
  char* B1 = (char*)&Bs[1][0] + tid * 16;

  floatx4 acc[2][4];
#pragma unroll
  for (int i = 0; i < 2; ++i)
#pragma unroll
    for (int j = 0; j < 4; ++j) acc[i][j] = (floatx4){0.f, 0.f, 0.f, 0.f};

  for (int k0 = 0; k0 < HIDS; k0 += 64) {
    __syncthreads();
    async_copy16(Ag + k0, A0);
    async_copy16(Ag + (size_t)64 * HIDS + k0, A0 + 4096);
    async_copy16(Ag + k0 + 32, A1);
    async_copy16(Ag + (size_t)64 * HIDS + k0 + 32, A1 + 4096);
    async_copy16(Bg + k0, B0);
    async_copy16(Bg + k0 + 32, B1);
    __syncthreads();

#pragma unroll
    for (int ks = 0; ks < 2; ++ks) {
      short8 af[2], bfr[4];
#pragma unroll
      for (int i = 0; i < 2; ++i)
        af[i] = *(const short8*)&As[ks][(wave * 32 + i * 16 + fm) * 32 + quad * 8];
#pragma unroll
      for (int j = 0; j < 4; ++j)
        bfr[j] = *(const short8*)&Bs[ks][(j * 16 + fm) * 32 + quad * 8];
#pragma unroll
      for (int i = 0; i < 2; ++i)
#pragma unroll
        for (int j = 0; j < 4; ++j)
          acc[i][j] = __builtin_amdgcn_mfma_f32_16x16x32_bf16(af[i], bfr[j],
                                                              acc[i][j], 0, 0, 0);
    }
  }

#pragma unroll
  for (int i = 0; i < 2; ++i) {
    const int row0 = bm + wave * 32 + i * 16 + quad * 4;
#pragma unroll
    for (int j = 0; j < 4; ++j) {
      const int col = bn + j * 16 + fm;
#pragma unroll
      for (int r = 0; r < 4; ++r)
        C[(size_t)(row0 + r) * HIDS + col] = acc[i][j][r];
    }
  }
}

#define SP 72   // ushort stride for bf16 LDS tiles (16B-aligned rows)
#define SGS 68  // float stride for Gamma tile

// ---------------------------------------------------------------------------
// sdelta: per (b,h,chunk): Gamma=cumsum(logsig16(z+bias)); Vt~=(e^-G V)^T;
//   Sdelta(bf16) = Lam . (V~^T @ K); Lam = e^{Gamma_63}.
// ---------------------------------------------------------------------------
__global__ __launch_bounds__(256) void sdelta_kernel(
    const ushort* __restrict__ k, const ushort* __restrict__ v,
    const ushort* __restrict__ zb, const float* __restrict__ bgk2,
    ushort* __restrict__ Sdelta, float* __restrict__ Lam) {
  const int bid = blockIdx.x;
  const int c = bid & 31, bh = bid >> 5;
  const int b = bh >> 4, h = bh & 15;
  const int tid = threadIdx.x;
  const int lane = tid & 63, wave = tid >> 6;
  const int fm = lane & 15, quad = lane >> 4;
  const int wm2 = (wave >> 1) * 32, wn2 = (wave & 1) * 32;

  __shared__ ushort sKt[64 * SP];
  __shared__ ushort sVt[64 * SP];
  __shared__ float sG[64 * SGS];

  const size_t base = ((size_t)b * LSEQ + (size_t)c * CHUNK) * HIDS + (size_t)h * HDIM;
  // natural partition (gate logits + bias)
  const int r = tid >> 2, c0 = (tid & 3) * 16;
  const size_t gb = base + (size_t)r * HIDS + c0;
  {
    float bias[16];
#pragma unroll
    for (int m = 0; m < 4; ++m)
      *(float4*)&bias[m * 4] = *(const float4*)(bgk2 + h * HDIM + c0 + m * 4);
    short8 z0 = *(const short8*)(zb + gb);
    short8 z1 = *(const short8*)(zb + gb + 8);
#pragma unroll
    for (int i = 0; i < 16; ++i) {
      float zz = bf2f((ushort)(i < 8 ? z0[i] : z1[i - 8])) + bias[i];
      sG[r * SGS + c0 + i] = logsig16(zz);
    }
  }
  // pair partition (K, V)
  const int pr = (tid >> 3) * 2, pc = (tid & 7) * 8;
  const size_t pb = base + (size_t)pr * HIDS + pc;
  short8 ka = *(const short8*)(k + pb);
  short8 kb2 = *(const short8*)(k + pb + HIDS);
  short8 va = *(const short8*)(v + pb);
  short8 vb2 = *(const short8*)(v + pb + HIDS);
  __syncthreads();

  // inclusive cumsum along t per v column
  const int vcol = tid & 63, qtr = tid >> 6;
  {
    float run = 0.f;
#pragma unroll
    for (int i = 0; i < 16; ++i) {
      int idx = (qtr * 16 + i) * SGS + vcol;
      run += sG[idx];
      sG[idx] = run;
    }
  }
  __syncthreads();
  float pre = 0.f;
  for (int j = 0; j < qtr; ++j) pre += sG[(j * 16 + 15) * SGS + vcol];
  __syncthreads();
#pragma unroll
  for (int i = 0; i < 16; ++i) sG[(qtr * 16 + i) * SGS + vcol] += pre;
  __syncthreads();

  // transposed tiles (ushort2 writes)
#pragma unroll
  for (int i = 0; i < 8; ++i) {
    ushort2 kk;
    kk.x = (ushort)ka[i];
    kk.y = (ushort)kb2[i];
    *(ushort2*)&sKt[(pc + i) * SP + pr] = kk;
    float Ga = sG[pr * SGS + pc + i];
    float Gb2 = sG[(pr + 1) * SGS + pc + i];
    ushort2 vv;
    vv.x = f2bf(bf2f((ushort)va[i]) * expf(-Ga));
    vv.y = f2bf(bf2f((ushort)vb2[i]) * expf(-Gb2));
    *(ushort2*)&sVt[(pc + i) * SP + pr] = vv;
  }
  __syncthreads();

  if (tid < 64)
    Lam[(size_t)(bh * NCHUNK + c) * HDIM + tid] = expf(sG[63 * SGS + tid]);

  floatx4 accD[2][2];
#pragma unroll
  for (int i = 0; i < 2; ++i)
#pragma unroll
    for (int j = 0; j < 2; ++j) accD[i][j] = (floatx4){0.f, 0.f, 0.f, 0.f};
#pragma unroll
  for (int ks = 0; ks < 2; ++ks) {
    short8 av[2], bk[2];
#pragma unroll
    for (int i = 0; i < 2; ++i)
      av[i] = *(const short8*)&sVt[(wm2 + i * 16 + fm) * SP + ks * 32 + quad * 8];
#pragma unroll
    for (int j = 0; j < 2; ++j)
      bk[j] = *(const short8*)&sKt[(wn2 + j * 16 + fm) * SP + ks * 32 + quad * 8];
#pragma unroll
    for (int i = 0; i < 2; ++i)
#pragma unroll
      for (int j = 0; j < 2; ++j)
        accD[i][j] = __builtin_amdgcn_mfma_f32_16x16x32_bf16(av[i], bk[j],
                                                             accD[i][j], 0, 0, 0);
  }
  const size_t sbase = (size_t)(bh * NCHUNK + c) * (HDIM * HDIM);
#pragma unroll
  for (int i = 0; i < 2; ++i) {
    const int m0 = wm2 + i * 16 + quad * 4;
    float lam[4];
#pragma unroll
    for (int rr = 0; rr < 4; ++rr) lam[rr] = expf(sG[63 * SGS + m0 + rr]);
#pragma unroll
    for (int j = 0; j < 2; ++j) {
      const int n = wn2 + j * 16 + fm;
#pragma unroll
      for (int rr = 0; rr < 4; ++rr)
        Sdelta[sbase + (size_t)(m0 + rr) * HDIM + n] = f2bf(accD[i][j][rr] * lam[rr]);
    }
  }
}

// ---------------------------------------------------------------------------
// state_scan: sequential over 32 chunk boundaries; 32 blocks, state in regs.
// Sdelta bf16 in, Sprev bf16 out, fp32 accumulate.
// ---------------------------------------------------------------------------
__global__ __launch_bounds__(256) void state_scan_kernel(
    const ushort* __restrict__ Sdelta, const float* __restrict__ Lam,
    ushort* __restrict__ Sprev) {
  const int bh = blockIdx.x;
  const int tid = threadIdx.x;
  float S[16];
#pragma unroll
  for (int i = 0; i < 16; ++i) S[i] = 0.f;

  float pd[16], pl[16];
  {
    const size_t base = (size_t)(bh * NCHUNK) * (HDIM * HDIM);
    const size_t lbase = (size_t)(bh * NCHUNK) * HDIM;
#pragma unroll
    for (int i = 0; i < 16; ++i) {
      int e = tid + 256 * i;
      pd[i] = bf2f(Sdelta[base + e]);
      pl[i] = Lam[lbase + (e >> 6)];
    }
  }
  for (int c = 0; c < NCHUNK; ++c) {
    float cd[16], cl[16];
#pragma unroll
    for (int i = 0; i < 16; ++i) { cd[i] = pd[i]; cl[i] = pl[i]; }
    if (c + 1 < NCHUNK) {
      const size_t base = (size_t)(bh * NCHUNK + c + 1) * (HDIM * HDIM);
      const size_t lbase = (size_t)(bh * NCHUNK + c + 1) * HDIM;
#pragma unroll
      for (int i = 0; i < 16; ++i) {
        int e = tid + 256 * i;
        pd[i] = bf2f(Sdelta[base + e]);
        pl[i] = Lam[lbase + (e >> 6)];
      }
    }
    const size_t obase = (size_t)(bh * NCHUNK + c) * (HDIM * HDIM);
#pragma unroll
    for (int i = 0; i < 16; ++i) {
      int e = tid + 256 * i;
      Sprev[obase + e] = f2bf(S[i]);
      S[i] = fmaf(S[i], cl[i], cd[i]);
    }
  }
}

// ---------------------------------------------------------------------------
// chunk_fused: att(bf16) = e^Gamma . ( tril(QK^T) @ (e^-G V) + Q @ Sprev^T )
// ---------------------------------------------------------------------------
__global__ __launch_bounds__(256) void chunk_fused_kernel(
    const ushort* __restrict__ q, const ushort* __restrict__ k,
    const ushort* __restrict__ v, const ushort* __restrict__ zb,
    const float* __restrict__ bgk2, const ushort* __restrict__ Sprev,
    ushort* __restrict__ att) {
  const int bid = blockIdx.x;
  const int c = bid & 31, bh = bid >> 5;
  const int b = bh >> 4, h = bh & 15;
  const int tid = threadIdx.x;
  const int lane = tid & 63, wave = tid >> 6;
  const int fm = lane & 15, quad = lane >> 4;
  const int wm2 = (wave >> 1) * 32, wn2 = (wave & 1) * 32;

  __shared__ ushort sQ[64 * SP];
  __shared__ ushort sK[64 * SP];
  __shared__ ushort sVt[64 * SP];
  __shared__ ushort sSp[64 * SP];
  __shared__ ushort sA[64 * SP];
  __shared__ float sG[64 * SGS];

  const size_t base = ((size_t)b * LSEQ + (size_t)c * CHUNK) * HIDS + (size_t)h * HDIM;
  const size_t sbase = (size_t)(bh * NCHUNK + c) * (HDIM * HDIM);
  // natural partition: Q, K, gate logits, Sprev
  const int r = tid >> 2, c0 = (tid & 3) * 16;
  const size_t gb = base + (size_t)r * HIDS + c0;
  *(short8*)&sQ[r * SP + c0] = *(const short8*)(q + gb);
  *(short8*)&sQ[r * SP + c0 + 8] = *(const short8*)(q + gb + 8);
  *(short8*)&sK[r * SP + c0] = *(const short8*)(k + gb);
  *(short8*)&sK[r * SP + c0 + 8] = *(const short8*)(k + gb + 8);
  {
    float bias[16];
#pragma unroll
    for (int m = 0; m < 4; ++m)
      *(float4*)&bias[m * 4] = *(const float4*)(bgk2 + h * HDIM + c0 + m * 4);
    short8 z0 = *(const short8*)(zb + gb);
    short8 z1 = *(const short8*)(zb + gb + 8);
#pragma unroll
    for (int i = 0; i < 16; ++i) {
      float zz = bf2f((ushort)(i < 8 ? z0[i] : z1[i - 8])) + bias[i];
      sG[r * SGS + c0 + i] = logsig16(zz);
    }
  }
  *(short8*)&sSp[r * SP + c0] = *(const short8*)(Sprev + sbase + (size_t)r * HDIM + c0);
  *(short8*)&sSp[r * SP + c0 + 8] =
      *(const short8*)(Sprev + sbase + (size_t)r * HDIM + c0 + 8);
  // pair partition: V
  const int pr = (tid >> 3) * 2, pc = (tid & 7) * 8;
  const size_t pb = base + (size_t)pr * HIDS + pc;
  short8 va = *(const short8*)(v + pb);
  short8 vb2 = *(const short8*)(v + pb + HIDS);
  __syncthreads();

  // cumsum Gamma
  const int vcol = tid & 63, qtr = tid >> 6;
  {
    float run = 0.f;
#pragma unroll
    for (int i = 0; i < 16; ++i) {
      int idx = (qtr * 16 + i) * SGS + vcol;
      run += sG[idx];
      sG[idx] = run;
    }
  }
  __syncthreads();
  float pre = 0.f;
  for (int j = 0; j < qtr; ++j) pre += sG[(j * 16 + 15) * SGS + vcol];
  __syncthreads();
#pragma unroll
  for (int i = 0; i < 16; ++i) sG[(qtr * 16 + i) * SGS + vcol] += pre;
  __syncthreads();

  // sVt = (e^-Gamma V)^T
#pragma unroll
  for (int i = 0; i < 8; ++i) {
    float Ga = sG[pr * SGS + pc + i];
    float Gb2 = sG[(pr + 1) * SGS + pc + i];
    ushort2 vv;
    vv.x = f2bf(bf2f((ushort)va[i]) * expf(-Ga));
    vv.y = f2bf(bf2f((ushort)vb2[i]) * expf(-Gb2));
    *(ushort2*)&sVt[(pc + i) * SP + pr] = vv;
  }
  __syncthreads();

  // scores = tril(Q K^T) -> sA (bf16)
  {
    floatx4 acc[2][2];
#pragma unroll
    for (int i = 0; i < 2; ++i)
#pragma unroll
      for (int j = 0; j < 2; ++j) acc[i][j] = (floatx4){0.f, 0.f, 0.f, 0.f};
#pragma unroll
    for (int ks = 0; ks < 2; ++ks) {
      short8 a[2], bb[2];
#pragma unroll
      for (int i = 0; i < 2; ++i)
        a[i] = *(const short8*)&sQ[(wm2 + i * 16 + fm) * SP + ks * 32 + quad * 8];
#pragma unroll
      for (int j = 0; j < 2; ++j)
        bb[j] = *(const short8*)&sK[(wn2 + j * 16 + fm) * SP + ks * 32 + quad * 8];
#pragma unroll
      for (int i = 0; i < 2; ++i)
#pragma unroll
        for (int j = 0; j < 2; ++j)
          acc[i][j] = __builtin_amdgcn_mfma_f32_16x16x32_bf16(a[i], bb[j],
                                                              acc[i][j], 0, 0, 0);
    }
#pragma unroll
    for (int i = 0; i < 2; ++i)
#pragma unroll
      for (int j = 0; j < 2; ++j) {
        const int t0 = wm2 + i * 16 + quad * 4;
        const int s = wn2 + j * 16 + fm;
#pragma unroll
        for (int rr = 0; rr < 4; ++rr) {
          float val = (s <= t0 + rr) ? acc[i][j][rr] : 0.f;
          sA[(t0 + rr) * SP + s] = f2bf(val);
        }
      }
  }
  __syncthreads();

  // att = e^G . (sA @ V~  +  Q @ Sprev^T)
  floatx4 acc[2][2];
#pragma unroll
  for (int i = 0; i < 2; ++i)
#pragma unroll
    for (int j = 0; j < 2; ++j) acc[i][j] = (floatx4){0.f, 0.f, 0.f, 0.f};
#pragma unroll
  for (int ks = 0; ks < 2; ++ks) {
    short8 aa[2], aq[2], bv[2], bs[2];
#pragma unroll
    for (int i = 0; i < 2; ++i) {
      aa[i] = *(const short8*)&sA[(wm2 + i * 16 + fm) * SP + ks * 32 + quad * 8];
      aq[i] = *(const short8*)&sQ[(wm2 + i * 16 + fm) * SP + ks * 32 + quad * 8];
    }
#pragma unroll
    for (int j = 0; j < 2; ++j) {
      bv[j] = *(const short8*)&sVt[(wn2 + j * 16 + fm) * SP + ks * 32 + quad * 8];
      bs[j] = *(const short8*)&sSp[(wn2 + j * 16 + fm) * SP + ks * 32 + quad * 8];
    }
#pragma unroll
    for (int i = 0; i < 2; ++i)
#pragma unroll
      for (int j = 0; j < 2; ++j) {
        acc[i][j] = __builtin_amdgcn_mfma_f32_16x16x32_bf16(aa[i], bv[j],
                                                            acc[i][j], 0, 0, 0);
        acc[i][j] = __builtin_amdgcn_mfma_f32_16x16x32_bf16(aq[i], bs[j],
                                                            acc[i][j], 0, 0, 0);
      }
  }
#pragma unroll
  for (int i = 0; i < 2; ++i)
#pragma unroll
    for (int j = 0; j < 2; ++j) {
      const int m0 = wm2 + i * 16 + quad * 4;
      const int n = wn2 + j * 16 + fm;
#pragma unroll
      for (int rr = 0; rr < 4; ++rr) {
        const int m = m0 + rr;
        att[base + (size_t)m * HIDS + n] =
            f2bf(acc[i][j][rr] * expf(sG[m * SGS + n]));
      }
    }
}

// ---------------------------------------------------------------------------
// y = (LayerNorm(att) * gamma + beta) * silu(g), bf16 in/out.
// ---------------------------------------------------------------------------
__global__ __launch_bounds__(256) void ln_gate_kernel(const ushort* __restrict__ att,
                                                      const ushort* __restrict__ g,
                                                      const float* __restrict__ gamma,
                                                      const float* __restrict__ beta,
                                                      ushort* __restrict__ ybf) {
  const int row = blockIdx.x;
  const int tid = threadIdx.x;
  ushort4 au = *(const ushort4*)(att + (size_t)row * HIDS + tid * 4);
  float ax = bf2f(au.x), ay = bf2f(au.y), az = bf2f(au.z), aw = bf2f(au.w);
  float s = ax + ay + az + aw;
  float ss = ax * ax + ay * ay + az * az + aw * aw;
#pragma unroll
  for (int off = 32; off; off >>= 1) {
    s += __shfl_down(s, off);
    ss += __shfl_down(ss, off);
  }
  __shared__ float rs[4], rss[4];
  const int wid = tid >> 6;
  if ((tid & 63) == 0) { rs[wid] = s; rss[wid] = ss; }
  __syncthreads();
  const float mean = (rs[0] + rs[1] + rs[2] + rs[3]) * (1.f / HIDS);
  const float ex2 = (rss[0] + rss[1] + rss[2] + rss[3]) * (1.f / HIDS);
  const float rstd = rsqrtf(ex2 - mean * mean + 1e-5f);

  float4 ga = *(const float4*)(gamma + tid * 4);
  float4 be = *(const float4*)(beta + tid * 4);
  ushort4 gu = *(const ushort4*)(g + (size_t)row * HIDS + tid * 4);
  float gx = bf2f(gu.x), gy = bf2f(gu.y), gz = bf2f(gu.z), gw = bf2f(gu.w);
  float4 o;
  o.x = ((ax - mean) * rstd * ga.x + be.x) * (gx / (1.f + expf(-gx)));
  o.y = ((ay - mean) * rstd * ga.y + be.y) * (gy / (1.f + expf(-gy)));
  o.z = ((az - mean) * rstd * ga.z + be.z) * (gz / (1.f + expf(-gz)));
  o.w = ((aw - mean) * rstd * ga.w + be.w) * (gw / (1.f + expf(-gw)));
  ushort4 ob;
  ob.x = f2bf(o.x); ob.y = f2bf(o.y); ob.z = f2bf(o.z); ob.w = f2bf(o.w);
  *(ushort4*)(ybf + (size_t)row * HIDS + tid * 4) = ob;
}

// ---------------------------------------------------------------------------
extern "C" void kernel_launch(void* const* d_in, const int* in_sizes, int n_in,
                              void* d_out, int out_size, void* d_ws, size_t ws_size,
                              hipStream_t stream) {
  const float* x     = (const float*)d_in[0];
  const float* Wq    = (const float*)d_in[1];
  const float* Wk    = (const float*)d_in[2];
  const float* Wv    = (const float*)d_in[3];
  const float* Wg    = (const float*)d_in[4];
  const float* Wgk1  = (const float*)d_in[5];
  const float* Wgk2  = (const float*)d_in[6];
  const float* bgk2  = (const float*)d_in[7];
  const float* gamma = (const float*)d_in[8];
  const float* beta  = (const float*)d_in[9];
  const float* Wout  = (const float*)d_in[10];
  float* out = (float*)d_out;

  const size_t SZ = (size_t)NROW * HIDS;  // 4M elements
  float* ws = (float*)d_ws;
  float* Lamb = ws;                         // 64K floats
  ushort* attb   = (ushort*)(ws + 65536);   // bf16 4M
  ushort* Sdelta = attb + SZ;               // bf16 4M
  ushort* Sprevb = Sdelta + SZ;             // bf16 4M
  ushort* qbf = Sprevb + SZ;
  ushort* kbf = qbf + SZ;
  ushort* vbf = kbf + SZ;
  ushort* gbf = vbf + SZ;
  ushort* zbf = gbf + SZ;                   // gate logits (bf16, pre-bias)
  ushort* xbf = zbf + SZ;
  ushort* Wtq = xbf + SZ;
  ushort* Wtk = Wtq + HIDS * HIDS;
  ushort* Wtv = Wtk + HIDS * HIDS;
  ushort* Wtg = Wtv + HIDS * HIDS;
  ushort* Wto = Wtg + HIDS * HIDS;
  ushort* Wte = Wto + HIDS * HIDS;
  ushort* ybf = vbf;  // vbf dead after chunk_fused

  cvt_x_kernel<<<SZ / 1024, 256, 0, stream>>>(x, xbf);
  transpose_w_kernel<<<dim3(16, 16, 5), 256, 0, stream>>>(
      Wq, Wk, Wv, Wg, Wout, Wtq, Wtk, Wtv, Wtg, Wto);
  weff_kernel<<<dim3(16, 16), 256, 0, stream>>>(Wgk1, Wgk2, Wte);

  proj5_kernel<<<dim3(HIDS / 128, NROW / 128, 5), 256, 0, stream>>>(
      xbf, Wtq, Wtk, Wtv, Wtg, Wte, qbf, kbf, vbf, gbf, zbf);

  sdelta_kernel<<<BBATCH * NHEAD * NCHUNK, 256, 0, stream>>>(
      kbf, vbf, zbf, bgk2, Sdelta, Lamb);
  state_scan_kernel<<<BBATCH * NHEAD, 256, 0, stream>>>(Sdelta, Lamb, Sprevb);
  chunk_fused_kernel<<<BBATCH * NHEAD * NCHUNK, 256, 0, stream>>>(
      qbf, kbf, vbf, zbf, bgk2, Sprevb, attb);

  ln_gate_kernel<<<NROW, 256, 0, stream>>>(attb, gbf, gamma, beta, ybf);
  gemm_out_kernel<<<dim3(HIDS / 64, NROW / 128), 256, 0, stream>>>(ybf, Wto, out);
}

// Round 8
// 224.680 us; speedup vs baseline: 1.2422x; 1.0698x over previous
//
#include <hip/hip_runtime.h>
#include <cstdint>
#include <cstddef>

#define HIDS 1024
#define NHEAD 16
#define HDIM 64
#define LSEQ 2048
#define BBATCH 2
#define NROW (BBATCH * LSEQ)  // 4096
#define CHUNK 64
#define NCHUNK (LSEQ / CHUNK)  // 32
#define RANK 16

typedef short short8 __attribute__((ext_vector_type(8)));
typedef float floatx4 __attribute__((ext_vector_type(4)));

__device__ __forceinline__ ushort f2bf(float f) {
  uint32_t u = __float_as_uint(f);
  uint32_t r = (u + 0x7fffu + ((u >> 16) & 1u)) >> 16;  // RNE
  return (ushort)r;
}
__device__ __forceinline__ float bf2f(ushort u) {
  return __uint_as_float(((uint32_t)u) << 16);
}
// log_sigmoid(z)/16, stable
__device__ __forceinline__ float logsig16(float z) {
  return (fminf(z, 0.f) - log1pf(expf(-fabsf(z)))) * (1.f / 16.f);
}

__device__ __forceinline__ void async_copy16(const void* g, void* l) {
  __builtin_amdgcn_global_load_lds(
      (const __attribute__((address_space(1))) void*)g,
      (__attribute__((address_space(3))) void*)l, 16, 0, 0);
}

// ---------------------------------------------------------------------------
// prep: fused cvt_x (blocks 0..4095), transpose_w (4096..5375, 5 x 256),
//       weff (5376..5631).  One launch instead of three.
// ---------------------------------------------------------------------------
__global__ __launch_bounds__(256) void prep_kernel(
    const float* __restrict__ x, ushort* __restrict__ xbf,
    const float* __restrict__ W0, const float* __restrict__ W1,
    const float* __restrict__ W2, const float* __restrict__ W3,
    const float* __restrict__ W4, ushort* __restrict__ T0,
    ushort* __restrict__ T1, ushort* __restrict__ T2, ushort* __restrict__ T3,
    ushort* __restrict__ T4, const float* __restrict__ Wgk1,
    const float* __restrict__ Wgk2, ushort* __restrict__ Wte) {
  __shared__ float sbuf[64 * 65];
  const int bid = blockIdx.x;
  const int tid = threadIdx.x;

  if (bid < 4096) {  // ---- cvt_x: 4 fp32 -> bf16 per thread
    const int i = bid * 256 + tid;
    float4 f = *(const float4*)(x + (size_t)i * 4);
    ushort4 o;
    o.x = f2bf(f.x); o.y = f2bf(f.y); o.z = f2bf(f.z); o.w = f2bf(f.w);
    *(ushort4*)(xbf + (size_t)i * 4) = o;
  } else if (bid < 5376) {  // ---- transpose_w
    const int w = bid - 4096;
    const int z = w >> 8, rem = w & 255;
    const float* W = (z == 0) ? W0 : (z == 1) ? W1 : (z == 2) ? W2
                     : (z == 3) ? W3 : W4;
    ushort* T = (z == 0) ? T0 : (z == 1) ? T1 : (z == 2) ? T2
                : (z == 3) ? T3 : T4;
    const int k0 = (rem >> 4) * 64, n0 = (rem & 15) * 64;
    const int r = tid >> 2, c4 = (tid & 3) * 16;
#pragma unroll
    for (int i = 0; i < 4; ++i) {
      float4 f = *(const float4*)(W + (size_t)(k0 + r) * HIDS + n0 + c4 + i * 4);
      sbuf[r * 65 + c4 + i * 4 + 0] = f.x;
      sbuf[r * 65 + c4 + i * 4 + 1] = f.y;
      sbuf[r * 65 + c4 + i * 4 + 2] = f.z;
      sbuf[r * 65 + c4 + i * 4 + 3] = f.w;
    }
    __syncthreads();
    const int n = tid >> 2, kc = (tid & 3) * 16;
#pragma unroll
    for (int i = 0; i < 4; ++i) {
      int kk = kc + i * 4;
      ushort4 o;
      o.x = f2bf(sbuf[(kk + 0) * 65 + n]);
      o.y = f2bf(sbuf[(kk + 1) * 65 + n]);
      o.z = f2bf(sbuf[(kk + 2) * 65 + n]);
      o.w = f2bf(sbuf[(kk + 3) * 65 + n]);
      *(ushort4*)(T + (size_t)(n0 + n) * HIDS + k0 + kk) = o;
    }
  } else {  // ---- weff: Wefft[n][k] = sum_r Wgk1[k][r]*Wgk2[r][n]
    const int rem = bid - 5376;
    const int n0 = (rem & 15) * 64, k0 = (rem >> 4) * 64;
    float* sW1 = sbuf;            // [64][17]
    float* sW2 = sbuf + 64 * 17;  // [16][65]
    {
      const int kl = tid >> 2, r4 = (tid & 3) * 4;
      float4 f = *(const float4*)(Wgk1 + (size_t)(k0 + kl) * RANK + r4);
      sW1[kl * 17 + r4] = f.x; sW1[kl * 17 + r4 + 1] = f.y;
      sW1[kl * 17 + r4 + 2] = f.z; sW1[kl * 17 + r4 + 3] = f.w;
      const int rr = tid >> 4, nl = (tid & 15) * 4;
      float4 g = *(const float4*)(Wgk2 + (size_t)rr * HIDS + n0 + nl);
      sW2[rr * 65 + nl] = g.x; sW2[rr * 65 + nl + 1] = g.y;
      sW2[rr * 65 + nl + 2] = g.z; sW2[rr * 65 + nl + 3] = g.w;
    }
    __syncthreads();
    const int nl = tid & 63, kq = (tid >> 6) * 16;
    float w2[16];
#pragma unroll
    for (int r = 0; r < 16; ++r) w2[r] = sW2[r * 65 + nl];
    ushort ob[16];
#pragma unroll
    for (int i = 0; i < 16; ++i) {
      float s = 0.f;
#pragma unroll
      for (int r = 0; r < 16; ++r) s = fmaf(sW1[(kq + i) * 17 + r], w2[r], s);
      ob[i] = f2bf(s);
    }
#pragma unroll
    for (int i = 0; i < 2; ++i)
      *(short8*)(Wte + (size_t)(n0 + nl) * HIDS + k0 + kq + i * 8) =
          *(short8*)&ob[i * 8];
  }
}

// ---------------------------------------------------------------------------
// proj5: 128x128 bf16 MFMA GEMM, BK=64, uniform bf16 epilogue (5 slices).
// ---------------------------------------------------------------------------
__global__ __launch_bounds__(256) void proj5_kernel(
    const ushort* __restrict__ xbf, const ushort* __restrict__ Wtq,
    const ushort* __restrict__ Wtk, const ushort* __restrict__ Wtv,
    const ushort* __restrict__ Wtg, const ushort* __restrict__ Wte,
    ushort* __restrict__ qb, ushort* __restrict__ kb, ushort* __restrict__ vb,
    ushort* __restrict__ gb, ushort* __restrict__ zb) {
  const int z = blockIdx.z;
  const ushort* Bt = (z == 0) ? Wtq : (z == 1) ? Wtk : (z == 2) ? Wtv
                     : (z == 3) ? Wtg : Wte;
  ushort* C = (z == 0) ? qb : (z == 1) ? kb : (z == 2) ? vb : (z == 3) ? gb : zb;
  __shared__ ushort As[2][128 * 32];
  __shared__ ushort Bs[2][128 * 32];
  const int tid = threadIdx.x;
  const int wave = tid >> 6, lane = tid & 63;
  const int wm = (wave >> 1) * 64, wn = (wave & 1) * 64;
  const int bm = blockIdx.y * 128, bn = blockIdx.x * 128;
  const int lrow = tid >> 2, lk8 = (tid & 3) * 8;
  const ushort* Ag = xbf + (size_t)(bm + lrow) * HIDS + lk8;
  const ushort* Bg = Bt + (size_t)(bn + lrow) * HIDS + lk8;
  char* A0 = (char*)&As[0][0] + tid * 16;
  char* A1 = (char*)&As[1][0] + tid * 16;
  char* B0 = (char*)&Bs[0][0] + tid * 16;
  char* B1 = (char*)&Bs[1][0] + tid * 16;

  floatx4 acc[4][4];
#pragma unroll
  for (int i = 0; i < 4; ++i)
#pragma unroll
    for (int j = 0; j < 4; ++j) acc[i][j] = (floatx4){0.f, 0.f, 0.f, 0.f};

  const int fm = lane & 15, quad = lane >> 4;

  for (int k0 = 0; k0 < HIDS; k0 += 64) {
    __syncthreads();
    async_copy16(Ag + k0, A0);
    async_copy16(Ag + (size_t)64 * HIDS + k0, A0 + 4096);
    async_copy16(Ag + k0 + 32, A1);
    async_copy16(Ag + (size_t)64 * HIDS + k0 + 32, A1 + 4096);
    async_copy16(Bg + k0, B0);
    async_copy16(Bg + (size_t)64 * HIDS + k0, B0 + 4096);
    async_copy16(Bg + k0 + 32, B1);
    async_copy16(Bg + (size_t)64 * HIDS + k0 + 32, B1 + 4096);
    __syncthreads();

#pragma unroll
    for (int ks = 0; ks < 2; ++ks) {
      short8 af[4], bfr[4];
#pragma unroll
      for (int i = 0; i < 4; ++i)
        af[i] = *(const short8*)&As[ks][(wm + i * 16 + fm) * 32 + quad * 8];
#pragma unroll
      for (int j = 0; j < 4; ++j)
        bfr[j] = *(const short8*)&Bs[ks][(wn + j * 16 + fm) * 32 + quad * 8];
#pragma unroll
      for (int i = 0; i < 4; ++i)
#pragma unroll
        for (int j = 0; j < 4; ++j)
          acc[i][j] = __builtin_amdgcn_mfma_f32_16x16x32_bf16(af[i], bfr[j],
                                                              acc[i][j], 0, 0, 0);
    }
  }

#pragma unroll
  for (int i = 0; i < 4; ++i) {
    const int row0 = bm + wm + i * 16 + quad * 4;
#pragma unroll
    for (int j = 0; j < 4; ++j) {
      const int col = bn + wn + j * 16 + fm;
#pragma unroll
      for (int r = 0; r < 4; ++r)
        C[(size_t)(row0 + r) * HIDS + col] = f2bf(acc[i][j][r]);
    }
  }
}

// ---------------------------------------------------------------------------
// Output GEMM: 128(M) x 64(N) tile, BK=64, fp32 out. 512 blocks.
// ---------------------------------------------------------------------------
__global__ __launch_bounds__(256) void gemm_out_kernel(
    const ushort* __restrict__ A, const ushort* __restrict__ Bt,
    float* __restrict__ C) {
  __shared__ ushort As[2][128 * 32];
  __shared__ ushort Bs[2][64 * 32];
  const int tid = threadIdx.x;
  const int wave = tid >> 6, lane = tid & 63;
  const int fm = lane & 15, quad = lane >> 4;
  const int bm = blockIdx.y * 128, bn = blockIdx.x * 64;
  const int lrow = tid >> 2, lk8 = (tid & 3) * 8;
  const ushort* Ag = A + (size_t)(bm + lrow) * HIDS + lk8;
  const ushort* Bg = Bt + (size_t)(bn + lrow) * HIDS + lk8;
  char* A0 = (char*)&As[0][0] + tid * 16;
  char* A1 = (char*)&As[1][0] + tid * 16;
  char* B0 = (char*)&Bs[0][0] + tid * 16;
  char* B1 = (char*)&Bs[1][0] + tid * 16;

  floatx4 acc[2][4];
#pragma unroll
  for (int i = 0; i < 2; ++i)
#pragma unroll
    for (int j = 0; j < 4; ++j) acc[i][j] = (floatx4){0.f, 0.f, 0.f, 0.f};

  for (int k0 = 0; k0 < HIDS; k0 += 64) {
    __syncthreads();
    async_copy16(Ag + k0, A0);
    async_copy16(Ag + (size_t)64 * HIDS + k0, A0 + 4096);
    async_copy16(Ag + k0 + 32, A1);
    async_copy16(Ag + (size_t)64 * HIDS + k0 + 32, A1 + 4096);
    async_copy16(Bg + k0, B0);
    async_copy16(Bg + k0 + 32, B1);
    __syncthreads();

#pragma unroll
    for (int ks = 0; ks < 2; ++ks) {
      short8 af[2], bfr[4];
#pragma unroll
      for (int i = 0; i < 2; ++i)
        af[i] = *(const short8*)&As[ks][(wave * 32 + i * 16 + fm) * 32 + quad * 8];
#pragma unroll
      for (int j = 0; j < 4; ++j)
        bfr[j] = *(const short8*)&Bs[ks][(j * 16 + fm) * 32 + quad * 8];
#pragma unroll
      for (int i = 0; i < 2; ++i)
#pragma unroll
        for (int j = 0; j < 4; ++j)
          acc[i][j] = __builtin_amdgcn_mfma_f32_16x16x32_bf16(af[i], bfr[j],
                                                              acc[i][j], 0, 0, 0);
    }
  }

#pragma unroll
  for (int i = 0; i < 2; ++i) {
    const int row0 = bm + wave * 32 + i * 16 + quad * 4;
#pragma unroll
    for (int j = 0; j < 4; ++j) {
      const int col = bn + j * 16 + fm;
#pragma unroll
      for (int r = 0; r < 4; ++r)
        C[(size_t)(row0 + r) * HIDS + col] = acc[i][j][r];
    }
  }
}

#define SP 72   // ushort stride for bf16 LDS tiles (16B-aligned rows)
#define SGS 68  // float stride for Gamma tile

// ---------------------------------------------------------------------------
// sdelta: per (b,h,chunk): Gamma=cumsum(logsig16(z+bias)); Vt~=(e^-G V)^T;
//   Sdelta(bf16) = Lam . (V~^T @ K); Lam = e^{Gamma_63}.
// ---------------------------------------------------------------------------
__global__ __launch_bounds__(256) void sdelta_kernel(
    const ushort* __restrict__ k, const ushort* __restrict__ v,
    const ushort* __restrict__ zb, const float* __restrict__ bgk2,
    ushort* __restrict__ Sdelta, float* __restrict__ Lam) {
  const int bid = blockIdx.x;
  const int c = bid & 31, bh = bid >> 5;
  const int b = bh >> 4, h = bh & 15;
  const int tid = threadIdx.x;
  const int lane = tid & 63, wave = tid >> 6;
  const int fm = lane & 15, quad = lane >> 4;
  const int wm2 = (wave >> 1) * 32, wn2 = (wave & 1) * 32;

  __shared__ ushort sKt[64 * SP];
  __shared__ ushort sVt[64 * SP];
  __shared__ float sG[64 * SGS];

  const size_t base = ((size_t)b * LSEQ + (size_t)c * CHUNK) * HIDS + (size_t)h * HDIM;
  // natural partition (gate logits + bias)
  const int r = tid >> 2, c0 = (tid & 3) * 16;
  const size_t gb = base + (size_t)r * HIDS + c0;
  {
    float bias[16];
#pragma unroll
    for (int m = 0; m < 4; ++m)
      *(float4*)&bias[m * 4] = *(const float4*)(bgk2 + h * HDIM + c0 + m * 4);
    short8 z0 = *(const short8*)(zb + gb);
    short8 z1 = *(const short8*)(zb + gb + 8);
#pragma unroll
    for (int i = 0; i < 16; ++i) {
      float zz = bf2f((ushort)(i < 8 ? z0[i] : z1[i - 8])) + bias[i];
      sG[r * SGS + c0 + i] = logsig16(zz);
    }
  }
  // pair partition (K, V)
  const int pr = (tid >> 3) * 2, pc = (tid & 7) * 8;
  const size_t pb = base + (size_t)pr * HIDS + pc;
  short8 ka = *(const short8*)(k + pb);
  short8 kb2 = *(const short8*)(k + pb + HIDS);
  short8 va = *(const short8*)(v + pb);
  short8 vb2 = *(const short8*)(v + pb + HIDS);
  __syncthreads();

  // inclusive cumsum along t per v column
  const int vcol = tid & 63, qtr = tid >> 6;
  {
    float run = 0.f;
#pragma unroll
    for (int i = 0; i < 16; ++i) {
      int idx = (qtr * 16 + i) * SGS + vcol;
      run += sG[idx];
      sG[idx] = run;
    }
  }
  __syncthreads();
  float pre = 0.f;
  for (int j = 0; j < qtr; ++j) pre += sG[(j * 16 + 15) * SGS + vcol];
  __syncthreads();
#pragma unroll
  for (int i = 0; i < 16; ++i) sG[(qtr * 16 + i) * SGS + vcol] += pre;
  __syncthreads();

  // transposed tiles (ushort2 writes)
#pragma unroll
  for (int i = 0; i < 8; ++i) {
    ushort2 kk;
    kk.x = (ushort)ka[i];
    kk.y = (ushort)kb2[i];
    *(ushort2*)&sKt[(pc + i) * SP + pr] = kk;
    float Ga = sG[pr * SGS + pc + i];
    float Gb2 = sG[(pr + 1) * SGS + pc + i];
    ushort2 vv;
    vv.x = f2bf(bf2f((ushort)va[i]) * expf(-Ga));
    vv.y = f2bf(bf2f((ushort)vb2[i]) * expf(-Gb2));
    *(ushort2*)&sVt[(pc + i) * SP + pr] = vv;
  }
  __syncthreads();

  if (tid < 64)
    Lam[(size_t)(bh * NCHUNK + c) * HDIM + tid] = expf(sG[63 * SGS + tid]);

  floatx4 accD[2][2];
#pragma unroll
  for (int i = 0; i < 2; ++i)
#pragma unroll
    for (int j = 0; j < 2; ++j) accD[i][j] = (floatx4){0.f, 0.f, 0.f, 0.f};
#pragma unroll
  for (int ks = 0; ks < 2; ++ks) {
    short8 av[2], bk[2];
#pragma unroll
    for (int i = 0; i < 2; ++i)
      av[i] = *(const short8*)&sVt[(wm2 + i * 16 + fm) * SP + ks * 32 + quad * 8];
#pragma unroll
    for (int j = 0; j < 2; ++j)
      bk[j] = *(const short8*)&sKt[(wn2 + j * 16 + fm) * SP + ks * 32 + quad * 8];
#pragma unroll
    for (int i = 0; i < 2; ++i)
#pragma unroll
      for (int j = 0; j < 2; ++j)
        accD[i][j] = __builtin_amdgcn_mfma_f32_16x16x32_bf16(av[i], bk[j],
                                                             accD[i][j], 0, 0, 0);
  }
  const size_t sbase = (size_t)(bh * NCHUNK + c) * (HDIM * HDIM);
#pragma unroll
  for (int i = 0; i < 2; ++i) {
    const int m0 = wm2 + i * 16 + quad * 4;
    float lam[4];
#pragma unroll
    for (int rr = 0; rr < 4; ++rr) lam[rr] = expf(sG[63 * SGS + m0 + rr]);
#pragma unroll
    for (int j = 0; j < 2; ++j) {
      const int n = wn2 + j * 16 + fm;
#pragma unroll
      for (int rr = 0; rr < 4; ++rr)
        Sdelta[sbase + (size_t)(m0 + rr) * HDIM + n] = f2bf(accD[i][j][rr] * lam[rr]);
    }
  }
}

// ---------------------------------------------------------------------------
// state_scan: elementwise-parallel over 4096 state slots; 256 blocks
// (8 slices x 32 bh), 2 elems/thread, fp32 accumulate, bf16 I/O.
// ---------------------------------------------------------------------------
__global__ __launch_bounds__(256) void state_scan_kernel(
    const ushort* __restrict__ Sdelta, const float* __restrict__ Lam,
    ushort* __restrict__ Sprev) {
  const int bh = blockIdx.x >> 3;
  const int sl = blockIdx.x & 7;
  const int tid = threadIdx.x;
  const int e0 = sl * 512 + tid;  // this thread owns e0 and e0+256
  float S0 = 0.f, S1 = 0.f;

  size_t base = (size_t)(bh * NCHUNK) * (HDIM * HDIM);
  size_t lbase = (size_t)(bh * NCHUNK) * HDIM;
  float pd0 = bf2f(Sdelta[base + e0]);
  float pd1 = bf2f(Sdelta[base + e0 + 256]);
  float pl0 = Lam[lbase + (e0 >> 6)];
  float pl1 = Lam[lbase + ((e0 + 256) >> 6)];

  for (int c = 0; c < NCHUNK; ++c) {
    float cd0 = pd0, cd1 = pd1, cl0 = pl0, cl1 = pl1;
    if (c + 1 < NCHUNK) {
      size_t nb = (size_t)(bh * NCHUNK + c + 1) * (HDIM * HDIM);
      size_t nl = (size_t)(bh * NCHUNK + c + 1) * HDIM;
      pd0 = bf2f(Sdelta[nb + e0]);
      pd1 = bf2f(Sdelta[nb + e0 + 256]);
      pl0 = Lam[nl + (e0 >> 6)];
      pl1 = Lam[nl + ((e0 + 256) >> 6)];
    }
    size_t ob = (size_t)(bh * NCHUNK + c) * (HDIM * HDIM);
    Sprev[ob + e0] = f2bf(S0);
    Sprev[ob + e0 + 256] = f2bf(S1);
    S0 = fmaf(S0, cl0, cd0);
    S1 = fmaf(S1, cl1, cd1);
  }
}

// ---------------------------------------------------------------------------
// chunk_fused: att(bf16) = e^Gamma . ( tril(QK^T) @ (e^-G V) + Q @ Sprev^T )
// sSp aliases sK (K dead after scores) -> LDS 53 KB -> 3 blocks/CU.
// ---------------------------------------------------------------------------
__global__ __launch_bounds__(256) void chunk_fused_kernel(
    const ushort* __restrict__ q, const ushort* __restrict__ k,
    const ushort* __restrict__ v, const ushort* __restrict__ zb,
    const float* __restrict__ bgk2, const ushort* __restrict__ Sprev,
    ushort* __restrict__ att) {
  const int bid = blockIdx.x;
  const int c = bid & 31, bh = bid >> 5;
  const int b = bh >> 4, h = bh & 15;
  const int tid = threadIdx.x;
  const int lane = tid & 63, wave = tid >> 6;
  const int fm = lane & 15, quad = lane >> 4;
  const int wm2 = (wave >> 1) * 32, wn2 = (wave & 1) * 32;

  __shared__ ushort sQ[64 * SP];
  __shared__ ushort sK[64 * SP];   // later reused as sSp
  __shared__ ushort sVt[64 * SP];
  __shared__ ushort sA[64 * SP];
  __shared__ float sG[64 * SGS];
  ushort* sSp = sK;

  const size_t base = ((size_t)b * LSEQ + (size_t)c * CHUNK) * HIDS + (size_t)h * HDIM;
  const size_t sbase = (size_t)(bh * NCHUNK + c) * (HDIM * HDIM);
  // natural partition: Q, K, gate logits; preload Sprev into regs
  const int r = tid >> 2, c0 = (tid & 3) * 16;
  const size_t gb = base + (size_t)r * HIDS + c0;
  short8 sp0 = *(const short8*)(Sprev + sbase + (size_t)r * HDIM + c0);
  short8 sp1 = *(const short8*)(Sprev + sbase + (size_t)r * HDIM + c0 + 8);
  *(short8*)&sQ[r * SP + c0] = *(const short8*)(q + gb);
  *(short8*)&sQ[r * SP + c0 + 8] = *(const short8*)(q + gb + 8);
  *(short8*)&sK[r * SP + c0] = *(const short8*)(k + gb);
  *(short8*)&sK[r * SP + c0 + 8] = *(const short8*)(k + gb + 8);
  {
    float bias[16];
#pragma unroll
    for (int m = 0; m < 4; ++m)
      *(float4*)&bias[m * 4] = *(const float4*)(bgk2 + h * HDIM + c0 + m * 4);
    short8 z0 = *(const short8*)(zb + gb);
    short8 z1 = *(const short8*)(zb + gb + 8);
#pragma unroll
    for (int i = 0; i < 16; ++i) {
      float zz = bf2f((ushort)(i < 8 ? z0[i] : z1[i - 8])) + bias[i];
      sG[r * SGS + c0 + i] = logsig16(zz);
    }
  }
  // pair partition: V
  const int pr = (tid >> 3) * 2, pc = (tid & 7) * 8;
  const size_t pb = base + (size_t)pr * HIDS + pc;
  short8 va = *(const short8*)(v + pb);
  short8 vb2 = *(const short8*)(v + pb + HIDS);
  __syncthreads();

  // cumsum Gamma
  const int vcol = tid & 63, qtr = tid >> 6;
  {
    float run = 0.f;
#pragma unroll
    for (int i = 0; i < 16; ++i) {
      int idx = (qtr * 16 + i) * SGS + vcol;
      run += sG[idx];
      sG[idx] = run;
    }
  }
  __syncthreads();
  float pre = 0.f;
  for (int j = 0; j < qtr; ++j) pre += sG[(j * 16 + 15) * SGS + vcol];
  __syncthreads();
#pragma unroll
  for (int i = 0; i < 16; ++i) sG[(qtr * 16 + i) * SGS + vcol] += pre;
  __syncthreads();

  // sVt = (e^-Gamma V)^T
#pragma unroll
  for (int i = 0; i < 8; ++i) {
    float Ga = sG[pr * SGS + pc + i];
    float Gb2 = sG[(pr + 1) * SGS + pc + i];
    ushort2 vv;
    vv.x = f2bf(bf2f((ushort)va[i]) * expf(-Ga));
    vv.y = f2bf(bf2f((ushort)vb2[i]) * expf(-Gb2));
    *(ushort2*)&sVt[(pc + i) * SP + pr] = vv;
  }
  __syncthreads();

  // scores = tril(Q K^T) (reads sQ, sK)
  floatx4 accS[2][2];
#pragma unroll
  for (int i = 0; i < 2; ++i)
#pragma unroll
    for (int j = 0; j < 2; ++j) accS[i][j] = (floatx4){0.f, 0.f, 0.f, 0.f};
#pragma unroll
  for (int ks = 0; ks < 2; ++ks) {
    short8 a[2], bb[2];
#pragma unroll
    for (int i = 0; i < 2; ++i)
      a[i] = *(const short8*)&sQ[(wm2 + i * 16 + fm) * SP + ks * 32 + quad * 8];
#pragma unroll
    for (int j = 0; j < 2; ++j)
      bb[j] = *(const short8*)&sK[(wn2 + j * 16 + fm) * SP + ks * 32 + quad * 8];
#pragma unroll
    for (int i = 0; i < 2; ++i)
#pragma unroll
      for (int j = 0; j < 2; ++j)
        accS[i][j] = __builtin_amdgcn_mfma_f32_16x16x32_bf16(a[i], bb[j],
                                                             accS[i][j], 0, 0, 0);
  }
  __syncthreads();  // all waves done reading sK

  // write sA (tril) and sSp (into sK space)
#pragma unroll
  for (int i = 0; i < 2; ++i)
#pragma unroll
    for (int j = 0; j < 2; ++j) {
      const int t0 = wm2 + i * 16 + quad * 4;
      const int s = wn2 + j * 16 + fm;
#pragma unroll
      for (int rr = 0; rr < 4; ++rr) {
        float val = (s <= t0 + rr) ? accS[i][j][rr] : 0.f;
        sA[(t0 + rr) * SP + s] = f2bf(val);
      }
    }
  *(short8*)&sSp[r * SP + c0] = sp0;
  *(short8*)&sSp[r * SP + c0 + 8] = sp1;
  __syncthreads();

  // att = e^G . (sA @ V~  +  Q @ Sprev^T)
  floatx4 acc[2][2];
#pragma unroll
  for (int i = 0; i < 2; ++i)
#pragma unroll
    for (int j = 0; j < 2; ++j) acc[i][j] = (floatx4){0.f, 0.f, 0.f, 0.f};
#pragma unroll
  for (int ks = 0; ks < 2; ++ks) {
    short8 aa[2], aq[2], bv[2], bs[2];
#pragma unroll
    for (int i = 0; i < 2; ++i) {
      aa[i] = *(const short8*)&sA[(wm2 + i * 16 + fm) * SP + ks * 32 + quad * 8];
      aq[i] = *(const short8*)&sQ[(wm2 + i * 16 + fm) * SP + ks * 32 + quad * 8];
    }
#pragma unroll
    for (int j = 0; j < 2; ++j) {
      bv[j] = *(const short8*)&sVt[(wn2 + j * 16 + fm) * SP + ks * 32 + quad * 8];
      bs[j] = *(const short8*)&sSp[(wn2 + j * 16 + fm) * SP + ks * 32 + quad * 8];
    }
#pragma unroll
    for (int i = 0; i < 2; ++i)
#pragma unroll
      for (int j = 0; j < 2; ++j) {
        acc[i][j] = __builtin_amdgcn_mfma_f32_16x16x32_bf16(aa[i], bv[j],
                                                            acc[i][j], 0, 0, 0);
        acc[i][j] = __builtin_amdgcn_mfma_f32_16x16x32_bf16(aq[i], bs[j],
                                                            acc[i][j], 0, 0, 0);
      }
  }
#pragma unroll
  for (int i = 0; i < 2; ++i)
#pragma unroll
    for (int j = 0; j < 2; ++j) {
      const int m0 = wm2 + i * 16 + quad * 4;
      const int n = wn2 + j * 16 + fm;
#pragma unroll
      for (int rr = 0; rr < 4; ++rr) {
        const int m = m0 + rr;
        att[base + (size_t)m * HIDS + n] =
            f2bf(acc[i][j][rr] * expf(sG[m * SGS + n]));
      }
    }
}

// ---------------------------------------------------------------------------
// y = (LayerNorm(att) * gamma + beta) * silu(g), bf16 in/out.
// ---------------------------------------------------------------------------
__global__ __launch_bounds__(256) void ln_gate_kernel(const ushort* __restrict__ att,
                                                      const ushort* __restrict__ g,
                                                      const float* __restrict__ gamma,
                                                      const float* __restrict__ beta,
                                                      ushort* __restrict__ ybf) {
  const int row = blockIdx.x;
  const int tid = threadIdx.x;
  ushort4 au = *(const ushort4*)(att + (size_t)row * HIDS + tid * 4);
  float ax = bf2f(au.x), ay = bf2f(au.y), az = bf2f(au.z), aw = bf2f(au.w);
  float s = ax + ay + az + aw;
  float ss = ax * ax + ay * ay + az * az + aw * aw;
#pragma unroll
  for (int off = 32; off; off >>= 1) {
    s += __shfl_down(s, off);
    ss += __shfl_down(ss, off);
  }
  __shared__ float rs[4], rss[4];
  const int wid = tid >> 6;
  if ((tid & 63) == 0) { rs[wid] = s; rss[wid] = ss; }
  __syncthreads();
  const float mean = (rs[0] + rs[1] + rs[2] + rs[3]) * (1.f / HIDS);
  const float ex2 = (rss[0] + rss[1] + rss[2] + rss[3]) * (1.f / HIDS);
  const float rstd = rsqrtf(ex2 - mean * mean + 1e-5f);

  float4 ga = *(const float4*)(gamma + tid * 4);
  float4 be = *(const float4*)(beta + tid * 4);
  ushort4 gu = *(const ushort4*)(g + (size_t)row * HIDS + tid * 4);
  float gx = bf2f(gu.x), gy = bf2f(gu.y), gz = bf2f(gu.z), gw = bf2f(gu.w);
  float4 o;
  o.x = ((ax - mean) * rstd * ga.x + be.x) * (gx / (1.f + expf(-gx)));
  o.y = ((ay - mean) * rstd * ga.y + be.y) * (gy / (1.f + expf(-gy)));
  o.z = ((az - mean) * rstd * ga.z + be.z) * (gz / (1.f + expf(-gz)));
  o.w = ((aw - mean) * rstd * ga.w + be.w) * (gw / (1.f + expf(-gw)));
  ushort4 ob;
  ob.x = f2bf(o.x); ob.y = f2bf(o.y); ob.z = f2bf(o.z); ob.w = f2bf(o.w);
  *(ushort4*)(ybf + (size_t)row * HIDS + tid * 4) = ob;
}

// ---------------------------------------------------------------------------
extern "C" void kernel_launch(void* const* d_in, const int* in_sizes, int n_in,
                              void* d_out, int out_size, void* d_ws, size_t ws_size,
                              hipStream_t stream) {
  const float* x     = (const float*)d_in[0];
  const float* Wq    = (const float*)d_in[1];
  const float* Wk    = (const float*)d_in[2];
  const float* Wv    = (const float*)d_in[3];
  const float* Wg    = (const float*)d_in[4];
  const float* Wgk1  = (const float*)d_in[5];
  const float* Wgk2  = (const float*)d_in[6];
  const float* bgk2  = (const float*)d_in[7];
  const float* gamma = (const float*)d_in[8];
  const float* beta  = (const float*)d_in[9];
  const float* Wout  = (const float*)d_in[10];
  float* out = (float*)d_out;

  const size_t SZ = (size_t)NROW * HIDS;  // 4M elements
  float* ws = (float*)d_ws;
  float* Lamb = ws;                         // 64K floats
  ushort* attb   = (ushort*)(ws + 65536);   // bf16 4M
  ushort* Sdelta = attb + SZ;               // bf16 4M
  ushort* Sprevb = Sdelta + SZ;             // bf16 4M
  ushort* qbf = Sprevb + SZ;
  ushort* kbf = qbf + SZ;
  ushort* vbf = kbf + SZ;
  ushort* gbf = vbf + SZ;
  ushort* zbf = gbf + SZ;                   // gate logits (bf16, pre-bias)
  ushort* xbf = zbf + SZ;
  ushort* Wtq = xbf + SZ;
  ushort* Wtk = Wtq + HIDS * HIDS;
  ushort* Wtv = Wtk + HIDS * HIDS;
  ushort* Wtg = Wtv + HIDS * HIDS;
  ushort* Wto = Wtg + HIDS * HIDS;
  ushort* Wte = Wto + HIDS * HIDS;
  ushort* ybf = vbf;  // vbf dead after chunk_fused

  prep_kernel<<<4096 + 1280 + 256, 256, 0, stream>>>(
      x, xbf, Wq, Wk, Wv, Wg, Wout, Wtq, Wtk, Wtv, Wtg, Wto, Wgk1, Wgk2, Wte);

  proj5_kernel<<<dim3(HIDS / 128, NROW / 128, 5), 256, 0, stream>>>(
      xbf, Wtq, Wtk, Wtv, Wtg, Wte, qbf, kbf, vbf, gbf, zbf);

  sdelta_kernel<<<BBATCH * NHEAD * NCHUNK, 256, 0, stream>>>(
      kbf, vbf, zbf, bgk2, Sdelta, Lamb);
  state_scan_kernel<<<256, 256, 0, stream>>>(Sdelta, Lamb, Sprevb);
  chunk_fused_kernel<<<BBATCH * NHEAD * NCHUNK, 256, 0, stream>>>(
      qbf, kbf, vbf, zbf, bgk2, Sprevb, attb);

  ln_gate_kernel<<<NROW, 256, 0, stream>>>(attb, gbf, gamma, beta, ybf);
  gemm_out_kernel<<<dim3(HIDS / 64, NROW / 128), 256, 0, stream>>>(ybf, Wto, out);
}

// Round 9
// 212.707 us; speedup vs baseline: 1.3121x; 1.0563x over previous
//
#include <hip/hip_runtime.h>
#include <cstdint>
#include <cstddef>

#define HIDS 1024
#define NHEAD 16
#define HDIM 64
#define LSEQ 2048
#define BBATCH 2
#define NROW (BBATCH * LSEQ)  // 4096
#define CHUNK 64
#define NCHUNK (LSEQ / CHUNK)  // 32
#define RANK 16

typedef short short8 __attribute__((ext_vector_type(8)));
typedef float floatx4 __attribute__((ext_vector_type(4)));

__device__ __forceinline__ ushort f2bf(float f) {
  uint32_t u = __float_as_uint(f);
  uint32_t r = (u + 0x7fffu + ((u >> 16) & 1u)) >> 16;  // RNE
  return (ushort)r;
}
__device__ __forceinline__ float bf2f(ushort u) {
  return __uint_as_float(((uint32_t)u) << 16);
}
// log_sigmoid(z)/16, stable
__device__ __forceinline__ float logsig16(float z) {
  return (fminf(z, 0.f) - log1pf(expf(-fabsf(z)))) * (1.f / 16.f);
}

__device__ __forceinline__ void async_copy16(const void* g, void* l) {
  __builtin_amdgcn_global_load_lds(
      (const __attribute__((address_space(1))) void*)g,
      (__attribute__((address_space(3))) void*)l, 16, 0, 0);
}

// ---------------------------------------------------------------------------
// prep: fused cvt_x (blocks 0..4095), transpose_w (4096..5375, 5 x 256),
//       weff (5376..5631).
// ---------------------------------------------------------------------------
__global__ __launch_bounds__(256) void prep_kernel(
    const float* __restrict__ x, ushort* __restrict__ xbf,
    const float* __restrict__ W0, const float* __restrict__ W1,
    const float* __restrict__ W2, const float* __restrict__ W3,
    const float* __restrict__ W4, ushort* __restrict__ T0,
    ushort* __restrict__ T1, ushort* __restrict__ T2, ushort* __restrict__ T3,
    ushort* __restrict__ T4, const float* __restrict__ Wgk1,
    const float* __restrict__ Wgk2, ushort* __restrict__ Wte) {
  __shared__ float sbuf[64 * 65];
  const int bid = blockIdx.x;
  const int tid = threadIdx.x;

  if (bid < 4096) {  // ---- cvt_x
    const int i = bid * 256 + tid;
    float4 f = *(const float4*)(x + (size_t)i * 4);
    ushort4 o;
    o.x = f2bf(f.x); o.y = f2bf(f.y); o.z = f2bf(f.z); o.w = f2bf(f.w);
    *(ushort4*)(xbf + (size_t)i * 4) = o;
  } else if (bid < 5376) {  // ---- transpose_w
    const int w = bid - 4096;
    const int z = w >> 8, rem = w & 255;
    const float* W = (z == 0) ? W0 : (z == 1) ? W1 : (z == 2) ? W2
                     : (z == 3) ? W3 : W4;
    ushort* T = (z == 0) ? T0 : (z == 1) ? T1 : (z == 2) ? T2
                : (z == 3) ? T3 : T4;
    const int k0 = (rem >> 4) * 64, n0 = (rem & 15) * 64;
    const int r = tid >> 2, c4 = (tid & 3) * 16;
#pragma unroll
    for (int i = 0; i < 4; ++i) {
      float4 f = *(const float4*)(W + (size_t)(k0 + r) * HIDS + n0 + c4 + i * 4);
      sbuf[r * 65 + c4 + i * 4 + 0] = f.x;
      sbuf[r * 65 + c4 + i * 4 + 1] = f.y;
      sbuf[r * 65 + c4 + i * 4 + 2] = f.z;
      sbuf[r * 65 + c4 + i * 4 + 3] = f.w;
    }
    __syncthreads();
    const int n = tid >> 2, kc = (tid & 3) * 16;
#pragma unroll
    for (int i = 0; i < 4; ++i) {
      int kk = kc + i * 4;
      ushort4 o;
      o.x = f2bf(sbuf[(kk + 0) * 65 + n]);
      o.y = f2bf(sbuf[(kk + 1) * 65 + n]);
      o.z = f2bf(sbuf[(kk + 2) * 65 + n]);
      o.w = f2bf(sbuf[(kk + 3) * 65 + n]);
      *(ushort4*)(T + (size_t)(n0 + n) * HIDS + k0 + kk) = o;
    }
  } else {  // ---- weff
    const int rem = bid - 5376;
    const int n0 = (rem & 15) * 64, k0 = (rem >> 4) * 64;
    float* sW1 = sbuf;            // [64][17]
    float* sW2 = sbuf + 64 * 17;  // [16][65]
    {
      const int kl = tid >> 2, r4 = (tid & 3) * 4;
      float4 f = *(const float4*)(Wgk1 + (size_t)(k0 + kl) * RANK + r4);
      sW1[kl * 17 + r4] = f.x; sW1[kl * 17 + r4 + 1] = f.y;
      sW1[kl * 17 + r4 + 2] = f.z; sW1[kl * 17 + r4 + 3] = f.w;
      const int rr = tid >> 4, nl = (tid & 15) * 4;
      float4 g = *(const float4*)(Wgk2 + (size_t)rr * HIDS + n0 + nl);
      sW2[rr * 65 + nl] = g.x; sW2[rr * 65 + nl + 1] = g.y;
      sW2[rr * 65 + nl + 2] = g.z; sW2[rr * 65 + nl + 3] = g.w;
    }
    __syncthreads();
    const int nl = tid & 63, kq = (tid >> 6) * 16;
    float w2[16];
#pragma unroll
    for (int r = 0; r < 16; ++r) w2[r] = sW2[r * 65 + nl];
    ushort ob[16];
#pragma unroll
    for (int i = 0; i < 16; ++i) {
      float s = 0.f;
#pragma unroll
      for (int r = 0; r < 16; ++r) s = fmaf(sW1[(kq + i) * 17 + r], w2[r], s);
      ob[i] = f2bf(s);
    }
#pragma unroll
    for (int i = 0; i < 2; ++i)
      *(short8*)(Wte + (size_t)(n0 + nl) * HIDS + k0 + kq + i * 8) =
          *(short8*)&ob[i * 8];
  }
}

// ---------------------------------------------------------------------------
// proj5: 128x128 bf16 MFMA GEMM, BK=64, uniform bf16 epilogue (5 slices).
// ---------------------------------------------------------------------------
__global__ __launch_bounds__(256) void proj5_kernel(
    const ushort* __restrict__ xbf, const ushort* __restrict__ Wtq,
    const ushort* __restrict__ Wtk, const ushort* __restrict__ Wtv,
    const ushort* __restrict__ Wtg, const ushort* __restrict__ Wte,
    ushort* __restrict__ qb, ushort* __restrict__ kb, ushort* __restrict__ vb,
    ushort* __restrict__ gb, ushort* __restrict__ zb) {
  const int z = blockIdx.z;
  const ushort* Bt = (z == 0) ? Wtq : (z == 1) ? Wtk : (z == 2) ? Wtv
                     : (z == 3) ? Wtg : Wte;
  ushort* C = (z == 0) ? qb : (z == 1) ? kb : (z == 2) ? vb : (z == 3) ? gb : zb;
  __shared__ ushort As[2][128 * 32];
  __shared__ ushort Bs[2][128 * 32];
  const int tid = threadIdx.x;
  const int wave = tid >> 6, lane = tid & 63;
  const int wm = (wave >> 1) * 64, wn = (wave & 1) * 64;
  const int bm = blockIdx.y * 128, bn = blockIdx.x * 128;
  const int lrow = tid >> 2, lk8 = (tid & 3) * 8;
  const ushort* Ag = xbf + (size_t)(bm + lrow) * HIDS + lk8;
  const ushort* Bg = Bt + (size_t)(bn + lrow) * HIDS + lk8;
  char* A0 = (char*)&As[0][0] + tid * 16;
  char* A1 = (char*)&As[1][0] + tid * 16;
  char* B0 = (char*)&Bs[0][0] + tid * 16;
  char* B1 = (char*)&Bs[1][0] + tid * 16;

  floatx4 acc[4][4];
#pragma unroll
  for (int i = 0; i < 4; ++i)
#pragma unroll
    for (int j = 0; j < 4; ++j) acc[i][j] = (floatx4){0.f, 0.f, 0.f, 0.f};

  const int fm = lane & 15, quad = lane >> 4;

  for (int k0 = 0; k0 < HIDS; k0 += 64) {
    __syncthreads();
    async_copy16(Ag + k0, A0);
    async_copy16(Ag + (size_t)64 * HIDS + k0, A0 + 4096);
    async_copy16(Ag + k0 + 32, A1);
    async_copy16(Ag + (size_t)64 * HIDS + k0 + 32, A1 + 4096);
    async_copy16(Bg + k0, B0);
    async_copy16(Bg + (size_t)64 * HIDS + k0, B0 + 4096);
    async_copy16(Bg + k0 + 32, B1);
    async_copy16(Bg + (size_t)64 * HIDS + k0 + 32, B1 + 4096);
    __syncthreads();

#pragma unroll
    for (int ks = 0; ks < 2; ++ks) {
      short8 af[4], bfr[4];
#pragma unroll
      for (int i = 0; i < 4; ++i)
        af[i] = *(const short8*)&As[ks][(wm + i * 16 + fm) * 32 + quad * 8];
#pragma unroll
      for (int j = 0; j < 4; ++j)
        bfr[j] = *(const short8*)&Bs[ks][(wn + j * 16 + fm) * 32 + quad * 8];
#pragma unroll
      for (int i = 0; i < 4; ++i)
#pragma unroll
        for (int j = 0; j < 4; ++j)
          acc[i][j] = __builtin_amdgcn_mfma_f32_16x16x32_bf16(af[i], bfr[j],
                                                              acc[i][j], 0, 0, 0);
    }
  }

#pragma unroll
  for (int i = 0; i < 4; ++i) {
    const int row0 = bm + wm + i * 16 + quad * 4;
#pragma unroll
    for (int j = 0; j < 4; ++j) {
      const int col = bn + wn + j * 16 + fm;
#pragma unroll
      for (int r = 0; r < 4; ++r)
        C[(size_t)(row0 + r) * HIDS + col] = f2bf(acc[i][j][r]);
    }
  }
}

// ---------------------------------------------------------------------------
// Output GEMM: 128(M) x 64(N) tile, BK=64, fp32 out. 512 blocks.
// ---------------------------------------------------------------------------
__global__ __launch_bounds__(256) void gemm_out_kernel(
    const ushort* __restrict__ A, const ushort* __restrict__ Bt,
    float* __restrict__ C) {
  __shared__ ushort As[2][128 * 32];
  __shared__ ushort Bs[2][64 * 32];
  const int tid = threadIdx.x;
  const int wave = tid >> 6, lane = tid & 63;
  const int fm = lane & 15, quad = lane >> 4;
  const int bm = blockIdx.y * 128, bn = blockIdx.x * 64;
  const int lrow = tid >> 2, lk8 = (tid & 3) * 8;
  const ushort* Ag = A + (size_t)(bm + lrow) * HIDS + lk8;
  const ushort* Bg = Bt + (size_t)(bn + lrow) * HIDS + lk8;
  char* A0 = (char*)&As[0][0] + tid * 16;
  char* A1 = (char*)&As[1][0] + tid * 16;
  char* B0 = (char*)&Bs[0][0] + tid * 16;
  char* B1 = (char*)&Bs[1][0] + tid * 16;

  floatx4 acc[2][4];
#pragma unroll
  for (int i = 0; i < 2; ++i)
#pragma unroll
    for (int j = 0; j < 4; ++j) acc[i][j] = (floatx4){0.f, 0.f, 0.f, 0.f};

  for (int k0 = 0; k0 < HIDS; k0 += 64) {
    __syncthreads();
    async_copy16(Ag + k0, A0);
    async_copy16(Ag + (size_t)64 * HIDS + k0, A0 + 4096);
    async_copy16(Ag + k0 + 32, A1);
    async_copy16(Ag + (size_t)64 * HIDS + k0 + 32, A1 + 4096);
    async_copy16(Bg + k0, B0);
    async_copy16(Bg + k0 + 32, B1);
    __syncthreads();

#pragma unroll
    for (int ks = 0; ks < 2; ++ks) {
      short8 af[2], bfr[4];
#pragma unroll
      for (int i = 0; i < 2; ++i)
        af[i] = *(const short8*)&As[ks][(wave * 32 + i * 16 + fm) * 32 + quad * 8];
#pragma unroll
      for (int j = 0; j < 4; ++j)
        bfr[j] = *(const short8*)&Bs[ks][(j * 16 + fm) * 32 + quad * 8];
#pragma unroll
      for (int i = 0; i < 2; ++i)
#pragma unroll
        for (int j = 0; j < 4; ++j)
          acc[i][j] = __builtin_amdgcn_mfma_f32_16x16x32_bf16(af[i], bfr[j],
                                                              acc[i][j], 0, 0, 0);
    }
  }

#pragma unroll
  for (int i = 0; i < 2; ++i) {
    const int row0 = bm + wave * 32 + i * 16 + quad * 4;
#pragma unroll
    for (int j = 0; j < 4; ++j) {
      const int col = bn + j * 16 + fm;
#pragma unroll
      for (int r = 0; r < 4; ++r)
        C[(size_t)(row0 + r) * HIDS + col] = acc[i][j][r];
    }
  }
}

#define SP 72   // ushort stride for bf16 LDS tiles (16B-aligned rows)
#define SGS 68  // float stride for Gamma tile

// ---------------------------------------------------------------------------
// sdelta: per (b,h,chunk): Gamma=cumsum(logsig16(z+bias)); Vt~=(e^-G V)^T;
//   Sdelta(bf16) = Lam . (V~^T @ K); Lam = e^{Gamma_63}.
// Also exports Vtg = V~^T tile (bf16) and Eb = e^Gamma (bf16) so chunk_fused
// does no transcendentals / cumsum at all.
// ---------------------------------------------------------------------------
__global__ __launch_bounds__(256) void sdelta_kernel(
    const ushort* __restrict__ k, const ushort* __restrict__ v,
    const ushort* __restrict__ zb, const float* __restrict__ bgk2,
    ushort* __restrict__ Sdelta, float* __restrict__ Lam,
    ushort* __restrict__ Vtg, ushort* __restrict__ Eb) {
  const int bid = blockIdx.x;
  const int c = bid & 31, bh = bid >> 5;
  const int b = bh >> 4, h = bh & 15;
  const int tid = threadIdx.x;
  const int lane = tid & 63, wave = tid >> 6;
  const int fm = lane & 15, quad = lane >> 4;
  const int wm2 = (wave >> 1) * 32, wn2 = (wave & 1) * 32;

  __shared__ ushort sKt[64 * SP];
  __shared__ ushort sVt[64 * SP];
  __shared__ float sG[64 * SGS];

  const size_t base = ((size_t)b * LSEQ + (size_t)c * CHUNK) * HIDS + (size_t)h * HDIM;
  // natural partition (gate logits + bias)
  const int r = tid >> 2, c0 = (tid & 3) * 16;
  const size_t gb = base + (size_t)r * HIDS + c0;
  {
    float bias[16];
#pragma unroll
    for (int m = 0; m < 4; ++m)
      *(float4*)&bias[m * 4] = *(const float4*)(bgk2 + h * HDIM + c0 + m * 4);
    short8 z0 = *(const short8*)(zb + gb);
    short8 z1 = *(const short8*)(zb + gb + 8);
#pragma unroll
    for (int i = 0; i < 16; ++i) {
      float zz = bf2f((ushort)(i < 8 ? z0[i] : z1[i - 8])) + bias[i];
      sG[r * SGS + c0 + i] = logsig16(zz);
    }
  }
  // pair partition (K, V)
  const int pr = (tid >> 3) * 2, pc = (tid & 7) * 8;
  const size_t pb = base + (size_t)pr * HIDS + pc;
  short8 ka = *(const short8*)(k + pb);
  short8 kb2 = *(const short8*)(k + pb + HIDS);
  short8 va = *(const short8*)(v + pb);
  short8 vb2 = *(const short8*)(v + pb + HIDS);
  __syncthreads();

  // inclusive cumsum along t per v column
  const int vcol = tid & 63, qtr = tid >> 6;
  {
    float run = 0.f;
#pragma unroll
    for (int i = 0; i < 16; ++i) {
      int idx = (qtr * 16 + i) * SGS + vcol;
      run += sG[idx];
      sG[idx] = run;
    }
  }
  __syncthreads();
  float pre = 0.f;
  for (int j = 0; j < qtr; ++j) pre += sG[(j * 16 + 15) * SGS + vcol];
  __syncthreads();
#pragma unroll
  for (int i = 0; i < 16; ++i) sG[(qtr * 16 + i) * SGS + vcol] += pre;
  __syncthreads();

  // E = e^Gamma -> global (natural partition, coalesced 32B/thread)
  {
    ushort eb[16];
#pragma unroll
    for (int i = 0; i < 16; ++i) eb[i] = f2bf(expf(sG[r * SGS + c0 + i]));
    *(short8*)(Eb + gb) = *(short8*)&eb[0];
    *(short8*)(Eb + gb + 8) = *(short8*)&eb[8];
  }

  // transposed tiles (ushort2 writes)
#pragma unroll
  for (int i = 0; i < 8; ++i) {
    ushort2 kk;
    kk.x = (ushort)ka[i];
    kk.y = (ushort)kb2[i];
    *(ushort2*)&sKt[(pc + i) * SP + pr] = kk;
    float Ga = sG[pr * SGS + pc + i];
    float Gb2 = sG[(pr + 1) * SGS + pc + i];
    ushort2 vv;
    vv.x = f2bf(bf2f((ushort)va[i]) * expf(-Ga));
    vv.y = f2bf(bf2f((ushort)vb2[i]) * expf(-Gb2));
    *(ushort2*)&sVt[(pc + i) * SP + pr] = vv;
  }
  __syncthreads();

  // export V~^T tile for chunk_fused (row=v, col=s; coalesced 32B/thread)
  {
    const size_t vb3 = (size_t)(bh * NCHUNK + c) * (HDIM * HDIM);
    *(short8*)(Vtg + vb3 + (size_t)r * HDIM + c0) = *(const short8*)&sVt[r * SP + c0];
    *(short8*)(Vtg + vb3 + (size_t)r * HDIM + c0 + 8) =
        *(const short8*)&sVt[r * SP + c0 + 8];
  }

  if (tid < 64)
    Lam[(size_t)(bh * NCHUNK + c) * HDIM + tid] = expf(sG[63 * SGS + tid]);

  floatx4 accD[2][2];
#pragma unroll
  for (int i = 0; i < 2; ++i)
#pragma unroll
    for (int j = 0; j < 2; ++j) accD[i][j] = (floatx4){0.f, 0.f, 0.f, 0.f};
#pragma unroll
  for (int ks = 0; ks < 2; ++ks) {
    short8 av[2], bk[2];
#pragma unroll
    for (int i = 0; i < 2; ++i)
      av[i] = *(const short8*)&sVt[(wm2 + i * 16 + fm) * SP + ks * 32 + quad * 8];
#pragma unroll
    for (int j = 0; j < 2; ++j)
      bk[j] = *(const short8*)&sKt[(wn2 + j * 16 + fm) * SP + ks * 32 + quad * 8];
#pragma unroll
    for (int i = 0; i < 2; ++i)
#pragma unroll
      for (int j = 0; j < 2; ++j)
        accD[i][j] = __builtin_amdgcn_mfma_f32_16x16x32_bf16(av[i], bk[j],
                                                             accD[i][j], 0, 0, 0);
  }
  const size_t sbase = (size_t)(bh * NCHUNK + c) * (HDIM * HDIM);
#pragma unroll
  for (int i = 0; i < 2; ++i) {
    const int m0 = wm2 + i * 16 + quad * 4;
    float lam[4];
#pragma unroll
    for (int rr = 0; rr < 4; ++rr) lam[rr] = expf(sG[63 * SGS + m0 + rr]);
#pragma unroll
    for (int j = 0; j < 2; ++j) {
      const int n = wn2 + j * 16 + fm;
#pragma unroll
      for (int rr = 0; rr < 4; ++rr)
        Sdelta[sbase + (size_t)(m0 + rr) * HDIM + n] = f2bf(accD[i][j][rr] * lam[rr]);
    }
  }
}

// ---------------------------------------------------------------------------
// state_scan: elementwise-parallel over 4096 state slots; 256 blocks.
// ---------------------------------------------------------------------------
__global__ __launch_bounds__(256) void state_scan_kernel(
    const ushort* __restrict__ Sdelta, const float* __restrict__ Lam,
    ushort* __restrict__ Sprev) {
  const int bh = blockIdx.x >> 3;
  const int sl = blockIdx.x & 7;
  const int tid = threadIdx.x;
  const int e0 = sl * 512 + tid;
  float S0 = 0.f, S1 = 0.f;

  size_t base = (size_t)(bh * NCHUNK) * (HDIM * HDIM);
  size_t lbase = (size_t)(bh * NCHUNK) * HDIM;
  float pd0 = bf2f(Sdelta[base + e0]);
  float pd1 = bf2f(Sdelta[base + e0 + 256]);
  float pl0 = Lam[lbase + (e0 >> 6)];
  float pl1 = Lam[lbase + ((e0 + 256) >> 6)];

  for (int c = 0; c < NCHUNK; ++c) {
    float cd0 = pd0, cd1 = pd1, cl0 = pl0, cl1 = pl1;
    if (c + 1 < NCHUNK) {
      size_t nb = (size_t)(bh * NCHUNK + c + 1) * (HDIM * HDIM);
      size_t nl = (size_t)(bh * NCHUNK + c + 1) * HDIM;
      pd0 = bf2f(Sdelta[nb + e0]);
      pd1 = bf2f(Sdelta[nb + e0 + 256]);
      pl0 = Lam[nl + (e0 >> 6)];
      pl1 = Lam[nl + ((e0 + 256) >> 6)];
    }
    size_t ob = (size_t)(bh * NCHUNK + c) * (HDIM * HDIM);
    Sprev[ob + e0] = f2bf(S0);
    Sprev[ob + e0 + 256] = f2bf(S1);
    S0 = fmaf(S0, cl0, cd0);
    S1 = fmaf(S1, cl1, cd1);
  }
}

// ---------------------------------------------------------------------------
// chunk_fused: att(bf16) = E . ( tril(QK^T) @ V~ + Q @ Sprev^T )
// No transcendentals, no cumsum: V~ and E come precomputed from sdelta.
// LDS 36 KB -> 4 blocks/CU; 3 barriers.
// ---------------------------------------------------------------------------
__global__ __launch_bounds__(256) void chunk_fused_kernel(
    const ushort* __restrict__ q, const ushort* __restrict__ k,
    const ushort* __restrict__ Vtg, const ushort* __restrict__ Eb,
    const ushort* __restrict__ Sprev, ushort* __restrict__ att) {
  const int bid = blockIdx.x;
  const int c = bid & 31, bh = bid >> 5;
  const int b = bh >> 4, h = bh & 15;
  const int tid = threadIdx.x;
  const int lane = tid & 63, wave = tid >> 6;
  const int fm = lane & 15, quad = lane >> 4;
  const int wm2 = (wave >> 1) * 32, wn2 = (wave & 1) * 32;

  __shared__ ushort sQ[64 * SP];
  __shared__ ushort sK[64 * SP];   // reused as sSp after scores
  __shared__ ushort sVt[64 * SP];
  __shared__ ushort sA[64 * SP];
  ushort* sSp = sK;

  const size_t base = ((size_t)b * LSEQ + (size_t)c * CHUNK) * HIDS + (size_t)h * HDIM;
  const size_t sbase = (size_t)(bh * NCHUNK + c) * (HDIM * HDIM);
  const int r = tid >> 2, c0 = (tid & 3) * 16;
  const size_t gb = base + (size_t)r * HIDS + c0;
  // preload Sprev into regs (stored into sK's space after scores)
  short8 sp0 = *(const short8*)(Sprev + sbase + (size_t)r * HDIM + c0);
  short8 sp1 = *(const short8*)(Sprev + sbase + (size_t)r * HDIM + c0 + 8);
  *(short8*)&sQ[r * SP + c0] = *(const short8*)(q + gb);
  *(short8*)&sQ[r * SP + c0 + 8] = *(const short8*)(q + gb + 8);
  *(short8*)&sK[r * SP + c0] = *(const short8*)(k + gb);
  *(short8*)&sK[r * SP + c0 + 8] = *(const short8*)(k + gb + 8);
  *(short8*)&sVt[r * SP + c0] = *(const short8*)(Vtg + sbase + (size_t)r * HDIM + c0);
  *(short8*)&sVt[r * SP + c0 + 8] =
      *(const short8*)(Vtg + sbase + (size_t)r * HDIM + c0 + 8);
  __syncthreads();

  // scores = tril(Q K^T) (reads sQ, sK)
  floatx4 accS[2][2];
#pragma unroll
  for (int i = 0; i < 2; ++i)
#pragma unroll
    for (int j = 0; j < 2; ++j) accS[i][j] = (floatx4){0.f, 0.f, 0.f, 0.f};
#pragma unroll
  for (int ks = 0; ks < 2; ++ks) {
    short8 a[2], bb[2];
#pragma unroll
    for (int i = 0; i < 2; ++i)
      a[i] = *(const short8*)&sQ[(wm2 + i * 16 + fm) * SP + ks * 32 + quad * 8];
#pragma unroll
    for (int j = 0; j < 2; ++j)
      bb[j] = *(const short8*)&sK[(wn2 + j * 16 + fm) * SP + ks * 32 + quad * 8];
#pragma unroll
    for (int i = 0; i < 2; ++i)
#pragma unroll
      for (int j = 0; j < 2; ++j)
        accS[i][j] = __builtin_amdgcn_mfma_f32_16x16x32_bf16(a[i], bb[j],
                                                             accS[i][j], 0, 0, 0);
  }
  __syncthreads();  // all waves done reading sK

  // write sA (tril) and sSp (into sK space)
#pragma unroll
  for (int i = 0; i < 2; ++i)
#pragma unroll
    for (int j = 0; j < 2; ++j) {
      const int t0 = wm2 + i * 16 + quad * 4;
      const int s = wn2 + j * 16 + fm;
#pragma unroll
      for (int rr = 0; rr < 4; ++rr) {
        float val = (s <= t0 + rr) ? accS[i][j][rr] : 0.f;
        sA[(t0 + rr) * SP + s] = f2bf(val);
      }
    }
  *(short8*)&sSp[r * SP + c0] = sp0;
  *(short8*)&sSp[r * SP + c0 + 8] = sp1;
  __syncthreads();

  // att = E . (sA @ V~  +  Q @ Sprev^T)
  floatx4 acc[2][2];
#pragma unroll
  for (int i = 0; i < 2; ++i)
#pragma unroll
    for (int j = 0; j < 2; ++j) acc[i][j] = (floatx4){0.f, 0.f, 0.f, 0.f};
#pragma unroll
  for (int ks = 0; ks < 2; ++ks) {
    short8 aa[2], aq[2], bv[2], bs[2];
#pragma unroll
    for (int i = 0; i < 2; ++i) {
      aa[i] = *(const short8*)&sA[(wm2 + i * 16 + fm) * SP + ks * 32 + quad * 8];
      aq[i] = *(const short8*)&sQ[(wm2 + i * 16 + fm) * SP + ks * 32 + quad * 8];
    }
#pragma unroll
    for (int j = 0; j < 2; ++j) {
      bv[j] = *(const short8*)&sVt[(wn2 + j * 16 + fm) * SP + ks * 32 + quad * 8];
      bs[j] = *(const short8*)&sSp[(wn2 + j * 16 + fm) * SP + ks * 32 + quad * 8];
    }
#pragma unroll
    for (int i = 0; i < 2; ++i)
#pragma unroll
      for (int j = 0; j < 2; ++j) {
        acc[i][j] = __builtin_amdgcn_mfma_f32_16x16x32_bf16(aa[i], bv[j],
                                                            acc[i][j], 0, 0, 0);
        acc[i][j] = __builtin_amdgcn_mfma_f32_16x16x32_bf16(aq[i], bs[j],
                                                            acc[i][j], 0, 0, 0);
      }
  }
#pragma unroll
  for (int i = 0; i < 2; ++i)
#pragma unroll
    for (int j = 0; j < 2; ++j) {
      const int m0 = wm2 + i * 16 + quad * 4;
      const int n = wn2 + j * 16 + fm;
#pragma unroll
      for (int rr = 0; rr < 4; ++rr) {
        const size_t idx = base + (size_t)(m0 + rr) * HIDS + n;
        att[idx] = f2bf(acc[i][j][rr] * bf2f(Eb[idx]));
      }
    }
}

// ---------------------------------------------------------------------------
// y = (LayerNorm(att) * gamma + beta) * silu(g), bf16 in/out.
// ---------------------------------------------------------------------------
__global__ __launch_bounds__(256) void ln_gate_kernel(const ushort* __restrict__ att,
                                                      const ushort* __restrict__ g,
                                                      const float* __restrict__ gamma,
                                                      const float* __restrict__ beta,
                                                      ushort* __restrict__ ybf) {
  const int row = blockIdx.x;
  const int tid = threadIdx.x;
  ushort4 au = *(const ushort4*)(att + (size_t)row * HIDS + tid * 4);
  float ax = bf2f(au.x), ay = bf2f(au.y), az = bf2f(au.z), aw = bf2f(au.w);
  float s = ax + ay + az + aw;
  float ss = ax * ax + ay * ay + az * az + aw * aw;
#pragma unroll
  for (int off = 32; off; off >>= 1) {
    s += __shfl_down(s, off);
    ss += __shfl_down(ss, off);
  }
  __shared__ float rs[4], rss[4];
  const int wid = tid >> 6;
  if ((tid & 63) == 0) { rs[wid] = s; rss[wid] = ss; }
  __syncthreads();
  const float mean = (rs[0] + rs[1] + rs[2] + rs[3]) * (1.f / HIDS);
  const float ex2 = (rss[0] + rss[1] + rss[2] + rss[3]) * (1.f / HIDS);
  const float rstd = rsqrtf(ex2 - mean * mean + 1e-5f);

  float4 ga = *(const float4*)(gamma + tid * 4);
  float4 be = *(const float4*)(beta + tid * 4);
  ushort4 gu = *(const ushort4*)(g + (size_t)row * HIDS + tid * 4);
  float gx = bf2f(gu.x), gy = bf2f(gu.y), gz = bf2f(gu.z), gw = bf2f(gu.w);
  float4 o;
  o.x = ((ax - mean) * rstd * ga.x + be.x) * (gx / (1.f + expf(-gx)));
  o.y = ((ay - mean) * rstd * ga.y + be.y) * (gy / (1.f + expf(-gy)));
  o.z = ((az - mean) * rstd * ga.z + be.z) * (gz / (1.f + expf(-gz)));
  o.w = ((aw - mean) * rstd * ga.w + be.w) * (gw / (1.f + expf(-gw)));
  ushort4 ob;
  ob.x = f2bf(o.x); ob.y = f2bf(o.y); ob.z = f2bf(o.z); ob.w = f2bf(o.w);
  *(ushort4*)(ybf + (size_t)row * HIDS + tid * 4) = ob;
}

// ---------------------------------------------------------------------------
extern "C" void kernel_launch(void* const* d_in, const int* in_sizes, int n_in,
                              void* d_out, int out_size, void* d_ws, size_t ws_size,
                              hipStream_t stream) {
  const float* x     = (const float*)d_in[0];
  const float* Wq    = (const float*)d_in[1];
  const float* Wk    = (const float*)d_in[2];
  const float* Wv    = (const float*)d_in[3];
  const float* Wg    = (const float*)d_in[4];
  const float* Wgk1  = (const float*)d_in[5];
  const float* Wgk2  = (const float*)d_in[6];
  const float* bgk2  = (const float*)d_in[7];
  const float* gamma = (const float*)d_in[8];
  const float* beta  = (const float*)d_in[9];
  const float* Wout  = (const float*)d_in[10];
  float* out = (float*)d_out;

  const size_t SZ = (size_t)NROW * HIDS;  // 4M elements
  float* ws = (float*)d_ws;
  float* Lamb = ws;                         // 64K floats
  ushort* attb   = (ushort*)(ws + 65536);   // bf16 4M
  ushort* Sdelta = attb + SZ;
  ushort* Sprevb = Sdelta + SZ;
  ushort* Vtgb   = Sprevb + SZ;             // V~^T tiles (bf16)
  ushort* Ebb    = Vtgb + SZ;               // e^Gamma (bf16)
  ushort* qbf = Ebb + SZ;
  ushort* kbf = qbf + SZ;
  ushort* vbf = kbf + SZ;
  ushort* gbf = vbf + SZ;
  ushort* zbf = gbf + SZ;                   // gate logits (bf16, pre-bias)
  ushort* xbf = zbf + SZ;
  ushort* Wtq = xbf + SZ;
  ushort* Wtk = Wtq + HIDS * HIDS;
  ushort* Wtv = Wtk + HIDS * HIDS;
  ushort* Wtg = Wtv + HIDS * HIDS;
  ushort* Wto = Wtg + HIDS * HIDS;
  ushort* Wte = Wto + HIDS * HIDS;
  ushort* ybf = vbf;  // vbf dead after sdelta

  prep_kernel<<<4096 + 1280 + 256, 256, 0, stream>>>(
      x, xbf, Wq, Wk, Wv, Wg, Wout, Wtq, Wtk, Wtv, Wtg, Wto, Wgk1, Wgk2, Wte);

  proj5_kernel<<<dim3(HIDS / 128, NROW / 128, 5), 256, 0, stream>>>(
      xbf, Wtq, Wtk, Wtv, Wtg, Wte, qbf, kbf, vbf, gbf, zbf);

  sdelta_kernel<<<BBATCH * NHEAD * NCHUNK, 256, 0, stream>>>(
      kbf, vbf, zbf, bgk2, Sdelta, Lamb, Vtgb, Ebb);
  state_scan_kernel<<<256, 256, 0, stream>>>(Sdelta, Lamb, Sprevb);
  chunk_fused_kernel<<<BBATCH * NHEAD * NCHUNK, 256, 0, stream>>>(
      qbf, kbf, Vtgb, Ebb, Sprevb, attb);

  ln_gate_kernel<<<NROW, 256, 0, stream>>>(attb, gbf, gamma, beta, ybf);
  gemm_out_kernel<<<dim3(HIDS / 64, NROW / 128), 256, 0, stream>>>(ybf, Wto, out);
}

// Round 10
// 211.337 us; speedup vs baseline: 1.3206x; 1.0065x over previous
//
#include <hip/hip_runtime.h>
#include <cstdint>
#include <cstddef>

#define HIDS 1024
#define NHEAD 16
#define HDIM 64
#define LSEQ 2048
#define BBATCH 2
#define NROW (BBATCH * LSEQ)  // 4096
#define CHUNK 64
#define NCHUNK (LSEQ / CHUNK)  // 32
#define RANK 16

typedef short short8 __attribute__((ext_vector_type(8)));
typedef float floatx4 __attribute__((ext_vector_type(4)));

__device__ __forceinline__ ushort f2bf(float f) {
  uint32_t u = __float_as_uint(f);
  uint32_t r = (u + 0x7fffu + ((u >> 16) & 1u)) >> 16;  // RNE
  return (ushort)r;
}
__device__ __forceinline__ float bf2f(ushort u) {
  return __uint_as_float(((uint32_t)u) << 16);
}
// log_sigmoid(z)/16 via native exp/log: arg of log is in (1,2], so plain
// __logf is accurate; when exp(-|z|) is tiny, log(1+t)~t anyway (gate ~1).
__device__ __forceinline__ float logsig16(float z) {
  return (fminf(z, 0.f) - __logf(1.f + __expf(-fabsf(z)))) * (1.f / 16.f);
}

__device__ __forceinline__ void async_copy16(const void* g, void* l) {
  __builtin_amdgcn_global_load_lds(
      (const __attribute__((address_space(1))) void*)g,
      (__attribute__((address_space(3))) void*)l, 16, 0, 0);
}

// ---------------------------------------------------------------------------
// prep: fused cvt_x (blocks 0..4095), transpose_w (4096..5375, 5 x 256),
//       weff (5376..5631).
// ---------------------------------------------------------------------------
__global__ __launch_bounds__(256) void prep_kernel(
    const float* __restrict__ x, ushort* __restrict__ xbf,
    const float* __restrict__ W0, const float* __restrict__ W1,
    const float* __restrict__ W2, const float* __restrict__ W3,
    const float* __restrict__ W4, ushort* __restrict__ T0,
    ushort* __restrict__ T1, ushort* __restrict__ T2, ushort* __restrict__ T3,
    ushort* __restrict__ T4, const float* __restrict__ Wgk1,
    const float* __restrict__ Wgk2, ushort* __restrict__ Wte) {
  __shared__ float sbuf[64 * 65];
  const int bid = blockIdx.x;
  const int tid = threadIdx.x;

  if (bid < 4096) {  // ---- cvt_x
    const int i = bid * 256 + tid;
    float4 f = *(const float4*)(x + (size_t)i * 4);
    ushort4 o;
    o.x = f2bf(f.x); o.y = f2bf(f.y); o.z = f2bf(f.z); o.w = f2bf(f.w);
    *(ushort4*)(xbf + (size_t)i * 4) = o;
  } else if (bid < 5376) {  // ---- transpose_w
    const int w = bid - 4096;
    const int z = w >> 8, rem = w & 255;
    const float* W = (z == 0) ? W0 : (z == 1) ? W1 : (z == 2) ? W2
                     : (z == 3) ? W3 : W4;
    ushort* T = (z == 0) ? T0 : (z == 1) ? T1 : (z == 2) ? T2
                : (z == 3) ? T3 : T4;
    const int k0 = (rem >> 4) * 64, n0 = (rem & 15) * 64;
    const int r = tid >> 2, c4 = (tid & 3) * 16;
#pragma unroll
    for (int i = 0; i < 4; ++i) {
      float4 f = *(const float4*)(W + (size_t)(k0 + r) * HIDS + n0 + c4 + i * 4);
      sbuf[r * 65 + c4 + i * 4 + 0] = f.x;
      sbuf[r * 65 + c4 + i * 4 + 1] = f.y;
      sbuf[r * 65 + c4 + i * 4 + 2] = f.z;
      sbuf[r * 65 + c4 + i * 4 + 3] = f.w;
    }
    __syncthreads();
    const int n = tid >> 2, kc = (tid & 3) * 16;
#pragma unroll
    for (int i = 0; i < 4; ++i) {
      int kk = kc + i * 4;
      ushort4 o;
      o.x = f2bf(sbuf[(kk + 0) * 65 + n]);
      o.y = f2bf(sbuf[(kk + 1) * 65 + n]);
      o.z = f2bf(sbuf[(kk + 2) * 65 + n]);
      o.w = f2bf(sbuf[(kk + 3) * 65 + n]);
      *(ushort4*)(T + (size_t)(n0 + n) * HIDS + k0 + kk) = o;
    }
  } else {  // ---- weff
    const int rem = bid - 5376;
    const int n0 = (rem & 15) * 64, k0 = (rem >> 4) * 64;
    float* sW1 = sbuf;            // [64][17]
    float* sW2 = sbuf + 64 * 17;  // [16][65]
    {
      const int kl = tid >> 2, r4 = (tid & 3) * 4;
      float4 f = *(const float4*)(Wgk1 + (size_t)(k0 + kl) * RANK + r4);
      sW1[kl * 17 + r4] = f.x; sW1[kl * 17 + r4 + 1] = f.y;
      sW1[kl * 17 + r4 + 2] = f.z; sW1[kl * 17 + r4 + 3] = f.w;
      const int rr = tid >> 4, nl = (tid & 15) * 4;
      float4 g = *(const float4*)(Wgk2 + (size_t)rr * HIDS + n0 + nl);
      sW2[rr * 65 + nl] = g.x; sW2[rr * 65 + nl + 1] = g.y;
      sW2[rr * 65 + nl + 2] = g.z; sW2[rr * 65 + nl + 3] = g.w;
    }
    __syncthreads();
    const int nl = tid & 63, kq = (tid >> 6) * 16;
    float w2[16];
#pragma unroll
    for (int r = 0; r < 16; ++r) w2[r] = sW2[r * 65 + nl];
    ushort ob[16];
#pragma unroll
    for (int i = 0; i < 16; ++i) {
      float s = 0.f;
#pragma unroll
      for (int r = 0; r < 16; ++r) s = fmaf(sW1[(kq + i) * 17 + r], w2[r], s);
      ob[i] = f2bf(s);
    }
#pragma unroll
    for (int i = 0; i < 2; ++i)
      *(short8*)(Wte + (size_t)(n0 + nl) * HIDS + k0 + kq + i * 8) =
          *(short8*)&ob[i * 8];
  }
}

// ---------------------------------------------------------------------------
// proj5: 128x128 bf16 MFMA GEMM, BK=64, uniform bf16 epilogue.
// Grid x = 40 = (8 N-tiles) x (5 slices), z fastest -> 5 consecutive blocks
// share one A-tile (L2-hot A reads).
// ---------------------------------------------------------------------------
__global__ __launch_bounds__(256) void proj5_kernel(
    const ushort* __restrict__ xbf, const ushort* __restrict__ Wtq,
    const ushort* __restrict__ Wtk, const ushort* __restrict__ Wtv,
    const ushort* __restrict__ Wtg, const ushort* __restrict__ Wte,
    ushort* __restrict__ qb, ushort* __restrict__ kb, ushort* __restrict__ vb,
    ushort* __restrict__ gb, ushort* __restrict__ zb) {
  const int bxz = blockIdx.x;
  const int z = bxz % 5;       // fastest-varying
  const int bx = bxz / 5;
  const ushort* Bt = (z == 0) ? Wtq : (z == 1) ? Wtk : (z == 2) ? Wtv
                     : (z == 3) ? Wtg : Wte;
  ushort* C = (z == 0) ? qb : (z == 1) ? kb : (z == 2) ? vb : (z == 3) ? gb : zb;
  __shared__ ushort As[2][128 * 32];
  __shared__ ushort Bs[2][128 * 32];
  const int tid = threadIdx.x;
  const int wave = tid >> 6, lane = tid & 63;
  const int wm = (wave >> 1) * 64, wn = (wave & 1) * 64;
  const int bm = blockIdx.y * 128, bn = bx * 128;
  const int lrow = tid >> 2, lk8 = (tid & 3) * 8;
  const ushort* Ag = xbf + (size_t)(bm + lrow) * HIDS + lk8;
  const ushort* Bg = Bt + (size_t)(bn + lrow) * HIDS + lk8;
  char* A0 = (char*)&As[0][0] + tid * 16;
  char* A1 = (char*)&As[1][0] + tid * 16;
  char* B0 = (char*)&Bs[0][0] + tid * 16;
  char* B1 = (char*)&Bs[1][0] + tid * 16;

  floatx4 acc[4][4];
#pragma unroll
  for (int i = 0; i < 4; ++i)
#pragma unroll
    for (int j = 0; j < 4; ++j) acc[i][j] = (floatx4){0.f, 0.f, 0.f, 0.f};

  const int fm = lane & 15, quad = lane >> 4;

  for (int k0 = 0; k0 < HIDS; k0 += 64) {
    __syncthreads();
    async_copy16(Ag + k0, A0);
    async_copy16(Ag + (size_t)64 * HIDS + k0, A0 + 4096);
    async_copy16(Ag + k0 + 32, A1);
    async_copy16(Ag + (size_t)64 * HIDS + k0 + 32, A1 + 4096);
    async_copy16(Bg + k0, B0);
    async_copy16(Bg + (size_t)64 * HIDS + k0, B0 + 4096);
    async_copy16(Bg + k0 + 32, B1);
    async_copy16(Bg + (size_t)64 * HIDS + k0 + 32, B1 + 4096);
    __syncthreads();

#pragma unroll
    for (int ks = 0; ks < 2; ++ks) {
      short8 af[4], bfr[4];
#pragma unroll
      for (int i = 0; i < 4; ++i)
        af[i] = *(const short8*)&As[ks][(wm + i * 16 + fm) * 32 + quad * 8];
#pragma unroll
      for (int j = 0; j < 4; ++j)
        bfr[j] = *(const short8*)&Bs[ks][(wn + j * 16 + fm) * 32 + quad * 8];
#pragma unroll
      for (int i = 0; i < 4; ++i)
#pragma unroll
        for (int j = 0; j < 4; ++j)
          acc[i][j] = __builtin_amdgcn_mfma_f32_16x16x32_bf16(af[i], bfr[j],
                                                              acc[i][j], 0, 0, 0);
    }
  }

#pragma unroll
  for (int i = 0; i < 4; ++i) {
    const int row0 = bm + wm + i * 16 + quad * 4;
#pragma unroll
    for (int j = 0; j < 4; ++j) {
      const int col = bn + wn + j * 16 + fm;
#pragma unroll
      for (int r = 0; r < 4; ++r)
        C[(size_t)(row0 + r) * HIDS + col] = f2bf(acc[i][j][r]);
    }
  }
}

// ---------------------------------------------------------------------------
// Output GEMM: 128(M) x 64(N) tile, BK=64, fp32 out. 512 blocks.
// ---------------------------------------------------------------------------
__global__ __launch_bounds__(256) void gemm_out_kernel(
    const ushort* __restrict__ A, const ushort* __restrict__ Bt,
    float* __restrict__ C) {
  __shared__ ushort As[2][128 * 32];
  __shared__ ushort Bs[2][64 * 32];
  const int tid = threadIdx.x;
  const int wave = tid >> 6, lane = tid & 63;
  const int fm = lane & 15, quad = lane >> 4;
  const int bm = blockIdx.y * 128, bn = blockIdx.x * 64;
  const int lrow = tid >> 2, lk8 = (tid & 3) * 8;
  const ushort* Ag = A + (size_t)(bm + lrow) * HIDS + lk8;
  const ushort* Bg = Bt + (size_t)(bn + lrow) * HIDS + lk8;
  char* A0 = (char*)&As[0][0] + tid * 16;
  char* A1 = (char*)&As[1][0] + tid * 16;
  char* B0 = (char*)&Bs[0][0] + tid * 16;
  char* B1 = (char*)&Bs[1][0] + tid * 16;

  floatx4 acc[2][4];
#pragma unroll
  for (int i = 0; i < 2; ++i)
#pragma unroll
    for (int j = 0; j < 4; ++j) acc[i][j] = (floatx4){0.f, 0.f, 0.f, 0.f};

  for (int k0 = 0; k0 < HIDS; k0 += 64) {
    __syncthreads();
    async_copy16(Ag + k0, A0);
    async_copy16(Ag + (size_t)64 * HIDS + k0, A0 + 4096);
    async_copy16(Ag + k0 + 32, A1);
    async_copy16(Ag + (size_t)64 * HIDS + k0 + 32, A1 + 4096);
    async_copy16(Bg + k0, B0);
    async_copy16(Bg + k0 + 32, B1);
    __syncthreads();

#pragma unroll
    for (int ks = 0; ks < 2; ++ks) {
      short8 af[2], bfr[4];
#pragma unroll
      for (int i = 0; i < 2; ++i)
        af[i] = *(const short8*)&As[ks][(wave * 32 + i * 16 + fm) * 32 + quad * 8];
#pragma unroll
      for (int j = 0; j < 4; ++j)
        bfr[j] = *(const short8*)&Bs[ks][(j * 16 + fm) * 32 + quad * 8];
#pragma unroll
      for (int i = 0; i < 2; ++i)
#pragma unroll
        for (int j = 0; j < 4; ++j)
          acc[i][j] = __builtin_amdgcn_mfma_f32_16x16x32_bf16(af[i], bfr[j],
                                                              acc[i][j], 0, 0, 0);
    }
  }

#pragma unroll
  for (int i = 0; i < 2; ++i) {
    const int row0 = bm + wave * 32 + i * 16 + quad * 4;
#pragma unroll
    for (int j = 0; j < 4; ++j) {
      const int col = bn + j * 16 + fm;
#pragma unroll
      for (int r = 0; r < 4; ++r)
        C[(size_t)(row0 + r) * HIDS + col] = acc[i][j][r];
    }
  }
}

#define SP 72   // ushort stride for bf16 LDS tiles (16B-aligned rows)
#define SGS 68  // float stride for Gamma tile

// ---------------------------------------------------------------------------
// sdelta: per (b,h,chunk): Gamma=cumsum(logsig16(z+bias)); Vt~=(e^-G V)^T;
//   Sdelta(bf16) = Lam . (V~^T @ K); also exports Vtg (V~^T) and Eb = e^Gamma.
// ---------------------------------------------------------------------------
__global__ __launch_bounds__(256) void sdelta_kernel(
    const ushort* __restrict__ k, const ushort* __restrict__ v,
    const ushort* __restrict__ zb, const float* __restrict__ bgk2,
    ushort* __restrict__ Sdelta, float* __restrict__ Lam,
    ushort* __restrict__ Vtg, ushort* __restrict__ Eb) {
  const int bid = blockIdx.x;
  const int c = bid & 31, bh = bid >> 5;
  const int b = bh >> 4, h = bh & 15;
  const int tid = threadIdx.x;
  const int lane = tid & 63, wave = tid >> 6;
  const int fm = lane & 15, quad = lane >> 4;
  const int wm2 = (wave >> 1) * 32, wn2 = (wave & 1) * 32;

  __shared__ ushort sKt[64 * SP];
  __shared__ ushort sVt[64 * SP];
  __shared__ float sG[64 * SGS];

  const size_t base = ((size_t)b * LSEQ + (size_t)c * CHUNK) * HIDS + (size_t)h * HDIM;
  const int r = tid >> 2, c0 = (tid & 3) * 16;
  const size_t gb = base + (size_t)r * HIDS + c0;
  {
    float bias[16];
#pragma unroll
    for (int m = 0; m < 4; ++m)
      *(float4*)&bias[m * 4] = *(const float4*)(bgk2 + h * HDIM + c0 + m * 4);
    short8 z0 = *(const short8*)(zb + gb);
    short8 z1 = *(const short8*)(zb + gb + 8);
#pragma unroll
    for (int i = 0; i < 16; ++i) {
      float zz = bf2f((ushort)(i < 8 ? z0[i] : z1[i - 8])) + bias[i];
      sG[r * SGS + c0 + i] = logsig16(zz);
    }
  }
  // pair partition (K, V)
  const int pr = (tid >> 3) * 2, pc = (tid & 7) * 8;
  const size_t pb = base + (size_t)pr * HIDS + pc;
  short8 ka = *(const short8*)(k + pb);
  short8 kb2 = *(const short8*)(k + pb + HIDS);
  short8 va = *(const short8*)(v + pb);
  short8 vb2 = *(const short8*)(v + pb + HIDS);
  __syncthreads();

  // inclusive cumsum along t per v column
  const int vcol = tid & 63, qtr = tid >> 6;
  {
    float run = 0.f;
#pragma unroll
    for (int i = 0; i < 16; ++i) {
      int idx = (qtr * 16 + i) * SGS + vcol;
      run += sG[idx];
      sG[idx] = run;
    }
  }
  __syncthreads();
  float pre = 0.f;
  for (int j = 0; j < qtr; ++j) pre += sG[(j * 16 + 15) * SGS + vcol];
  __syncthreads();
#pragma unroll
  for (int i = 0; i < 16; ++i) sG[(qtr * 16 + i) * SGS + vcol] += pre;
  __syncthreads();

  // E = e^Gamma -> global (coalesced 32B/thread)
  {
    ushort eb[16];
#pragma unroll
    for (int i = 0; i < 16; ++i) eb[i] = f2bf(__expf(sG[r * SGS + c0 + i]));
    *(short8*)(Eb + gb) = *(short8*)&eb[0];
    *(short8*)(Eb + gb + 8) = *(short8*)&eb[8];
  }

  // transposed tiles (ushort2 writes)
#pragma unroll
  for (int i = 0; i < 8; ++i) {
    ushort2 kk;
    kk.x = (ushort)ka[i];
    kk.y = (ushort)kb2[i];
    *(ushort2*)&sKt[(pc + i) * SP + pr] = kk;
    float Ga = sG[pr * SGS + pc + i];
    float Gb2 = sG[(pr + 1) * SGS + pc + i];
    ushort2 vv;
    vv.x = f2bf(bf2f((ushort)va[i]) * __expf(-Ga));
    vv.y = f2bf(bf2f((ushort)vb2[i]) * __expf(-Gb2));
    *(ushort2*)&sVt[(pc + i) * SP + pr] = vv;
  }
  __syncthreads();

  // export V~^T tile (coalesced 32B/thread)
  {
    const size_t vb3 = (size_t)(bh * NCHUNK + c) * (HDIM * HDIM);
    *(short8*)(Vtg + vb3 + (size_t)r * HDIM + c0) = *(const short8*)&sVt[r * SP + c0];
    *(short8*)(Vtg + vb3 + (size_t)r * HDIM + c0 + 8) =
        *(const short8*)&sVt[r * SP + c0 + 8];
  }

  if (tid < 64)
    Lam[(size_t)(bh * NCHUNK + c) * HDIM + tid] = __expf(sG[63 * SGS + tid]);

  floatx4 accD[2][2];
#pragma unroll
  for (int i = 0; i < 2; ++i)
#pragma unroll
    for (int j = 0; j < 2; ++j) accD[i][j] = (floatx4){0.f, 0.f, 0.f, 0.f};
#pragma unroll
  for (int ks = 0; ks < 2; ++ks) {
    short8 av[2], bk[2];
#pragma unroll
    for (int i = 0; i < 2; ++i)
      av[i] = *(const short8*)&sVt[(wm2 + i * 16 + fm) * SP + ks * 32 + quad * 8];
#pragma unroll
    for (int j = 0; j < 2; ++j)
      bk[j] = *(const short8*)&sKt[(wn2 + j * 16 + fm) * SP + ks * 32 + quad * 8];
#pragma unroll
    for (int i = 0; i < 2; ++i)
#pragma unroll
      for (int j = 0; j < 2; ++j)
        accD[i][j] = __builtin_amdgcn_mfma_f32_16x16x32_bf16(av[i], bk[j],
                                                             accD[i][j], 0, 0, 0);
  }
  const size_t sbase = (size_t)(bh * NCHUNK + c) * (HDIM * HDIM);
#pragma unroll
  for (int i = 0; i < 2; ++i) {
    const int m0 = wm2 + i * 16 + quad * 4;
    float lam[4];
#pragma unroll
    for (int rr = 0; rr < 4; ++rr) lam[rr] = __expf(sG[63 * SGS + m0 + rr]);
#pragma unroll
    for (int j = 0; j < 2; ++j) {
      const int n = wn2 + j * 16 + fm;
#pragma unroll
      for (int rr = 0; rr < 4; ++rr)
        Sdelta[sbase + (size_t)(m0 + rr) * HDIM + n] = f2bf(accD[i][j][rr] * lam[rr]);
    }
  }
}

// ---------------------------------------------------------------------------
// state_scan: elementwise-parallel over 4096 state slots; 256 blocks.
// Depth-2 prefetch to hide load latency across the 32-step chain.
// ---------------------------------------------------------------------------
__global__ __launch_bounds__(256) void state_scan_kernel(
    const ushort* __restrict__ Sdelta, const float* __restrict__ Lam,
    ushort* __restrict__ Sprev) {
  const int bh = blockIdx.x >> 3;
  const int sl = blockIdx.x & 7;
  const int tid = threadIdx.x;
  const int e0 = sl * 512 + tid;
  float S0 = 0.f, S1 = 0.f;

  float pd0[2], pd1[2], pl0[2], pl1[2];
#pragma unroll
  for (int s = 0; s < 2; ++s) {
    size_t nb = (size_t)(bh * NCHUNK + s) * (HDIM * HDIM);
    size_t nl = (size_t)(bh * NCHUNK + s) * HDIM;
    pd0[s] = bf2f(Sdelta[nb + e0]);
    pd1[s] = bf2f(Sdelta[nb + e0 + 256]);
    pl0[s] = Lam[nl + (e0 >> 6)];
    pl1[s] = Lam[nl + ((e0 + 256) >> 6)];
  }

  for (int c = 0; c < NCHUNK; ++c) {
    const int s = c & 1;
    float cd0 = pd0[s], cd1 = pd1[s], cl0 = pl0[s], cl1 = pl1[s];
    if (c + 2 < NCHUNK) {
      size_t nb = (size_t)(bh * NCHUNK + c + 2) * (HDIM * HDIM);
      size_t nl = (size_t)(bh * NCHUNK + c + 2) * HDIM;
      pd0[s] = bf2f(Sdelta[nb + e0]);
      pd1[s] = bf2f(Sdelta[nb + e0 + 256]);
      pl0[s] = Lam[nl + (e0 >> 6)];
      pl1[s] = Lam[nl + ((e0 + 256) >> 6)];
    }
    size_t ob = (size_t)(bh * NCHUNK + c) * (HDIM * HDIM);
    Sprev[ob + e0] = f2bf(S0);
    Sprev[ob + e0 + 256] = f2bf(S1);
    S0 = fmaf(S0, cl0, cd0);
    S1 = fmaf(S1, cl1, cd1);
  }
}

// ---------------------------------------------------------------------------
// chunk_fused: att(bf16) = E . ( tril(QK^T) @ V~ + Q @ Sprev^T )
// ---------------------------------------------------------------------------
__global__ __launch_bounds__(256) void chunk_fused_kernel(
    const ushort* __restrict__ q, const ushort* __restrict__ k,
    const ushort* __restrict__ Vtg, const ushort* __restrict__ Eb,
    const ushort* __restrict__ Sprev, ushort* __restrict__ att) {
  const int bid = blockIdx.x;
  const int c = bid & 31, bh = bid >> 5;
  const int b = bh >> 4, h = bh & 15;
  const int tid = threadIdx.x;
  const int lane = tid & 63, wave = tid >> 6;
  const int fm = lane & 15, quad = lane >> 4;
  const int wm2 = (wave >> 1) * 32, wn2 = (wave & 1) * 32;

  __shared__ ushort sQ[64 * SP];
  __shared__ ushort sK[64 * SP];   // reused as sSp after scores
  __shared__ ushort sVt[64 * SP];
  __shared__ ushort sA[64 * SP];
  ushort* sSp = sK;

  const size_t base = ((size_t)b * LSEQ + (size_t)c * CHUNK) * HIDS + (size_t)h * HDIM;
  const size_t sbase = (size_t)(bh * NCHUNK + c) * (HDIM * HDIM);
  const int r = tid >> 2, c0 = (tid & 3) * 16;
  const size_t gb = base + (size_t)r * HIDS + c0;
  short8 sp0 = *(const short8*)(Sprev + sbase + (size_t)r * HDIM + c0);
  short8 sp1 = *(const short8*)(Sprev + sbase + (size_t)r * HDIM + c0 + 8);
  *(short8*)&sQ[r * SP + c0] = *(const short8*)(q + gb);
  *(short8*)&sQ[r * SP + c0 + 8] = *(const short8*)(q + gb + 8);
  *(short8*)&sK[r * SP + c0] = *(const short8*)(k + gb);
  *(short8*)&sK[r * SP + c0 + 8] = *(const short8*)(k + gb + 8);
  *(short8*)&sVt[r * SP + c0] = *(const short8*)(Vtg + sbase + (size_t)r * HDIM + c0);
  *(short8*)&sVt[r * SP + c0 + 8] =
      *(const short8*)(Vtg + sbase + (size_t)r * HDIM + c0 + 8);
  __syncthreads();

  // scores = tril(Q K^T)
  floatx4 accS[2][2];
#pragma unroll
  for (int i = 0; i < 2; ++i)
#pragma unroll
    for (int j = 0; j < 2; ++j) accS[i][j] = (floatx4){0.f, 0.f, 0.f, 0.f};
#pragma unroll
  for (int ks = 0; ks < 2; ++ks) {
    short8 a[2], bb[2];
#pragma unroll
    for (int i = 0; i < 2; ++i)
      a[i] = *(const short8*)&sQ[(wm2 + i * 16 + fm) * SP + ks * 32 + quad * 8];
#pragma unroll
    for (int j = 0; j < 2; ++j)
      bb[j] = *(const short8*)&sK[(wn2 + j * 16 + fm) * SP + ks * 32 + quad * 8];
#pragma unroll
    for (int i = 0; i < 2; ++i)
#pragma unroll
      for (int j = 0; j < 2; ++j)
        accS[i][j] = __builtin_amdgcn_mfma_f32_16x16x32_bf16(a[i], bb[j],
                                                             accS[i][j], 0, 0, 0);
  }
  __syncthreads();  // all waves done reading sK

  // write sA (tril) and sSp (into sK space)
#pragma unroll
  for (int i = 0; i < 2; ++i)
#pragma unroll
    for (int j = 0; j < 2; ++j) {
      const int t0 = wm2 + i * 16 + quad * 4;
      const int s = wn2 + j * 16 + fm;
#pragma unroll
      for (int rr = 0; rr < 4; ++rr) {
        float val = (s <= t0 + rr) ? accS[i][j][rr] : 0.f;
        sA[(t0 + rr) * SP + s] = f2bf(val);
      }
    }
  *(short8*)&sSp[r * SP + c0] = sp0;
  *(short8*)&sSp[r * SP + c0 + 8] = sp1;
  __syncthreads();

  // att = E . (sA @ V~  +  Q @ Sprev^T)
  floatx4 acc[2][2];
#pragma unroll
  for (int i = 0; i < 2; ++i)
#pragma unroll
    for (int j = 0; j < 2; ++j) acc[i][j] = (floatx4){0.f, 0.f, 0.f, 0.f};
#pragma unroll
  for (int ks = 0; ks < 2; ++ks) {
    short8 aa[2], aq[2], bv[2], bs[2];
#pragma unroll
    for (int i = 0; i < 2; ++i) {
      aa[i] = *(const short8*)&sA[(wm2 + i * 16 + fm) * SP + ks * 32 + quad * 8];
      aq[i] = *(const short8*)&sQ[(wm2 + i * 16 + fm) * SP + ks * 32 + quad * 8];
    }
#pragma unroll
    for (int j = 0; j < 2; ++j) {
      bv[j] = *(const short8*)&sVt[(wn2 + j * 16 + fm) * SP + ks * 32 + quad * 8];
      bs[j] = *(const short8*)&sSp[(wn2 + j * 16 + fm) * SP + ks * 32 + quad * 8];
    }
#pragma unroll
    for (int i = 0; i < 2; ++i)
#pragma unroll
      for (int j = 0; j < 2; ++j) {
        acc[i][j] = __builtin_amdgcn_mfma_f32_16x16x32_bf16(aa[i], bv[j],
                                                            acc[i][j], 0, 0, 0);
        acc[i][j] = __builtin_amdgcn_mfma_f32_16x16x32_bf16(aq[i], bs[j],
                                                            acc[i][j], 0, 0, 0);
      }
  }
#pragma unroll
  for (int i = 0; i < 2; ++i)
#pragma unroll
    for (int j = 0; j < 2; ++j) {
      const int m0 = wm2 + i * 16 + quad * 4;
      const int n = wn2 + j * 16 + fm;
#pragma unroll
      for (int rr = 0; rr < 4; ++rr) {
        const size_t idx = base + (size_t)(m0 + rr) * HIDS + n;
        att[idx] = f2bf(acc[i][j][rr] * bf2f(Eb[idx]));
      }
    }
}

// ---------------------------------------------------------------------------
// y = (LayerNorm(att) * gamma + beta) * silu(g), bf16 in/out.
// ---------------------------------------------------------------------------
__global__ __launch_bounds__(256) void ln_gate_kernel(const ushort* __restrict__ att,
                                                      const ushort* __restrict__ g,
                                                      const float* __restrict__ gamma,
                                                      const float* __restrict__ beta,
                                                      ushort* __restrict__ ybf) {
  const int row = blockIdx.x;
  const int tid = threadIdx.x;
  ushort4 au = *(const ushort4*)(att + (size_t)row * HIDS + tid * 4);
  float ax = bf2f(au.x), ay = bf2f(au.y), az = bf2f(au.z), aw = bf2f(au.w);
  float s = ax + ay + az + aw;
  float ss = ax * ax + ay * ay + az * az + aw * aw;
#pragma unroll
  for (int off = 32; off; off >>= 1) {
    s += __shfl_down(s, off);
    ss += __shfl_down(ss, off);
  }
  __shared__ float rs[4], rss[4];
  const int wid = tid >> 6;
  if ((tid & 63) == 0) { rs[wid] = s; rss[wid] = ss; }
  __syncthreads();
  const float mean = (rs[0] + rs[1] + rs[2] + rs[3]) * (1.f / HIDS);
  const float ex2 = (rss[0] + rss[1] + rss[2] + rss[3]) * (1.f / HIDS);
  const float rstd = rsqrtf(ex2 - mean * mean + 1e-5f);

  float4 ga = *(const float4*)(gamma + tid * 4);
  float4 be = *(const float4*)(beta + tid * 4);
  ushort4 gu = *(const ushort4*)(g + (size_t)row * HIDS + tid * 4);
  float gx = bf2f(gu.x), gy = bf2f(gu.y), gz = bf2f(gu.z), gw = bf2f(gu.w);
  float4 o;
  o.x = ((ax - mean) * rstd * ga.x + be.x) * (gx / (1.f + __expf(-gx)));
  o.y = ((ay - mean) * rstd * ga.y + be.y) * (gy / (1.f + __expf(-gy)));
  o.z = ((az - mean) * rstd * ga.z + be.z) * (gz / (1.f + __expf(-gz)));
  o.w = ((aw - mean) * rstd * ga.w + be.w) * (gw / (1.f + __expf(-gw)));
  ushort4 ob;
  ob.x = f2bf(o.x); ob.y = f2bf(o.y); ob.z = f2bf(o.z); ob.w = f2bf(o.w);
  *(ushort4*)(ybf + (size_t)row * HIDS + tid * 4) = ob;
}

// ---------------------------------------------------------------------------
extern "C" void kernel_launch(void* const* d_in, const int* in_sizes, int n_in,
                              void* d_out, int out_size, void* d_ws, size_t ws_size,
                              hipStream_t stream) {
  const float* x     = (const float*)d_in[0];
  const float* Wq    = (const float*)d_in[1];
  const float* Wk    = (const float*)d_in[2];
  const float* Wv    = (const float*)d_in[3];
  const float* Wg    = (const float*)d_in[4];
  const float* Wgk1  = (const float*)d_in[5];
  const float* Wgk2  = (const float*)d_in[6];
  const float* bgk2  = (const float*)d_in[7];
  const float* gamma = (const float*)d_in[8];
  const float* beta  = (const float*)d_in[9];
  const float* Wout  = (const float*)d_in[10];
  float* out = (float*)d_out;

  const size_t SZ = (size_t)NROW * HIDS;  // 4M elements
  float* ws = (float*)d_ws;
  float* Lamb = ws;                         // 64K floats
  ushort* attb   = (ushort*)(ws + 65536);   // bf16 4M
  ushort* Sdelta = attb + SZ;
  ushort* Sprevb = Sdelta + SZ;
  ushort* Vtgb   = Sprevb + SZ;             // V~^T tiles (bf16)
  ushort* Ebb    = Vtgb + SZ;               // e^Gamma (bf16)
  ushort* qbf = Ebb + SZ;
  ushort* kbf = qbf + SZ;
  ushort* vbf = kbf + SZ;
  ushort* gbf = vbf + SZ;
  ushort* zbf = gbf + SZ;                   // gate logits (bf16, pre-bias)
  ushort* xbf = zbf + SZ;
  ushort* Wtq = xbf + SZ;
  ushort* Wtk = Wtq + HIDS * HIDS;
  ushort* Wtv = Wtk + HIDS * HIDS;
  ushort* Wtg = Wtv + HIDS * HIDS;
  ushort* Wto = Wtg + HIDS * HIDS;
  ushort* Wte = Wto + HIDS * HIDS;
  ushort* ybf = vbf;  // vbf dead after sdelta

  prep_kernel<<<4096 + 1280 + 256, 256, 0, stream>>>(
      x, xbf, Wq, Wk, Wv, Wg, Wout, Wtq, Wtk, Wtv, Wtg, Wto, Wgk1, Wgk2, Wte);

  proj5_kernel<<<dim3(5 * (HIDS / 128), NROW / 128), 256, 0, stream>>>(
      xbf, Wtq, Wtk, Wtv, Wtg, Wte, qbf, kbf, vbf, gbf, zbf);

  sdelta_kernel<<<BBATCH * NHEAD * NCHUNK, 256, 0, stream>>>(
      kbf, vbf, zbf, bgk2, Sdelta, Lamb, Vtgb, Ebb);
  state_scan_kernel<<<256, 256, 0, stream>>>(Sdelta, Lamb, Sprevb);
  chunk_fused_kernel<<<BBATCH * NHEAD * NCHUNK, 256, 0, stream>>>(
      qbf, kbf, Vtgb, Ebb, Sprevb, attb);

  ln_gate_kernel<<<NROW, 256, 0, stream>>>(attb, gbf, gamma, beta, ybf);
  gemm_out_kernel<<<dim3(HIDS / 64, NROW / 128), 256, 0, stream>>>(ybf, Wto, out);
}

// Round 11
// 206.415 us; speedup vs baseline: 1.3521x; 1.0238x over previous
//
#include <hip/hip_runtime.h>
#include <cstdint>
#include <cstddef>

#define HIDS 1024
#define NHEAD 16
#define HDIM 64
#define LSEQ 2048
#define BBATCH 2
#define NROW (BBATCH * LSEQ)  // 4096
#define CHUNK 64
#define NCHUNK (LSEQ / CHUNK)  // 32
#define RANK 16

typedef short short8 __attribute__((ext_vector_type(8)));
typedef float floatx4 __attribute__((ext_vector_type(4)));

__device__ __forceinline__ ushort f2bf(float f) {
  uint32_t u = __float_as_uint(f);
  uint32_t r = (u + 0x7fffu + ((u >> 16) & 1u)) >> 16;  // RNE
  return (ushort)r;
}
__device__ __forceinline__ float bf2f(ushort u) {
  return __uint_as_float(((uint32_t)u) << 16);
}
// log_sigmoid(z)/16 via native exp/log (arg of log in (1,2] -> accurate)
__device__ __forceinline__ float logsig16(float z) {
  return (fminf(z, 0.f) - __logf(1.f + __expf(-fabsf(z)))) * (1.f / 16.f);
}

__device__ __forceinline__ void async_copy16(const void* g, void* l) {
  __builtin_amdgcn_global_load_lds(
      (const __attribute__((address_space(1))) void*)g,
      (__attribute__((address_space(3))) void*)l, 16, 0, 0);
}

// ---------------------------------------------------------------------------
// prep: fused cvt_x (blocks 0..4095), transpose_w (4096..5375), weff (5376+).
// ---------------------------------------------------------------------------
__global__ __launch_bounds__(256) void prep_kernel(
    const float* __restrict__ x, ushort* __restrict__ xbf,
    const float* __restrict__ W0, const float* __restrict__ W1,
    const float* __restrict__ W2, const float* __restrict__ W3,
    const float* __restrict__ W4, ushort* __restrict__ T0,
    ushort* __restrict__ T1, ushort* __restrict__ T2, ushort* __restrict__ T3,
    ushort* __restrict__ T4, const float* __restrict__ Wgk1,
    const float* __restrict__ Wgk2, ushort* __restrict__ Wte) {
  __shared__ float sbuf[64 * 65];
  const int bid = blockIdx.x;
  const int tid = threadIdx.x;

  if (bid < 4096) {  // ---- cvt_x
    const int i = bid * 256 + tid;
    float4 f = *(const float4*)(x + (size_t)i * 4);
    ushort4 o;
    o.x = f2bf(f.x); o.y = f2bf(f.y); o.z = f2bf(f.z); o.w = f2bf(f.w);
    *(ushort4*)(xbf + (size_t)i * 4) = o;
  } else if (bid < 5376) {  // ---- transpose_w
    const int w = bid - 4096;
    const int z = w >> 8, rem = w & 255;
    const float* W = (z == 0) ? W0 : (z == 1) ? W1 : (z == 2) ? W2
                     : (z == 3) ? W3 : W4;
    ushort* T = (z == 0) ? T0 : (z == 1) ? T1 : (z == 2) ? T2
                : (z == 3) ? T3 : T4;
    const int k0 = (rem >> 4) * 64, n0 = (rem & 15) * 64;
    const int r = tid >> 2, c4 = (tid & 3) * 16;
#pragma unroll
    for (int i = 0; i < 4; ++i) {
      float4 f = *(const float4*)(W + (size_t)(k0 + r) * HIDS + n0 + c4 + i * 4);
      sbuf[r * 65 + c4 + i * 4 + 0] = f.x;
      sbuf[r * 65 + c4 + i * 4 + 1] = f.y;
      sbuf[r * 65 + c4 + i * 4 + 2] = f.z;
      sbuf[r * 65 + c4 + i * 4 + 3] = f.w;
    }
    __syncthreads();
    const int n = tid >> 2, kc = (tid & 3) * 16;
#pragma unroll
    for (int i = 0; i < 4; ++i) {
      int kk = kc + i * 4;
      ushort4 o;
      o.x = f2bf(sbuf[(kk + 0) * 65 + n]);
      o.y = f2bf(sbuf[(kk + 1) * 65 + n]);
      o.z = f2bf(sbuf[(kk + 2) * 65 + n]);
      o.w = f2bf(sbuf[(kk + 3) * 65 + n]);
      *(ushort4*)(T + (size_t)(n0 + n) * HIDS + k0 + kk) = o;
    }
  } else {  // ---- weff
    const int rem = bid - 5376;
    const int n0 = (rem & 15) * 64, k0 = (rem >> 4) * 64;
    float* sW1 = sbuf;            // [64][17]
    float* sW2 = sbuf + 64 * 17;  // [16][65]
    {
      const int kl = tid >> 2, r4 = (tid & 3) * 4;
      float4 f = *(const float4*)(Wgk1 + (size_t)(k0 + kl) * RANK + r4);
      sW1[kl * 17 + r4] = f.x; sW1[kl * 17 + r4 + 1] = f.y;
      sW1[kl * 17 + r4 + 2] = f.z; sW1[kl * 17 + r4 + 3] = f.w;
      const int rr = tid >> 4, nl = (tid & 15) * 4;
      float4 g = *(const float4*)(Wgk2 + (size_t)rr * HIDS + n0 + nl);
      sW2[rr * 65 + nl] = g.x; sW2[rr * 65 + nl + 1] = g.y;
      sW2[rr * 65 + nl + 2] = g.z; sW2[rr * 65 + nl + 3] = g.w;
    }
    __syncthreads();
    const int nl = tid & 63, kq = (tid >> 6) * 16;
    float w2[16];
#pragma unroll
    for (int r = 0; r < 16; ++r) w2[r] = sW2[r * 65 + nl];
    ushort ob[16];
#pragma unroll
    for (int i = 0; i < 16; ++i) {
      float s = 0.f;
#pragma unroll
      for (int r = 0; r < 16; ++r) s = fmaf(sW1[(kq + i) * 17 + r], w2[r], s);
      ob[i] = f2bf(s);
    }
#pragma unroll
    for (int i = 0; i < 2; ++i)
      *(short8*)(Wte + (size_t)(n0 + nl) * HIDS + k0 + kq + i * 8) =
          *(short8*)&ob[i * 8];
  }
}

// ---------------------------------------------------------------------------
// proj5: 128x128 bf16 MFMA GEMM, BK=64, XOR-swizzled LDS staging (conflict-
// free reads), z fastest-varying for L2-hot A reads, uniform bf16 epilogue.
// ---------------------------------------------------------------------------
__global__ __launch_bounds__(256) void proj5_kernel(
    const ushort* __restrict__ xbf, const ushort* __restrict__ Wtq,
    const ushort* __restrict__ Wtk, const ushort* __restrict__ Wtv,
    const ushort* __restrict__ Wtg, const ushort* __restrict__ Wte,
    ushort* __restrict__ qb, ushort* __restrict__ kb, ushort* __restrict__ vb,
    ushort* __restrict__ gb, ushort* __restrict__ zb) {
  const int bxz = blockIdx.x;
  const int z = bxz % 5;       // fastest-varying
  const int bx = bxz / 5;
  const ushort* Bt = (z == 0) ? Wtq : (z == 1) ? Wtk : (z == 2) ? Wtv
                     : (z == 3) ? Wtg : Wte;
  ushort* C = (z == 0) ? qb : (z == 1) ? kb : (z == 2) ? vb : (z == 3) ? gb : zb;
  __shared__ ushort As[2][128 * 32];
  __shared__ ushort Bs[2][128 * 32];
  const int tid = threadIdx.x;
  const int wave = tid >> 6, lane = tid & 63;
  const int wm = (wave >> 1) * 64, wn = (wave & 1) * 64;
  const int bm = blockIdx.y * 128, bn = bx * 128;
  // staging: lane t sources k-chunk q = ((t&3) - ((t>>3)&3)) & 3  (XOR swizzle)
  const int lrow = tid >> 2;
  const int lk8 = ((((tid & 3) - ((tid >> 3) & 3)) & 3)) * 8;
  const ushort* Ag = xbf + (size_t)(bm + lrow) * HIDS + lk8;
  const ushort* Bg = Bt + (size_t)(bn + lrow) * HIDS + lk8;
  char* A0 = (char*)&As[0][0] + tid * 16;
  char* A1 = (char*)&As[1][0] + tid * 16;
  char* B0 = (char*)&Bs[0][0] + tid * 16;
  char* B1 = (char*)&Bs[1][0] + tid * 16;

  floatx4 acc[4][4];
#pragma unroll
  for (int i = 0; i < 4; ++i)
#pragma unroll
    for (int j = 0; j < 4; ++j) acc[i][j] = (floatx4){0.f, 0.f, 0.f, 0.f};

  const int fm = lane & 15, quad = lane >> 4;
  const int sq8 = ((quad + (fm >> 1)) & 3) * 8;  // swizzled read slot

  for (int k0 = 0; k0 < HIDS; k0 += 64) {
    __syncthreads();
    async_copy16(Ag + k0, A0);
    async_copy16(Ag + (size_t)64 * HIDS + k0, A0 + 4096);
    async_copy16(Ag + k0 + 32, A1);
    async_copy16(Ag + (size_t)64 * HIDS + k0 + 32, A1 + 4096);
    async_copy16(Bg + k0, B0);
    async_copy16(Bg + (size_t)64 * HIDS + k0, B0 + 4096);
    async_copy16(Bg + k0 + 32, B1);
    async_copy16(Bg + (size_t)64 * HIDS + k0 + 32, B1 + 4096);
    __syncthreads();

#pragma unroll
    for (int ks = 0; ks < 2; ++ks) {
      short8 af[4], bfr[4];
#pragma unroll
      for (int i = 0; i < 4; ++i)
        af[i] = *(const short8*)&As[ks][(wm + i * 16 + fm) * 32 + sq8];
#pragma unroll
      for (int j = 0; j < 4; ++j)
        bfr[j] = *(const short8*)&Bs[ks][(wn + j * 16 + fm) * 32 + sq8];
#pragma unroll
      for (int i = 0; i < 4; ++i)
#pragma unroll
        for (int j = 0; j < 4; ++j)
          acc[i][j] = __builtin_amdgcn_mfma_f32_16x16x32_bf16(af[i], bfr[j],
                                                              acc[i][j], 0, 0, 0);
    }
  }

#pragma unroll
  for (int i = 0; i < 4; ++i) {
    const int row0 = bm + wm + i * 16 + quad * 4;
#pragma unroll
    for (int j = 0; j < 4; ++j) {
      const int col = bn + wn + j * 16 + fm;
#pragma unroll
      for (int r = 0; r < 4; ++r)
        C[(size_t)(row0 + r) * HIDS + col] = f2bf(acc[i][j][r]);
    }
  }
}

// ---------------------------------------------------------------------------
// Output GEMM: 128(M) x 64(N) tile, BK=64, swizzled staging, fp32 out.
// ---------------------------------------------------------------------------
__global__ __launch_bounds__(256) void gemm_out_kernel(
    const ushort* __restrict__ A, const ushort* __restrict__ Bt,
    float* __restrict__ C) {
  __shared__ ushort As[2][128 * 32];
  __shared__ ushort Bs[2][64 * 32];
  const int tid = threadIdx.x;
  const int wave = tid >> 6, lane = tid & 63;
  const int fm = lane & 15, quad = lane >> 4;
  const int sq8 = ((quad + (fm >> 1)) & 3) * 8;
  const int bm = blockIdx.y * 128, bn = blockIdx.x * 64;
  const int lrow = tid >> 2;
  const int lk8 = ((((tid & 3) - ((tid >> 3) & 3)) & 3)) * 8;
  const ushort* Ag = A + (size_t)(bm + lrow) * HIDS + lk8;
  const ushort* Bg = Bt + (size_t)(bn + lrow) * HIDS + lk8;
  char* A0 = (char*)&As[0][0] + tid * 16;
  char* A1 = (char*)&As[1][0] + tid * 16;
  char* B0 = (char*)&Bs[0][0] + tid * 16;
  char* B1 = (char*)&Bs[1][0] + tid * 16;

  floatx4 acc[2][4];
#pragma unroll
  for (int i = 0; i < 2; ++i)
#pragma unroll
    for (int j = 0; j < 4; ++j) acc[i][j] = (floatx4){0.f, 0.f, 0.f, 0.f};

  for (int k0 = 0; k0 < HIDS; k0 += 64) {
    __syncthreads();
    async_copy16(Ag + k0, A0);
    async_copy16(Ag + (size_t)64 * HIDS + k0, A0 + 4096);
    async_copy16(Ag + k0 + 32, A1);
    async_copy16(Ag + (size_t)64 * HIDS + k0 + 32, A1 + 4096);
    async_copy16(Bg + k0, B0);
    async_copy16(Bg + k0 + 32, B1);
    __syncthreads();

#pragma unroll
    for (int ks = 0; ks < 2; ++ks) {
      short8 af[2], bfr[4];
#pragma unroll
      for (int i = 0; i < 2; ++i)
        af[i] = *(const short8*)&As[ks][(wave * 32 + i * 16 + fm) * 32 + sq8];
#pragma unroll
      for (int j = 0; j < 4; ++j)
        bfr[j] = *(const short8*)&Bs[ks][(j * 16 + fm) * 32 + sq8];
#pragma unroll
      for (int i = 0; i < 2; ++i)
#pragma unroll
        for (int j = 0; j < 4; ++j)
          acc[i][j] = __builtin_amdgcn_mfma_f32_16x16x32_bf16(af[i], bfr[j],
                                                              acc[i][j], 0, 0, 0);
    }
  }

#pragma unroll
  for (int i = 0; i < 2; ++i) {
    const int row0 = bm + wave * 32 + i * 16 + quad * 4;
#pragma unroll
    for (int j = 0; j < 4; ++j) {
      const int col = bn + j * 16 + fm;
#pragma unroll
      for (int r = 0; r < 4; ++r)
        C[(size_t)(row0 + r) * HIDS + col] = acc[i][j][r];
    }
  }
}

#define SP 72   // ushort stride for bf16 LDS tiles (16B-aligned rows)
#define SGS 68  // float stride for Gamma tile

// ---------------------------------------------------------------------------
// sdelta: Gamma=cumsum(logsig16(z+bias)); Vt~=(e^-G V)^T; Sdelta = Lam.(V~^T K)
// exports Vtg (V~^T) and Eb = e^Gamma for chunk_fused.
// ---------------------------------------------------------------------------
__global__ __launch_bounds__(256) void sdelta_kernel(
    const ushort* __restrict__ k, const ushort* __restrict__ v,
    const ushort* __restrict__ zb, const float* __restrict__ bgk2,
    ushort* __restrict__ Sdelta, float* __restrict__ Lam,
    ushort* __restrict__ Vtg, ushort* __restrict__ Eb) {
  const int bid = blockIdx.x;
  const int c = bid & 31, bh = bid >> 5;
  const int b = bh >> 4, h = bh & 15;
  const int tid = threadIdx.x;
  const int lane = tid & 63, wave = tid >> 6;
  const int fm = lane & 15, quad = lane >> 4;
  const int wm2 = (wave >> 1) * 32, wn2 = (wave & 1) * 32;

  __shared__ ushort sKt[64 * SP];
  __shared__ ushort sVt[64 * SP];
  __shared__ float sG[64 * SGS];

  const size_t base = ((size_t)b * LSEQ + (size_t)c * CHUNK) * HIDS + (size_t)h * HDIM;
  const int r = tid >> 2, c0 = (tid & 3) * 16;
  const size_t gb = base + (size_t)r * HIDS + c0;
  {
    float bias[16];
#pragma unroll
    for (int m = 0; m < 4; ++m)
      *(float4*)&bias[m * 4] = *(const float4*)(bgk2 + h * HDIM + c0 + m * 4);
    short8 z0 = *(const short8*)(zb + gb);
    short8 z1 = *(const short8*)(zb + gb + 8);
#pragma unroll
    for (int i = 0; i < 16; ++i) {
      float zz = bf2f((ushort)(i < 8 ? z0[i] : z1[i - 8])) + bias[i];
      sG[r * SGS + c0 + i] = logsig16(zz);
    }
  }
  // pair partition (K, V)
  const int pr = (tid >> 3) * 2, pc = (tid & 7) * 8;
  const size_t pb = base + (size_t)pr * HIDS + pc;
  short8 ka = *(const short8*)(k + pb);
  short8 kb2 = *(const short8*)(k + pb + HIDS);
  short8 va = *(const short8*)(v + pb);
  short8 vb2 = *(const short8*)(v + pb + HIDS);
  __syncthreads();

  // inclusive cumsum along t per v column
  const int vcol = tid & 63, qtr = tid >> 6;
  {
    float run = 0.f;
#pragma unroll
    for (int i = 0; i < 16; ++i) {
      int idx = (qtr * 16 + i) * SGS + vcol;
      run += sG[idx];
      sG[idx] = run;
    }
  }
  __syncthreads();
  float pre = 0.f;
  for (int j = 0; j < qtr; ++j) pre += sG[(j * 16 + 15) * SGS + vcol];
  __syncthreads();
#pragma unroll
  for (int i = 0; i < 16; ++i) sG[(qtr * 16 + i) * SGS + vcol] += pre;
  __syncthreads();

  // E = e^Gamma -> global (coalesced 32B/thread)
  {
    ushort eb[16];
#pragma unroll
    for (int i = 0; i < 16; ++i) eb[i] = f2bf(__expf(sG[r * SGS + c0 + i]));
    *(short8*)(Eb + gb) = *(short8*)&eb[0];
    *(short8*)(Eb + gb + 8) = *(short8*)&eb[8];
  }

  // transposed tiles (ushort2 writes)
#pragma unroll
  for (int i = 0; i < 8; ++i) {
    ushort2 kk;
    kk.x = (ushort)ka[i];
    kk.y = (ushort)kb2[i];
    *(ushort2*)&sKt[(pc + i) * SP + pr] = kk;
    float Ga = sG[pr * SGS + pc + i];
    float Gb2 = sG[(pr + 1) * SGS + pc + i];
    ushort2 vv;
    vv.x = f2bf(bf2f((ushort)va[i]) * __expf(-Ga));
    vv.y = f2bf(bf2f((ushort)vb2[i]) * __expf(-Gb2));
    *(ushort2*)&sVt[(pc + i) * SP + pr] = vv;
  }
  __syncthreads();

  // export V~^T tile (coalesced 32B/thread)
  {
    const size_t vb3 = (size_t)(bh * NCHUNK + c) * (HDIM * HDIM);
    *(short8*)(Vtg + vb3 + (size_t)r * HDIM + c0) = *(const short8*)&sVt[r * SP + c0];
    *(short8*)(Vtg + vb3 + (size_t)r * HDIM + c0 + 8) =
        *(const short8*)&sVt[r * SP + c0 + 8];
  }

  if (tid < 64)
    Lam[(size_t)(bh * NCHUNK + c) * HDIM + tid] = __expf(sG[63 * SGS + tid]);

  floatx4 accD[2][2];
#pragma unroll
  for (int i = 0; i < 2; ++i)
#pragma unroll
    for (int j = 0; j < 2; ++j) accD[i][j] = (floatx4){0.f, 0.f, 0.f, 0.f};
#pragma unroll
  for (int ks = 0; ks < 2; ++ks) {
    short8 av[2], bk[2];
#pragma unroll
    for (int i = 0; i < 2; ++i)
      av[i] = *(const short8*)&sVt[(wm2 + i * 16 + fm) * SP + ks * 32 + quad * 8];
#pragma unroll
    for (int j = 0; j < 2; ++j)
      bk[j] = *(const short8*)&sKt[(wn2 + j * 16 + fm) * SP + ks * 32 + quad * 8];
#pragma unroll
    for (int i = 0; i < 2; ++i)
#pragma unroll
      for (int j = 0; j < 2; ++j)
        accD[i][j] = __builtin_amdgcn_mfma_f32_16x16x32_bf16(av[i], bk[j],
                                                             accD[i][j], 0, 0, 0);
  }
  const size_t sbase = (size_t)(bh * NCHUNK + c) * (HDIM * HDIM);
#pragma unroll
  for (int i = 0; i < 2; ++i) {
    const int m0 = wm2 + i * 16 + quad * 4;
    float lam[4];
#pragma unroll
    for (int rr = 0; rr < 4; ++rr) lam[rr] = __expf(sG[63 * SGS + m0 + rr]);
#pragma unroll
    for (int j = 0; j < 2; ++j) {
      const int n = wn2 + j * 16 + fm;
#pragma unroll
      for (int rr = 0; rr < 4; ++rr)
        Sdelta[sbase + (size_t)(m0 + rr) * HDIM + n] = f2bf(accD[i][j][rr] * lam[rr]);
    }
  }
}

// ---------------------------------------------------------------------------
// state_scan: elementwise-parallel over 4096 state slots; 256 blocks.
// ---------------------------------------------------------------------------
__global__ __launch_bounds__(256) void state_scan_kernel(
    const ushort* __restrict__ Sdelta, const float* __restrict__ Lam,
    ushort* __restrict__ Sprev) {
  const int bh = blockIdx.x >> 3;
  const int sl = blockIdx.x & 7;
  const int tid = threadIdx.x;
  const int e0 = sl * 512 + tid;
  float S0 = 0.f, S1 = 0.f;

  float pd0[2], pd1[2], pl0[2], pl1[2];
#pragma unroll
  for (int s = 0; s < 2; ++s) {
    size_t nb = (size_t)(bh * NCHUNK + s) * (HDIM * HDIM);
    size_t nl = (size_t)(bh * NCHUNK + s) * HDIM;
    pd0[s] = bf2f(Sdelta[nb + e0]);
    pd1[s] = bf2f(Sdelta[nb + e0 + 256]);
    pl0[s] = Lam[nl + (e0 >> 6)];
    pl1[s] = Lam[nl + ((e0 + 256) >> 6)];
  }

  for (int c = 0; c < NCHUNK; ++c) {
    const int s = c & 1;
    float cd0 = pd0[s], cd1 = pd1[s], cl0 = pl0[s], cl1 = pl1[s];
    if (c + 2 < NCHUNK) {
      size_t nb = (size_t)(bh * NCHUNK + c + 2) * (HDIM * HDIM);
      size_t nl = (size_t)(bh * NCHUNK + c + 2) * HDIM;
      pd0[s] = bf2f(Sdelta[nb + e0]);
      pd1[s] = bf2f(Sdelta[nb + e0 + 256]);
      pl0[s] = Lam[nl + (e0 >> 6)];
      pl1[s] = Lam[nl + ((e0 + 256) >> 6)];
    }
    size_t ob = (size_t)(bh * NCHUNK + c) * (HDIM * HDIM);
    Sprev[ob + e0] = f2bf(S0);
    Sprev[ob + e0 + 256] = f2bf(S1);
    S0 = fmaf(S0, cl0, cd0);
    S1 = fmaf(S1, cl1, cd1);
  }
}

// ---------------------------------------------------------------------------
// chunk_fused: att(bf16) = E . ( tril(QK^T) @ V~ + Q @ Sprev^T )
// ---------------------------------------------------------------------------
__global__ __launch_bounds__(256) void chunk_fused_kernel(
    const ushort* __restrict__ q, const ushort* __restrict__ k,
    const ushort* __restrict__ Vtg, const ushort* __restrict__ Eb,
    const ushort* __restrict__ Sprev, ushort* __restrict__ att) {
  const int bid = blockIdx.x;
  const int c = bid & 31, bh = bid >> 5;
  const int b = bh >> 4, h = bh & 15;
  const int tid = threadIdx.x;
  const int lane = tid & 63, wave = tid >> 6;
  const int fm = lane & 15, quad = lane >> 4;
  const int wm2 = (wave >> 1) * 32, wn2 = (wave & 1) * 32;

  __shared__ ushort sQ[64 * SP];
  __shared__ ushort sK[64 * SP];   // reused as sSp after scores
  __shared__ ushort sVt[64 * SP];
  __shared__ ushort sA[64 * SP];
  ushort* sSp = sK;

  const size_t base = ((size_t)b * LSEQ + (size_t)c * CHUNK) * HIDS + (size_t)h * HDIM;
  const size_t sbase = (size_t)(bh * NCHUNK + c) * (HDIM * HDIM);
  const int r = tid >> 2, c0 = (tid & 3) * 16;
  const size_t gb = base + (size_t)r * HIDS + c0;
  short8 sp0 = *(const short8*)(Sprev + sbase + (size_t)r * HDIM + c0);
  short8 sp1 = *(const short8*)(Sprev + sbase + (size_t)r * HDIM + c0 + 8);
  *(short8*)&sQ[r * SP + c0] = *(const short8*)(q + gb);
  *(short8*)&sQ[r * SP + c0 + 8] = *(const short8*)(q + gb + 8);
  *(short8*)&sK[r * SP + c0] = *(const short8*)(k + gb);
  *(short8*)&sK[r * SP + c0 + 8] = *(const short8*)(k + gb + 8);
  *(short8*)&sVt[r * SP + c0] = *(const short8*)(Vtg + sbase + (size_t)r * HDIM + c0);
  *(short8*)&sVt[r * SP + c0 + 8] =
      *(const short8*)(Vtg + sbase + (size_t)r * HDIM + c0 + 8);
  __syncthreads();

  // scores = tril(Q K^T)
  floatx4 accS[2][2];
#pragma unroll
  for (int i = 0; i < 2; ++i)
#pragma unroll
    for (int j = 0; j < 2; ++j) accS[i][j] = (floatx4){0.f, 0.f, 0.f, 0.f};
#pragma unroll
  for (int ks = 0; ks < 2; ++ks) {
    short8 a[2], bb[2];
#pragma unroll
    for (int i = 0; i < 2; ++i)
      a[i] = *(const short8*)&sQ[(wm2 + i * 16 + fm) * SP + ks * 32 + quad * 8];
#pragma unroll
    for (int j = 0; j < 2; ++j)
      bb[j] = *(const short8*)&sK[(wn2 + j * 16 + fm) * SP + ks * 32 + quad * 8];
#pragma unroll
    for (int i = 0; i < 2; ++i)
#pragma unroll
      for (int j = 0; j < 2; ++j)
        accS[i][j] = __builtin_amdgcn_mfma_f32_16x16x32_bf16(a[i], bb[j],
                                                             accS[i][j], 0, 0, 0);
  }
  __syncthreads();  // all waves done reading sK

  // write sA (tril) and sSp (into sK space)
#pragma unroll
  for (int i = 0; i < 2; ++i)
#pragma unroll
    for (int j = 0; j < 2; ++j) {
      const int t0 = wm2 + i * 16 + quad * 4;
      const int s = wn2 + j * 16 + fm;
#pragma unroll
      for (int rr = 0; rr < 4; ++rr) {
        float val = (s <= t0 + rr) ? accS[i][j][rr] : 0.f;
        sA[(t0 + rr) * SP + s] = f2bf(val);
      }
    }
  *(short8*)&sSp[r * SP + c0] = sp0;
  *(short8*)&sSp[r * SP + c0 + 8] = sp1;
  __syncthreads();

  // att = E . (sA @ V~  +  Q @ Sprev^T)
  floatx4 acc[2][2];
#pragma unroll
  for (int i = 0; i < 2; ++i)
#pragma unroll
    for (int j = 0; j < 2; ++j) acc[i][j] = (floatx4){0.f, 0.f, 0.f, 0.f};
#pragma unroll
  for (int ks = 0; ks < 2; ++ks) {
    short8 aa[2], aq[2], bv[2], bs[2];
#pragma unroll
    for (int i = 0; i < 2; ++i) {
      aa[i] = *(const short8*)&sA[(wm2 + i * 16 + fm) * SP + ks * 32 + quad * 8];
      aq[i] = *(const short8*)&sQ[(wm2 + i * 16 + fm) * SP + ks * 32 + quad * 8];
    }
#pragma unroll
    for (int j = 0; j < 2; ++j) {
      bv[j] = *(const short8*)&sVt[(wn2 + j * 16 + fm) * SP + ks * 32 + quad * 8];
      bs[j] = *(const short8*)&sSp[(wn2 + j * 16 + fm) * SP + ks * 32 + quad * 8];
    }
#pragma unroll
    for (int i = 0; i < 2; ++i)
#pragma unroll
      for (int j = 0; j < 2; ++j) {
        acc[i][j] = __builtin_amdgcn_mfma_f32_16x16x32_bf16(aa[i], bv[j],
                                                            acc[i][j], 0, 0, 0);
        acc[i][j] = __builtin_amdgcn_mfma_f32_16x16x32_bf16(aq[i], bs[j],
                                                            acc[i][j], 0, 0, 0);
      }
  }
#pragma unroll
  for (int i = 0; i < 2; ++i)
#pragma unroll
    for (int j = 0; j < 2; ++j) {
      const int m0 = wm2 + i * 16 + quad * 4;
      const int n = wn2 + j * 16 + fm;
#pragma unroll
      for (int rr = 0; rr < 4; ++rr) {
        const size_t idx = base + (size_t)(m0 + rr) * HIDS + n;
        att[idx] = f2bf(acc[i][j][rr] * bf2f(Eb[idx]));
      }
    }
}

// ---------------------------------------------------------------------------
// y = (LayerNorm(att) * gamma + beta) * silu(g), bf16 in/out.
// ---------------------------------------------------------------------------
__global__ __launch_bounds__(256) void ln_gate_kernel(const ushort* __restrict__ att,
                                                      const ushort* __restrict__ g,
                                                      const float* __restrict__ gamma,
                                                      const float* __restrict__ beta,
                                                      ushort* __restrict__ ybf) {
  const int row = blockIdx.x;
  const int tid = threadIdx.x;
  ushort4 au = *(const ushort4*)(att + (size_t)row * HIDS + tid * 4);
  float ax = bf2f(au.x), ay = bf2f(au.y), az = bf2f(au.z), aw = bf2f(au.w);
  float s = ax + ay + az + aw;
  float ss = ax * ax + ay * ay + az * az + aw * aw;
#pragma unroll
  for (int off = 32; off; off >>= 1) {
    s += __shfl_down(s, off);
    ss += __shfl_down(ss, off);
  }
  __shared__ float rs[4], rss[4];
  const int wid = tid >> 6;
  if ((tid & 63) == 0) { rs[wid] = s; rss[wid] = ss; }
  __syncthreads();
  const float mean = (rs[0] + rs[1] + rs[2] + rs[3]) * (1.f / HIDS);
  const float ex2 = (rss[0] + rss[1] + rss[2] + rss[3]) * (1.f / HIDS);
  const float rstd = rsqrtf(ex2 - mean * mean + 1e-5f);

  float4 ga = *(const float4*)(gamma + tid * 4);
  float4 be = *(const float4*)(beta + tid * 4);
  ushort4 gu = *(const ushort4*)(g + (size_t)row * HIDS + tid * 4);
  float gx = bf2f(gu.x), gy = bf2f(gu.y), gz = bf2f(gu.z), gw = bf2f(gu.w);
  float4 o;
  o.x = ((ax - mean) * rstd * ga.x + be.x) * (gx / (1.f + __expf(-gx)));
  o.y = ((ay - mean) * rstd * ga.y + be.y) * (gy / (1.f + __expf(-gy)));
  o.z = ((az - mean) * rstd * ga.z + be.z) * (gz / (1.f + __expf(-gz)));
  o.w = ((aw - mean) * rstd * ga.w + be.w) * (gw / (1.f + __expf(-gw)));
  ushort4 ob;
  ob.x = f2bf(o.x); ob.y = f2bf(o.y); ob.z = f2bf(o.z); ob.w = f2bf(o.w);
  *(ushort4*)(ybf + (size_t)row * HIDS + tid * 4) = ob;
}

// ---------------------------------------------------------------------------
extern "C" void kernel_launch(void* const* d_in, const int* in_sizes, int n_in,
                              void* d_out, int out_size, void* d_ws, size_t ws_size,
                              hipStream_t stream) {
  const float* x     = (const float*)d_in[0];
  const float* Wq    = (const float*)d_in[1];
  const float* Wk    = (const float*)d_in[2];
  const float* Wv    = (const float*)d_in[3];
  const float* Wg    = (const float*)d_in[4];
  const float* Wgk1  = (const float*)d_in[5];
  const float* Wgk2  = (const float*)d_in[6];
  const float* bgk2  = (const float*)d_in[7];
  const float* gamma = (const float*)d_in[8];
  const float* beta  = (const float*)d_in[9];
  const float* Wout  = (const float*)d_in[10];
  float* out = (float*)d_out;

  const size_t SZ = (size_t)NROW * HIDS;  // 4M elements
  float* ws = (float*)d_ws;
  float* Lamb = ws;                         // 64K floats
  ushort* attb   = (ushort*)(ws + 65536);   // bf16 4M
  ushort* Sdelta = attb + SZ;
  ushort* Sprevb = Sdelta + SZ;
  ushort* Vtgb   = Sprevb + SZ;             // V~^T tiles (bf16)
  ushort* Ebb    = Vtgb + SZ;               // e^Gamma (bf16)
  ushort* qbf = Ebb + SZ;
  ushort* kbf = qbf + SZ;
  ushort* vbf = kbf + SZ;
  ushort* gbf = vbf + SZ;
  ushort* zbf = gbf + SZ;                   // gate logits (bf16, pre-bias)
  ushort* xbf = zbf + SZ;
  ushort* Wtq = xbf + SZ;
  ushort* Wtk = Wtq + HIDS * HIDS;
  ushort* Wtv = Wtk + HIDS * HIDS;
  ushort* Wtg = Wtv + HIDS * HIDS;
  ushort* Wto = Wtg + HIDS * HIDS;
  ushort* Wte = Wto + HIDS * HIDS;
  ushort* ybf = vbf;  // vbf dead after sdelta

  prep_kernel<<<4096 + 1280 + 256, 256, 0, stream>>>(
      x, xbf, Wq, Wk, Wv, Wg, Wout, Wtq, Wtk, Wtv, Wtg, Wto, Wgk1, Wgk2, Wte);

  proj5_kernel<<<dim3(5 * (HIDS / 128), NROW / 128), 256, 0, stream>>>(
      xbf, Wtq, Wtk, Wtv, Wtg, Wte, qbf, kbf, vbf, gbf, zbf);

  sdelta_kernel<<<BBATCH * NHEAD * NCHUNK, 256, 0, stream>>>(
      kbf, vbf, zbf, bgk2, Sdelta, Lamb, Vtgb, Ebb);
  state_scan_kernel<<<256, 256, 0, stream>>>(Sdelta, Lamb, Sprevb);
  chunk_fused_kernel<<<BBATCH * NHEAD * NCHUNK, 256, 0, stream>>>(
      qbf, kbf, Vtgb, Ebb, Sprevb, attb);

  ln_gate_kernel<<<NROW, 256, 0, stream>>>(attb, gbf, gamma, beta, ybf);
  gemm_out_kernel<<<dim3(HIDS / 64, NROW / 128), 256, 0, stream>>>(ybf, Wto, out);
}